// Round 1
// baseline (430.897 us; speedup 1.0000x reference)
//
#include <hip/hip_runtime.h>
#include <cmath>

#define DEV __device__ __forceinline__

constexpr int B_ = 2;
constexpr int S4[4]    = {48, 24, 12, 6};
constexpr int L4[4]    = {2304, 576, 144, 36};
constexpr int LOFF4[4] = {0, 2304, 2880, 3024};
constexpr int LTOT = 3060;
constexpr int NT4[4]   = {144, 36, 9, 3};
constexpr int TOFF4[4] = {0, 144, 180, 189};
constexpr int NTT = 192;
constexpr int NCH4[4]   = {18, 5, 2, 1};     // ceil(L/128)
constexpr int CHOFF4[4] = {0, 18, 23, 25};
constexpr int NCHL = 26;
constexpr int NCHC = 18;
constexpr int LC = 2304;
constexpr float LOG2E = 1.44269504088896f;

DEV float siluf(float x) { return x / (1.f + __expf(-x)); }
DEV float softplusf(float x) { return fmaxf(x, 0.f) + log1pf(__expf(-fabsf(x))); }

// ---------------- prep: Wt = projW^T ; WP = cr_Wout @ projW^T ----------------
__global__ __launch_bounds__(256) void k_prep1(const float* __restrict__ projW,
                                               float* __restrict__ Wt) {
  int i = blockIdx.x * 256 + threadIdx.x;   // 16384
  int o = i >> 8, c = i & 255;
  Wt[c * 64 + o] = projW[o * 256 + c];
}

__global__ __launch_bounds__(256) void k_prep2(const float* __restrict__ crWout,
                                               const float* __restrict__ Wt,
                                               float* __restrict__ WP) {
  int i = blockIdx.x * 256 + threadIdx.x;   // 32768
  int d = i >> 6, o = i & 63;
  float acc = 0.f;
#pragma unroll 4
  for (int c = 0; c < 256; ++c)
    acc = fmaf(crWout[d * 256 + c], Wt[c * 64 + o], acc);
  WP[d * 64 + o] = acc;
}

// ------------- level front: in-GEMM + conv + silu + dbc + dt (fused) ---------
__global__ __launch_bounds__(256) void k_front_lvl(
    const float* __restrict__ f0, const float* __restrict__ f1,
    const float* __restrict__ f2, const float* __restrict__ f3,
    const float* __restrict__ Win,   // (4,64,256)
    const float* __restrict__ Wconv, // (4,128,4)
    const float* __restrict__ bconv, // (4,128)
    const float* __restrict__ Wx,    // (4,128,36)
    const float* __restrict__ Wdt,   // (4,4,128)
    const float* __restrict__ bdt,   // (4,128)
    float* __restrict__ u_l, float* __restrict__ dt_l,
    float* __restrict__ bc_l, float* __restrict__ z_l) {
  __shared__ float s_x[64 * 20];     // input tile, rows c, cols r (19 used)
  __shared__ float s_xs[19 * 128];   // xs rows l0-3 .. l0+15
  __shared__ float s_u[16 * 132];    // padded to kill bank conflicts
  __shared__ float s_dbc[16 * 36];
  int bid = blockIdx.x;              // B*NTT
  int b = bid / NTT, t = bid - b * NTT;
  int lvl = 0;
  while (lvl < 3 && t >= TOFF4[lvl + 1]) ++lvl;
  int tl = t - TOFF4[lvl];
  int L = L4[lvl], loff = LOFF4[lvl];
  int l0 = tl * 16;
  int nl = min(16, L - l0);
  const float* fx = lvl == 0 ? f0 : lvl == 1 ? f1 : lvl == 2 ? f2 : f3;
  int tid = threadIdx.x;

  for (int i = tid; i < 64 * 20; i += 256) {
    int c = i / 20, r = i - c * 20;
    int l = l0 - 3 + r;
    float v = 0.f;
    if (r < 19 && l >= 0 && l < L) v = fx[(size_t)(b * 64 + c) * L + l];
    s_x[i] = v;
  }
  __syncthreads();
  {  // xz GEMM: 19 rows x 256 cols, K=64
    int j = tid;
    float acc[19];
#pragma unroll
    for (int r = 0; r < 19; ++r) acc[r] = 0.f;
    const float* W = Win + lvl * 64 * 256 + j;
    for (int c = 0; c < 64; ++c) {
      float w = W[c * 256];
#pragma unroll
      for (int r = 0; r < 19; ++r) acc[r] = fmaf(w, s_x[c * 20 + r], acc[r]);
    }
    if (j < 128) {
#pragma unroll
      for (int r = 0; r < 19; ++r) s_xs[r * 128 + j] = acc[r];
    } else {
      int d = j - 128;
      for (int r = 3; r < 19; ++r) {
        int l = l0 - 3 + r;   // level-local row
        if (l < l0 + nl)
          z_l[((size_t)(b * LTOT) + loff + l) * 128 + d] = acc[r];
      }
    }
  }
  __syncthreads();
  // causal conv (K=4) + silu -> u
  for (int i = tid; i < 16 * 128; i += 256) {
    int l = i >> 7, d = i & 127;
    if (l < nl) {
      const float* wc = Wconv + (lvl * 128 + d) * 4;
      float a = bconv[lvl * 128 + d];
#pragma unroll
      for (int k = 0; k < 4; ++k) a = fmaf(wc[k], s_xs[(l + k) * 128 + d], a);
      float uu = siluf(a);
      s_u[l * 132 + d] = uu;
      u_l[((size_t)(b * LTOT) + loff + l0 + l) * 128 + d] = uu;
    }
  }
  __syncthreads();
  // dbc = u @ Wx  (16 l x 36 j, K=128)
  for (int i = tid; i < 16 * 36; i += 256) {
    int l = i & 15, jj = i >> 4;
    if (l < nl) {
      const float* wx = Wx + lvl * 128 * 36 + jj;
      float a = 0.f;
      for (int d = 0; d < 128; ++d) a = fmaf(s_u[l * 132 + d], wx[d * 36], a);
      s_dbc[l * 36 + jj] = a;
      if (jj >= 4)
        bc_l[((size_t)(b * LTOT) + loff + l0 + l) * 32 + (jj - 4)] = a;
    }
  }
  __syncthreads();
  // dt = softplus(dbc[:, :4] @ Wdt + bdt)
  for (int i = tid; i < 16 * 128; i += 256) {
    int l = i >> 7, d = i & 127;
    if (l < nl) {
      float a = bdt[lvl * 128 + d];
#pragma unroll
      for (int r = 0; r < 4; ++r)
        a = fmaf(s_dbc[l * 36 + r], Wdt[(lvl * 4 + r) * 128 + d], a);
      dt_l[((size_t)(b * LTOT) + loff + l0 + l) * 128 + d] = softplusf(a);
    }
  }
}

// ----------------------------- chunked scan ---------------------------------
// MODE 0 = levels (DI=128), MODE 1 = cross (DI=512). PASSC: emit gated y.
template <int MODE, int PASSC>
__global__ __launch_bounds__(256) void k_scan(
    const float* __restrict__ dtb, const float* __restrict__ ub,
    const float* __restrict__ bcb, const float* __restrict__ zb,
    const float* __restrict__ Alog, const float* __restrict__ Dsk,
    float* __restrict__ hloc, float* __restrict__ Ssum,
    const float* __restrict__ hin, float* __restrict__ yg) {
  constexpr int DI = MODE ? 512 : 128;
  constexpr int NDT = DI / 16;
  constexpr int NCHT = MODE ? NCHC : NCHL;
  constexpr int LT = MODE ? LC : LTOT;
  extern __shared__ float sm[];
  float* s_dt = sm;
  float* s_u = sm + 2048;
  float* s_B = sm + 2 * 2048;
  float* s_C = sm + 3 * 2048;
  float* s_z = sm + 4 * 2048;
  float* s_y = sm + 5 * 2048;

  int bid = blockIdx.x;
  int gc = bid % NCHT;
  int rem2 = bid / NCHT;
  int dti = rem2 % NDT;
  int b = rem2 / NDT;
  int lvl = 0, ch = gc, Lq = LC, loff = 0;
  if (MODE == 0) {
    while (lvl < 3 && gc >= CHOFF4[lvl + 1]) ++lvl;
    ch = gc - CHOFF4[lvl];
    Lq = L4[lvl];
    loff = LOFF4[lvl];
  }
  int l0 = ch * 128;
  int len = min(128, Lq - l0);
  int labs0 = loff + l0;
  int d0 = dti * 16;
  int tid = threadIdx.x;
  int n = tid & 15, dd = tid >> 4;
  int d = d0 + dd;

  for (int i = tid; i < len * 16; i += 256) {
    int l = i >> 4, j = i & 15;
    size_t g = ((size_t)(b * LT) + labs0 + l) * DI + d0 + j;
    s_dt[i] = dtb[g];
    s_u[i] = ub[g];
    if (PASSC) s_z[i] = zb[g];
    size_t gb = ((size_t)(b * LT) + labs0 + l) * 32 + j;
    s_B[i] = bcb[gb];
    if (PASSC) s_C[i] = bcb[gb + 16];
  }
  __syncthreads();

  int ai = (MODE ? d : lvl * 128 + d);
  float kA2 = -__expf(Alog[ai * 16 + n]) * LOG2E;
  size_t hix = (((size_t)(b * NCHT) + gc) * DI + d) * 16 + n;
  float h = 0.f, ss = 0.f;
  if (PASSC) h = hin[hix];
  float dsk = PASSC ? Dsk[ai] : 0.f;

  for (int l = 0; l < len; ++l) {
    float dt = s_dt[l * 16 + dd];
    float uu = s_u[l * 16 + dd];
    float bm = s_B[l * 16 + n];
    float dA = exp2f(kA2 * dt);
    h = fmaf(dA, h, dt * uu * bm);
    if (PASSC) {
      float p = h * s_C[l * 16 + n];
      p += __shfl_xor(p, 1, 16);
      p += __shfl_xor(p, 2, 16);
      p += __shfl_xor(p, 4, 16);
      p += __shfl_xor(p, 8, 16);
      if (n == 0) s_y[l * 16 + dd] = fmaf(uu, dsk, p);
    } else {
      ss += dt;
    }
  }
  if (!PASSC) {
    hloc[hix] = h;
    if (n == 0) Ssum[((size_t)(b * NCHT) + gc) * DI + d] = ss;
  } else {
    __syncthreads();
    for (int i = tid; i < len * 16; i += 256) {
      int l = i >> 4, j = i & 15;
      float z = s_z[i];
      float gate = z / (1.f + __expf(-z));
      yg[((size_t)(b * LT) + labs0 + l) * DI + d0 + j] = s_y[i] * gate;
    }
  }
}

__global__ __launch_bounds__(256) void k_combine_lvl(
    const float* __restrict__ Alog, const float* __restrict__ hloc,
    const float* __restrict__ Ssum, float* __restrict__ hin) {
  int i = blockIdx.x * 256 + threadIdx.x;   // 16384
  int n = i & 15, d = (i >> 4) & 127, lvl = (i >> 11) & 3, b = i >> 13;
  float kA2 = -__expf(Alog[(lvl * 128 + d) * 16 + n]) * LOG2E;
  float h = 0.f;
  int nch = NCH4[lvl];
  for (int ch = 0; ch < nch; ++ch) {
    int gc = CHOFF4[lvl] + ch;
    size_t ix = (((size_t)(b * NCHL) + gc) * 128 + d) * 16 + n;
    hin[ix] = h;
    float S = Ssum[((size_t)(b * NCHL) + gc) * 128 + d];
    h = fmaf(exp2f(kA2 * S), h, hloc[ix]);
  }
}

__global__ __launch_bounds__(256) void k_combine_cr(
    const float* __restrict__ Alog, const float* __restrict__ hloc,
    const float* __restrict__ Ssum, float* __restrict__ hin) {
  int i = blockIdx.x * 256 + threadIdx.x;   // 16384
  int n = i & 15, d = (i >> 4) & 511, b = i >> 13;
  float kA2 = -__expf(Alog[d * 16 + n]) * LOG2E;
  float h = 0.f;
  for (int ch = 0; ch < NCHC; ++ch) {
    size_t ix = (((size_t)(b * NCHC) + ch) * 512 + d) * 16 + n;
    hin[ix] = h;
    float S = Ssum[((size_t)(b * NCHC) + ch) * 512 + d];
    h = fmaf(exp2f(kA2 * S), h, hloc[ix]);
  }
}

// --------------- level out-GEMM + residual, store (B,C,L) CHW ----------------
__global__ __launch_bounds__(256) void k_out_lvl(
    const float* __restrict__ yg_l, const float* __restrict__ Wout, // (4,128,64)
    const float* __restrict__ f0, const float* __restrict__ f1,
    const float* __restrict__ f2, const float* __restrict__ f3,
    float* __restrict__ fout) {
  __shared__ float s_yg[16 * 128];
  __shared__ float s_o[16 * 64];
  int bid = blockIdx.x;  // B*NTT
  int b = bid / NTT, t = bid - b * NTT;
  int lvl = 0;
  while (lvl < 3 && t >= TOFF4[lvl + 1]) ++lvl;
  int tl = t - TOFF4[lvl];
  int L = L4[lvl], loff = LOFF4[lvl];
  int l0 = tl * 16, nl = min(16, L - l0);
  const float* fx = lvl == 0 ? f0 : lvl == 1 ? f1 : lvl == 2 ? f2 : f3;
  int tid = threadIdx.x;
  for (int i = tid; i < 16 * 128; i += 256) {
    int l = i >> 7, d = i & 127;
    s_yg[i] = (l < nl) ? yg_l[((size_t)(b * LTOT) + loff + l0 + l) * 128 + d] : 0.f;
  }
  __syncthreads();
  {
    int c = tid & 63, lg = (tid >> 6) * 4;
    float acc[4] = {0.f, 0.f, 0.f, 0.f};
    const float* W = Wout + lvl * 128 * 64 + c;
    for (int dq = 0; dq < 128; ++dq) {
      float w = W[dq * 64];
#pragma unroll
      for (int a = 0; a < 4; ++a)
        acc[a] = fmaf(w, s_yg[(lg + a) * 128 + dq], acc[a]);
    }
#pragma unroll
    for (int a = 0; a < 4; ++a) s_o[(lg + a) * 64 + c] = acc[a];
  }
  __syncthreads();
  for (int i = tid; i < 16 * 64; i += 256) {
    int c = i >> 4, l = i & 15;
    if (l < nl)
      fout[((size_t)(b * 64) + c) * LTOT + loff + l0 + l] =
          s_o[l * 64 + c] + fx[((size_t)(b * 64) + c) * L + l0 + l];
  }
}

// --------------------------- bilinear resize + concat ------------------------
__global__ __launch_bounds__(256) void k_resize(const float* __restrict__ fout,
                                                float* __restrict__ xcat) {
  int i = blockIdx.x * 256 + threadIdx.x;   // B*256*2304
  int hw = i % 2304;
  int rem = i / 2304;
  int ch = rem & 255;
  int b = rem >> 8;
  int oh = hw / 48, ow = hw - oh * 48;
  int lvl = ch >> 6, c = ch & 63;
  int s = S4[lvl];
  const float* base = fout + ((size_t)(b * 64) + c) * LTOT + LOFF4[lvl];
  float scl = (float)(s - 1) * (1.f / 47.f);
  float fy = oh * scl, fxx = ow * scl;
  int y0 = (int)floorf(fy), x0 = (int)floorf(fxx);
  float wy = fy - y0, wx = fxx - x0;
  int y1 = min(y0 + 1, s - 1), x1 = min(x0 + 1, s - 1);
  float v00 = base[y0 * s + x0], v01 = base[y0 * s + x1];
  float v10 = base[y1 * s + x0], v11 = base[y1 * s + x1];
  float top = v00 * (1.f - wx) + v01 * wx;
  float bot = v10 * (1.f - wx) + v11 * wx;
  xcat[i] = top * (1.f - wy) + bot * wy;
}

// ------------------- cross input GEMM: xcat @ cr_Win -------------------------
__global__ __launch_bounds__(256) void k_gemm_in_cr(
    const float* __restrict__ xcat,  // (B,256,2304)
    const float* __restrict__ Win,   // (256,1024)
    float* __restrict__ xs_c, float* __restrict__ z_c) {
  __shared__ __align__(16) float s_x[256 * 16];
  int bid = blockIdx.x;  // B*144*4
  int jb = bid & 3;
  int rem = bid >> 2;
  int tl = rem % 144, b = rem / 144;
  int l0 = tl * 16;
  int tid = threadIdx.x;
  for (int i = tid; i < 256 * 16; i += 256) {
    int c = i >> 4, l = i & 15;
    s_x[i] = xcat[((size_t)(b * 256) + c) * LC + l0 + l];
  }
  __syncthreads();
  int j0 = jb * 256 + (tid & 63) * 4;
  int lg = (tid >> 6) * 4;
  float acc[4][4];
#pragma unroll
  for (int a = 0; a < 4; ++a)
#pragma unroll
    for (int q = 0; q < 4; ++q) acc[a][q] = 0.f;
#pragma unroll 2
  for (int c = 0; c < 256; ++c) {
    float4 wv = *(const float4*)&Win[c * 1024 + j0];
    float4 xv = *(const float4*)&s_x[c * 16 + lg];
    float w[4] = {wv.x, wv.y, wv.z, wv.w};
    float xr[4] = {xv.x, xv.y, xv.z, xv.w};
#pragma unroll
    for (int a = 0; a < 4; ++a)
#pragma unroll
      for (int q = 0; q < 4; ++q) acc[a][q] = fmaf(xr[a], w[q], acc[a][q]);
  }
  bool is_z = (j0 >= 512);
#pragma unroll
  for (int a = 0; a < 4; ++a) {
    int l = l0 + lg + a;
    float4 v;
    v.x = acc[a][0]; v.y = acc[a][1]; v.z = acc[a][2]; v.w = acc[a][3];
    if (!is_z)
      *(float4*)&xs_c[((size_t)(b * LC) + l) * 512 + j0] = v;
    else
      *(float4*)&z_c[((size_t)(b * LC) + l) * 512 + (j0 - 512)] = v;
  }
}

// ------------- cross mid: conv + silu + dbc + dt (tile of 8 l) ---------------
__global__ __launch_bounds__(256) void k_mid_cr(
    const float* __restrict__ xs_c,   // (B,2304,512)
    const float* __restrict__ Wconv,  // (512,4)
    const float* __restrict__ bconv, const float* __restrict__ Wx, // (512,48)
    const float* __restrict__ Wdt,    // (16,512)
    const float* __restrict__ bdt, float* __restrict__ u_c,
    float* __restrict__ dt_c, float* __restrict__ bc_c) {
  __shared__ float s_xs[11 * 512];
  __shared__ float s_u[8 * 516];
  __shared__ float s_dbc[8 * 48];
  int bid = blockIdx.x;  // B*288
  int b = bid / 288, tl = bid - b * 288;
  int l0 = tl * 8;
  int tid = threadIdx.x;
  for (int i = tid; i < 11 * 512; i += 256) {
    int r = i >> 9, d = i & 511;
    int l = l0 - 3 + r;
    s_xs[i] = (l >= 0) ? xs_c[((size_t)(b * LC) + l) * 512 + d] : 0.f;
  }
  __syncthreads();
  for (int i = tid; i < 8 * 512; i += 256) {
    int l = i >> 9, d = i & 511;
    const float* wc = Wconv + d * 4;
    float a = bconv[d];
#pragma unroll
    for (int k = 0; k < 4; ++k) a = fmaf(wc[k], s_xs[(l + k) * 512 + d], a);
    float uu = siluf(a);
    s_u[l * 516 + d] = uu;
    u_c[((size_t)(b * LC) + l0 + l) * 512 + d] = uu;
  }
  __syncthreads();
  for (int i = tid; i < 8 * 48; i += 256) {
    int jj = i >> 3, l = i & 7;
    const float* wx = Wx + jj;
    float a = 0.f;
    for (int d = 0; d < 512; ++d) a = fmaf(s_u[l * 516 + d], wx[d * 48], a);
    s_dbc[l * 48 + jj] = a;
    if (jj >= 16) bc_c[((size_t)(b * LC) + l0 + l) * 32 + (jj - 16)] = a;
  }
  __syncthreads();
  for (int i = tid; i < 8 * 512; i += 256) {
    int l = i >> 9, d = i & 511;
    float a = bdt[d];
#pragma unroll
    for (int r = 0; r < 16; ++r)
      a = fmaf(s_dbc[l * 48 + r], Wdt[r * 512 + d], a);
    dt_c[((size_t)(b * LC) + l0 + l) * 512 + d] = softplusf(a);
  }
}

// --- final: out = relu(BN(projW @ (xcat + yg_c@Wout) + proj_b)), fused -------
__global__ __launch_bounds__(256) void k_final(
    const float* __restrict__ xcat, const float* __restrict__ yg_c,
    const float* __restrict__ Wt, const float* __restrict__ WP,
    const float* __restrict__ pb, const float* __restrict__ bng,
    const float* __restrict__ bnb, const float* __restrict__ bnm,
    const float* __restrict__ bnv, float* __restrict__ out) {
  __shared__ float s_xc[256 * 16];
  __shared__ float s_yg[16 * 512];
  int bid = blockIdx.x;  // B*144
  int b = bid / 144, tl = bid - b * 144;
  int l0 = tl * 16;
  int tid = threadIdx.x;
  for (int i = tid; i < 256 * 16; i += 256) {
    int c = i >> 4, l = i & 15;
    s_xc[i] = xcat[((size_t)(b * 256) + c) * LC + l0 + l];
  }
  for (int i = tid; i < 16 * 512; i += 256) {
    int l = i >> 9, d = i & 511;
    s_yg[i] = yg_c[((size_t)(b * LC) + l0 + l) * 512 + d];
  }
  __syncthreads();
  int o = tid & 63, lg = (tid >> 6) * 4;
  float acc[4] = {0.f, 0.f, 0.f, 0.f};
  for (int c = 0; c < 256; ++c) {
    float w = Wt[c * 64 + o];
#pragma unroll
    for (int a = 0; a < 4; ++a) acc[a] = fmaf(w, s_xc[c * 16 + lg + a], acc[a]);
  }
  for (int d = 0; d < 512; ++d) {
    float w = WP[d * 64 + o];
#pragma unroll
    for (int a = 0; a < 4; ++a) acc[a] = fmaf(w, s_yg[(lg + a) * 512 + d], acc[a]);
  }
  float bias = pb[o], m = bnm[o], g = bng[o], v = bnv[o], bb = bnb[o];
  float scl = g * (1.f / sqrtf(v + 1e-5f));
  float4 r;
  {
    float y0 = (acc[0] + bias - m) * scl + bb;
    float y1 = (acc[1] + bias - m) * scl + bb;
    float y2 = (acc[2] + bias - m) * scl + bb;
    float y3 = (acc[3] + bias - m) * scl + bb;
    r.x = fmaxf(y0, 0.f); r.y = fmaxf(y1, 0.f);
    r.z = fmaxf(y2, 0.f); r.w = fmaxf(y3, 0.f);
  }
  *(float4*)&out[((size_t)(b * 64) + o) * LC + l0 + lg] = r;
}

// -----------------------------------------------------------------------------
extern "C" void kernel_launch(void* const* d_in, const int* in_sizes, int n_in,
                              void* d_out, int out_size, void* d_ws,
                              size_t ws_size, hipStream_t stream) {
  (void)in_sizes; (void)n_in; (void)out_size; (void)ws_size;
  const float* f0 = (const float*)d_in[0];
  const float* f1 = (const float*)d_in[1];
  const float* f2 = (const float*)d_in[2];
  const float* f3 = (const float*)d_in[3];
  const float* lWin   = (const float*)d_in[4];
  const float* lWconv = (const float*)d_in[5];
  const float* lbconv = (const float*)d_in[6];
  const float* lWx    = (const float*)d_in[7];
  const float* lWdt   = (const float*)d_in[8];
  const float* lbdt   = (const float*)d_in[9];
  const float* lAlog  = (const float*)d_in[10];
  const float* lD     = (const float*)d_in[11];
  const float* lWout  = (const float*)d_in[12];
  const float* cWin   = (const float*)d_in[13];
  const float* cWconv = (const float*)d_in[14];
  const float* cbconv = (const float*)d_in[15];
  const float* cWx    = (const float*)d_in[16];
  const float* cWdt   = (const float*)d_in[17];
  const float* cbdt   = (const float*)d_in[18];
  const float* cAlog  = (const float*)d_in[19];
  const float* cD     = (const float*)d_in[20];
  const float* cWout  = (const float*)d_in[21];
  const float* projW  = (const float*)d_in[22];
  const float* projb  = (const float*)d_in[23];
  const float* bng    = (const float*)d_in[24];
  const float* bnb    = (const float*)d_in[25];
  const float* bnm    = (const float*)d_in[26];
  const float* bnv    = (const float*)d_in[27];
  float* out = (float*)d_out;

  float* ws = (float*)d_ws;
  size_t off = 0;
  auto alloc = [&](size_t n) { float* p = ws + off; off += n; return p; };
  float* Wt     = alloc(256 * 64);
  float* WP     = alloc(512 * 64);
  float* u_l    = alloc((size_t)B_ * LTOT * 128);
  float* dt_l   = alloc((size_t)B_ * LTOT * 128);
  float* z_l    = alloc((size_t)B_ * LTOT * 128);
  float* bc_l   = alloc((size_t)B_ * LTOT * 32);
  float* yg_l   = alloc((size_t)B_ * LTOT * 128);
  float* fout   = alloc((size_t)B_ * 64 * LTOT);
  float* xcat   = alloc((size_t)B_ * 256 * LC);
  float* xs_c   = alloc((size_t)B_ * LC * 512);
  float* z_c    = alloc((size_t)B_ * LC * 512);
  float* u_c    = alloc((size_t)B_ * LC * 512);
  float* dt_c   = alloc((size_t)B_ * LC * 512);
  float* bc_c   = alloc((size_t)B_ * LC * 32);
  float* yg_c   = alloc((size_t)B_ * LC * 512);
  float* hloc_l = alloc((size_t)B_ * NCHL * 128 * 16);
  float* S_l    = alloc((size_t)B_ * NCHL * 128);
  float* hin_l  = alloc((size_t)B_ * NCHL * 128 * 16);
  float* hloc_c = alloc((size_t)B_ * NCHC * 512 * 16);
  float* S_c    = alloc((size_t)B_ * NCHC * 512);
  float* hin_c  = alloc((size_t)B_ * NCHC * 512 * 16);

  k_prep1<<<64, 256, 0, stream>>>(projW, Wt);
  k_prep2<<<128, 256, 0, stream>>>(cWout, Wt, WP);

  k_front_lvl<<<B_ * NTT, 256, 0, stream>>>(f0, f1, f2, f3, lWin, lWconv,
                                            lbconv, lWx, lWdt, lbdt, u_l, dt_l,
                                            bc_l, z_l);

  k_scan<0, 0><<<B_ * 8 * NCHL, 256, 3 * 2048 * 4, stream>>>(
      dt_l, u_l, bc_l, nullptr, lAlog, lD, hloc_l, S_l, nullptr, nullptr);
  k_combine_lvl<<<64, 256, 0, stream>>>(lAlog, hloc_l, S_l, hin_l);
  k_scan<0, 1><<<B_ * 8 * NCHL, 256, 6 * 2048 * 4, stream>>>(
      dt_l, u_l, bc_l, z_l, lAlog, lD, nullptr, nullptr, hin_l, yg_l);

  k_out_lvl<<<B_ * NTT, 256, 0, stream>>>(yg_l, lWout, f0, f1, f2, f3, fout);
  k_resize<<<(B_ * 256 * LC) / 256, 256, 0, stream>>>(fout, xcat);

  k_gemm_in_cr<<<B_ * 144 * 4, 256, 0, stream>>>(xcat, cWin, xs_c, z_c);
  k_mid_cr<<<B_ * 288, 256, 0, stream>>>(xs_c, cWconv, cbconv, cWx, cWdt, cbdt,
                                         u_c, dt_c, bc_c);

  k_scan<1, 0><<<B_ * 32 * NCHC, 256, 3 * 2048 * 4, stream>>>(
      dt_c, u_c, bc_c, nullptr, cAlog, cD, hloc_c, S_c, nullptr, nullptr);
  k_combine_cr<<<64, 256, 0, stream>>>(cAlog, hloc_c, S_c, hin_c);
  k_scan<1, 1><<<B_ * 32 * NCHC, 256, 6 * 2048 * 4, stream>>>(
      dt_c, u_c, bc_c, z_c, cAlog, cD, nullptr, nullptr, hin_c, yg_c);

  k_final<<<B_ * 144, 256, 0, stream>>>(xcat, yg_c, Wt, WP, projb, bng, bnb,
                                        bnm, bnv, out);
}

// Round 2
// 398.118 us; speedup vs baseline: 1.0823x; 1.0823x over previous
//
#include <hip/hip_runtime.h>
#include <cmath>

#define DEV __device__ __forceinline__

typedef unsigned short u16;
typedef u16 u16x8 __attribute__((ext_vector_type(8)));
typedef u16 u16x4 __attribute__((ext_vector_type(4)));

constexpr int B_ = 2;
constexpr int S4[4]    = {48, 24, 12, 6};
constexpr int L4[4]    = {2304, 576, 144, 36};
constexpr int LOFF4[4] = {0, 2304, 2880, 3024};
constexpr int LTOT = 3060;
constexpr int TOFF4[4] = {0, 144, 180, 189};
constexpr int NTT = 192;
constexpr int NCH4[4]   = {36, 9, 3, 1};      // ceil(L/64)
constexpr int CHOFF4[4] = {0, 36, 45, 48};
constexpr int NCHL = 49;
constexpr int NCHC = 36;
constexpr int LC = 2304;
constexpr float LOG2E = 1.44269504088896f;

DEV float siluf(float x) { return x / (1.f + __expf(-x)); }
DEV float softplusf(float x) { return fmaxf(x, 0.f) + log1pf(__expf(-fabsf(x))); }
DEV float b2f(u16 x) { union { float f; unsigned u; } v; v.u = ((unsigned)x) << 16; return v.f; }
DEV u16 f2b(float f) {
  union { float f; unsigned u; } v; v.f = f;
  unsigned r = v.u + 0x7fffu + ((v.u >> 16) & 1u);
  return (u16)(r >> 16);
}

// ---------------- prep: Wt = projW^T ; WP = cr_Wout @ projW^T ----------------
__global__ __launch_bounds__(256) void k_prep1(const float* __restrict__ projW,
                                               float* __restrict__ Wt) {
  int i = blockIdx.x * 256 + threadIdx.x;   // 16384
  int o = i >> 8, c = i & 255;
  Wt[c * 64 + o] = projW[o * 256 + c];
}

__global__ __launch_bounds__(256) void k_prep2(const float* __restrict__ crWout,
                                               const float* __restrict__ Wt,
                                               float* __restrict__ WP) {
  int i = blockIdx.x * 256 + threadIdx.x;   // 32768
  int d = i >> 6, o = i & 63;
  float acc = 0.f;
#pragma unroll 4
  for (int c = 0; c < 256; ++c)
    acc = fmaf(crWout[d * 256 + c], Wt[c * 64 + o], acc);
  WP[d * 64 + o] = acc;
}

// ------------- level front: in-GEMM + conv + silu + dbc + dt (fused) ---------
__global__ __launch_bounds__(256) void k_front_lvl(
    const float* __restrict__ f0, const float* __restrict__ f1,
    const float* __restrict__ f2, const float* __restrict__ f3,
    const float* __restrict__ Win,   // (4,64,256)
    const float* __restrict__ Wconv, // (4,128,4)
    const float* __restrict__ bconv, // (4,128)
    const float* __restrict__ Wx,    // (4,128,36)
    const float* __restrict__ Wdt,   // (4,4,128)
    const float* __restrict__ bdt,   // (4,128)
    u16* __restrict__ u_l, u16* __restrict__ dt_l,
    u16* __restrict__ Bm_l, u16* __restrict__ Cm_l, u16* __restrict__ z_l) {
  __shared__ float s_x[64 * 20];
  __shared__ float s_xs[19 * 128];
  __shared__ float s_u[16 * 132];
  __shared__ float s_dbc[16 * 36];
  int bid = blockIdx.x;              // B*NTT
  int b = bid / NTT, t = bid - b * NTT;
  int lvl = 0;
  while (lvl < 3 && t >= TOFF4[lvl + 1]) ++lvl;
  int tl = t - TOFF4[lvl];
  int L = L4[lvl], loff = LOFF4[lvl];
  int l0 = tl * 16;
  int nl = min(16, L - l0);
  const float* fx = lvl == 0 ? f0 : lvl == 1 ? f1 : lvl == 2 ? f2 : f3;
  int tid = threadIdx.x;

  for (int i = tid; i < 64 * 20; i += 256) {
    int c = i / 20, r = i - c * 20;
    int l = l0 - 3 + r;
    float v = 0.f;
    if (r < 19 && l >= 0 && l < L) v = fx[(size_t)(b * 64 + c) * L + l];
    s_x[i] = v;
  }
  __syncthreads();
  {  // xz GEMM: 19 rows x 256 cols, K=64
    int j = tid;
    float acc[19];
#pragma unroll
    for (int r = 0; r < 19; ++r) acc[r] = 0.f;
    const float* W = Win + lvl * 64 * 256 + j;
    for (int c = 0; c < 64; ++c) {
      float w = W[c * 256];
#pragma unroll
      for (int r = 0; r < 19; ++r) acc[r] = fmaf(w, s_x[c * 20 + r], acc[r]);
    }
    if (j < 128) {
#pragma unroll
      for (int r = 0; r < 19; ++r) s_xs[r * 128 + j] = acc[r];
    } else {
      int d = j - 128;
      int dti = d >> 4, jj = d & 15;
      for (int r = 3; r < 19; ++r) {
        int l = l0 - 3 + r;
        if (l < l0 + nl)
          z_l[((size_t)(b * 8 + dti) * LTOT + loff + l) * 16 + jj] = f2b(acc[r]);
      }
    }
  }
  __syncthreads();
  for (int i = tid; i < 16 * 128; i += 256) {
    int l = i >> 7, d = i & 127;
    if (l < nl) {
      const float* wc = Wconv + (lvl * 128 + d) * 4;
      float a = bconv[lvl * 128 + d];
#pragma unroll
      for (int k = 0; k < 4; ++k) a = fmaf(wc[k], s_xs[(l + k) * 128 + d], a);
      float uu = siluf(a);
      s_u[l * 132 + d] = uu;
      u_l[((size_t)(b * 8 + (d >> 4)) * LTOT + loff + l0 + l) * 16 + (d & 15)] = f2b(uu);
    }
  }
  __syncthreads();
  for (int i = tid; i < 16 * 36; i += 256) {
    int l = i & 15, jj = i >> 4;
    if (l < nl) {
      const float* wx = Wx + lvl * 128 * 36 + jj;
      float a = 0.f;
      for (int d = 0; d < 128; ++d) a = fmaf(s_u[l * 132 + d], wx[d * 36], a);
      s_dbc[l * 36 + jj] = a;
      if (jj >= 4) {
        int q = jj - 4;
        size_t gb = ((size_t)(b * LTOT) + loff + l0 + l) * 16;
        if (q < 16) Bm_l[gb + q] = f2b(a);
        else        Cm_l[gb + (q - 16)] = f2b(a);
      }
    }
  }
  __syncthreads();
  for (int i = tid; i < 16 * 128; i += 256) {
    int l = i >> 7, d = i & 127;
    if (l < nl) {
      float a = bdt[lvl * 128 + d];
#pragma unroll
      for (int r = 0; r < 4; ++r)
        a = fmaf(s_dbc[l * 36 + r], Wdt[(lvl * 4 + r) * 128 + d], a);
      dt_l[((size_t)(b * 8 + (d >> 4)) * LTOT + loff + l0 + l) * 16 + (d & 15)] =
          f2b(softplusf(a));
    }
  }
}

// ----------------------------- chunked scan (CH=64) --------------------------
// MODE 0 = levels (DI=128), MODE 1 = cross (DI=512). PASSC: emit gated y.
template <int MODE, int PASSC>
__global__ __launch_bounds__(256) void k_scan(
    const u16* __restrict__ dtb, const u16* __restrict__ ub,
    const u16* __restrict__ Bmb, const u16* __restrict__ Cmb,
    const u16* __restrict__ zb,
    const float* __restrict__ Alog, const float* __restrict__ Dsk,
    float* __restrict__ hloc, float* __restrict__ Ssum,
    const float* __restrict__ hin, u16* __restrict__ yg) {
  constexpr int DI = MODE ? 512 : 128;
  constexpr int NDT = DI / 16;
  constexpr int NCHT = MODE ? NCHC : NCHL;
  constexpr int LT = MODE ? LC : LTOT;
  constexpr int NARR = PASSC ? 5 : 3;
  __shared__ __align__(16) u16 smem[NARR * 1024];
  u16* s_dt = smem;
  u16* s_u = smem + 1024;
  u16* s_B = smem + 2048;
  u16* s_C = PASSC ? smem + 3072 : nullptr;
  u16* s_y = PASSC ? smem + 4096 : nullptr;

  int bid = blockIdx.x;
  int dti = bid % NDT;
  int rem = bid / NDT;
  int gc = rem % NCHT;
  int b = rem / NCHT;
  int lvl = 0, ch = gc, Lq = LC, loff = 0;
  if (MODE == 0) {
    while (lvl < 3 && gc >= CHOFF4[lvl + 1]) ++lvl;
    ch = gc - CHOFF4[lvl];
    Lq = L4[lvl];
    loff = LOFF4[lvl];
  }
  int l0 = ch * 64;
  int len = min(64, Lq - l0);
  int labs0 = loff + l0;
  int tid = threadIdx.x;
  int n = tid & 15, dd = tid >> 4;
  int d = dti * 16 + dd;

  size_t base2 = ((size_t)(b * NDT + dti) * LT + labs0) * 16;
  size_t baseB = ((size_t)b * LT + labs0) * 16;
  {
    int nv = len * 2;   // ushort8 vectors per array
    const u16x8* pdt = (const u16x8*)(dtb + base2);
    const u16x8* pu  = (const u16x8*)(ub + base2);
    const u16x8* pB  = (const u16x8*)(Bmb + baseB);
    u16x8* qdt = (u16x8*)s_dt;
    u16x8* qu  = (u16x8*)s_u;
    u16x8* qB  = (u16x8*)s_B;
    for (int i = tid; i < nv; i += 256) {
      qdt[i] = pdt[i];
      qu[i]  = pu[i];
      qB[i]  = pB[i];
    }
    if (PASSC) {
      const u16x8* pC = (const u16x8*)(Cmb + baseB);
      u16x8* qC = (u16x8*)s_C;
      for (int i = tid; i < nv; i += 256) qC[i] = pC[i];
    }
  }
  __syncthreads();

  int ai = (MODE ? d : lvl * 128 + d);
  float kA2 = -__expf(Alog[ai * 16 + n]) * LOG2E;
  size_t hix = (((size_t)(b * NCHT) + gc) * DI + d) * 16 + n;
  float h = 0.f, ss = 0.f;
  if (PASSC) h = hin[hix];
  float dsk = PASSC ? Dsk[ai] : 0.f;

  for (int l = 0; l < len; ++l) {
    float dt = b2f(s_dt[l * 16 + dd]);
    float uu = b2f(s_u[l * 16 + dd]);
    float bm = b2f(s_B[l * 16 + n]);
    float dA = exp2f(kA2 * dt);
    h = fmaf(dA, h, dt * uu * bm);
    if (PASSC) {
      float p = h * b2f(s_C[l * 16 + n]);
      p += __shfl_xor(p, 1, 16);
      p += __shfl_xor(p, 2, 16);
      p += __shfl_xor(p, 4, 16);
      p += __shfl_xor(p, 8, 16);
      if (n == 0) s_y[l * 16 + dd] = f2b(fmaf(uu, dsk, p));
    } else {
      ss += dt;
    }
  }
  if (!PASSC) {
    hloc[hix] = h;
    if (n == 0) Ssum[((size_t)(b * NCHT) + gc) * DI + d] = ss;
  } else {
    __syncthreads();
    for (int i = tid; i < len * 16; i += 256) {
      float z = b2f(zb[base2 + i]);
      float gate = z / (1.f + __expf(-z));
      yg[base2 + i] = f2b(b2f(s_y[i]) * gate);
    }
  }
}

__global__ __launch_bounds__(256) void k_combine_lvl(
    const float* __restrict__ Alog, const float* __restrict__ hloc,
    const float* __restrict__ Ssum, float* __restrict__ hin) {
  int i = blockIdx.x * 256 + threadIdx.x;   // 16384
  int n = i & 15, d = (i >> 4) & 127, lvl = (i >> 11) & 3, b = i >> 13;
  float kA2 = -__expf(Alog[(lvl * 128 + d) * 16 + n]) * LOG2E;
  float h = 0.f;
  int nch = NCH4[lvl];
  for (int ch = 0; ch < nch; ++ch) {
    int gc = CHOFF4[lvl] + ch;
    size_t ix = (((size_t)(b * NCHL) + gc) * 128 + d) * 16 + n;
    hin[ix] = h;
    float S = Ssum[((size_t)(b * NCHL) + gc) * 128 + d];
    h = fmaf(exp2f(kA2 * S), h, hloc[ix]);
  }
}

__global__ __launch_bounds__(256) void k_combine_cr(
    const float* __restrict__ Alog, const float* __restrict__ hloc,
    const float* __restrict__ Ssum, float* __restrict__ hin) {
  int i = blockIdx.x * 256 + threadIdx.x;   // 16384
  int n = i & 15, d = (i >> 4) & 511, b = i >> 13;
  float kA2 = -__expf(Alog[d * 16 + n]) * LOG2E;
  float h = 0.f;
  for (int ch = 0; ch < NCHC; ++ch) {
    size_t ix = (((size_t)(b * NCHC) + ch) * 512 + d) * 16 + n;
    hin[ix] = h;
    float S = Ssum[((size_t)(b * NCHC) + ch) * 512 + d];
    h = fmaf(exp2f(kA2 * S), h, hloc[ix]);
  }
}

// --------------- level out-GEMM + residual, store (B,C,L) CHW ----------------
__global__ __launch_bounds__(256) void k_out_lvl(
    const u16* __restrict__ yg_l, const float* __restrict__ Wout, // (4,128,64)
    const float* __restrict__ f0, const float* __restrict__ f1,
    const float* __restrict__ f2, const float* __restrict__ f3,
    float* __restrict__ fout) {
  __shared__ float s_ygT[128 * 20];   // [d][l], stride 20
  __shared__ float s_o[16 * 64];
  int bid = blockIdx.x;  // B*NTT
  int b = bid / NTT, t = bid - b * NTT;
  int lvl = 0;
  while (lvl < 3 && t >= TOFF4[lvl + 1]) ++lvl;
  int tl = t - TOFF4[lvl];
  int L = L4[lvl], loff = LOFF4[lvl];
  int l0 = tl * 16, nl = min(16, L - l0);
  const float* fx = lvl == 0 ? f0 : lvl == 1 ? f1 : lvl == 2 ? f2 : f3;
  int tid = threadIdx.x;
  for (int i = tid; i < 16 * 128; i += 256) {
    int d = i & 127, l = i >> 7;
    float v = 0.f;
    if (l < nl)
      v = b2f(yg_l[((size_t)(b * 8 + (d >> 4)) * LTOT + loff + l0 + l) * 16 + (d & 15)]);
    s_ygT[d * 20 + l] = v;
  }
  __syncthreads();
  {
    int c = tid & 63, lg = (tid >> 6) * 4;
    float acc[4] = {0.f, 0.f, 0.f, 0.f};
    const float* W = Wout + lvl * 128 * 64 + c;
    for (int dq = 0; dq < 128; ++dq) {
      float w = W[dq * 64];
      float4 yv = *(const float4*)&s_ygT[dq * 20 + lg];
      acc[0] = fmaf(w, yv.x, acc[0]);
      acc[1] = fmaf(w, yv.y, acc[1]);
      acc[2] = fmaf(w, yv.z, acc[2]);
      acc[3] = fmaf(w, yv.w, acc[3]);
    }
#pragma unroll
    for (int a = 0; a < 4; ++a) s_o[(lg + a) * 64 + c] = acc[a];
  }
  __syncthreads();
  for (int i = tid; i < 16 * 64; i += 256) {
    int c = i >> 4, l = i & 15;
    if (l < nl)
      fout[((size_t)(b * 64) + c) * LTOT + loff + l0 + l] =
          s_o[l * 64 + c] + fx[((size_t)(b * 64) + c) * L + l0 + l];
  }
}

// --------------------------- bilinear resize + concat ------------------------
__global__ __launch_bounds__(256) void k_resize(const float* __restrict__ fout,
                                                float* __restrict__ xcat) {
  int i = blockIdx.x * 256 + threadIdx.x;   // B*256*2304
  int hw = i % 2304;
  int rem = i / 2304;
  int ch = rem & 255;
  int b = rem >> 8;
  int oh = hw / 48, ow = hw - oh * 48;
  int lvl = ch >> 6, c = ch & 63;
  int s = S4[lvl];
  const float* base = fout + ((size_t)(b * 64) + c) * LTOT + LOFF4[lvl];
  float scl = (float)(s - 1) * (1.f / 47.f);
  float fy = oh * scl, fxx = ow * scl;
  int y0 = (int)floorf(fy), x0 = (int)floorf(fxx);
  float wy = fy - y0, wx = fxx - x0;
  int y1 = min(y0 + 1, s - 1), x1 = min(x0 + 1, s - 1);
  float v00 = base[y0 * s + x0], v01 = base[y0 * s + x1];
  float v10 = base[y1 * s + x0], v11 = base[y1 * s + x1];
  float top = v00 * (1.f - wx) + v01 * wx;
  float bot = v10 * (1.f - wx) + v11 * wx;
  xcat[i] = top * (1.f - wy) + bot * wy;
}

// ------------------- cross input GEMM: xcat @ cr_Win -------------------------
__global__ __launch_bounds__(256) void k_gemm_in_cr(
    const float* __restrict__ xcat,  // (B,256,2304)
    const float* __restrict__ Win,   // (256,1024)
    u16* __restrict__ xs_c, u16* __restrict__ z_c) {
  __shared__ __align__(16) float s_x[256 * 16];
  int bid = blockIdx.x;  // B*144*4
  int jb = bid & 3;
  int rem = bid >> 2;
  int tl = rem % 144, b = rem / 144;
  int l0 = tl * 16;
  int tid = threadIdx.x;
  for (int i = tid; i < 256 * 16; i += 256) {
    int c = i >> 4, l = i & 15;
    s_x[i] = xcat[((size_t)(b * 256) + c) * LC + l0 + l];
  }
  __syncthreads();
  int j0 = jb * 256 + (tid & 63) * 4;
  int lg = (tid >> 6) * 4;
  float acc[4][4];
#pragma unroll
  for (int a = 0; a < 4; ++a)
#pragma unroll
    for (int q = 0; q < 4; ++q) acc[a][q] = 0.f;
#pragma unroll 2
  for (int c = 0; c < 256; ++c) {
    float4 wv = *(const float4*)&Win[c * 1024 + j0];
    float4 xv = *(const float4*)&s_x[c * 16 + lg];
    float w[4] = {wv.x, wv.y, wv.z, wv.w};
    float xr[4] = {xv.x, xv.y, xv.z, xv.w};
#pragma unroll
    for (int a = 0; a < 4; ++a)
#pragma unroll
      for (int q = 0; q < 4; ++q) acc[a][q] = fmaf(xr[a], w[q], acc[a][q]);
  }
  bool is_z = (j0 >= 512);
#pragma unroll
  for (int a = 0; a < 4; ++a) {
    int l = l0 + lg + a;
    u16x4 v;
    v.x = f2b(acc[a][0]); v.y = f2b(acc[a][1]);
    v.z = f2b(acc[a][2]); v.w = f2b(acc[a][3]);
    if (!is_z) {
      *(u16x4*)&xs_c[((size_t)(b * LC) + l) * 512 + j0] = v;
    } else {
      int dz = j0 - 512;
      *(u16x4*)&z_c[((size_t)(b * 32 + (dz >> 4)) * LC + l) * 16 + (dz & 15)] = v;
    }
  }
}

// ------------- cross mid: conv + silu + dbc + dt (tile of 8 l) ---------------
__global__ __launch_bounds__(256) void k_mid_cr(
    const u16* __restrict__ xs_c,    // (B,2304,512) bf16
    const float* __restrict__ Wconv, // (512,4)
    const float* __restrict__ bconv, const float* __restrict__ Wx, // (512,48)
    const float* __restrict__ Wdt,   // (16,512)
    const float* __restrict__ bdt, u16* __restrict__ u_c,
    u16* __restrict__ dt_c, u16* __restrict__ Bm_c, u16* __restrict__ Cm_c) {
  __shared__ __align__(16) u16 s_xs[11 * 512];
  __shared__ float s_u[8 * 516];
  __shared__ float s_dbc[8 * 48];
  int bid = blockIdx.x;  // B*288
  int b = bid / 288, tl = bid - b * 288;
  int l0 = tl * 8;
  int tid = threadIdx.x;
  for (int i = tid; i < 704; i += 256) {  // 11*512/8 ushort8 vectors
    int r = i >> 6;
    int l = l0 - 3 + r;
    u16x8 v = {0, 0, 0, 0, 0, 0, 0, 0};
    if (l >= 0)
      v = *(const u16x8*)&xs_c[((size_t)(b * LC) + l) * 512 + (i & 63) * 8];
    *(u16x8*)&s_xs[i * 8] = v;
  }
  __syncthreads();
  for (int i = tid; i < 8 * 512; i += 256) {
    int l = i >> 9, d = i & 511;
    const float* wc = Wconv + d * 4;
    float a = bconv[d];
#pragma unroll
    for (int k = 0; k < 4; ++k) a = fmaf(wc[k], b2f(s_xs[(l + k) * 512 + d]), a);
    float uu = siluf(a);
    s_u[l * 516 + d] = uu;
    u_c[((size_t)(b * 32 + (d >> 4)) * LC + l0 + l) * 16 + (d & 15)] = f2b(uu);
  }
  __syncthreads();
  for (int i = tid; i < 8 * 48; i += 256) {
    int jj = i >> 3, l = i & 7;
    const float* wx = Wx + jj;
    float a = 0.f;
    for (int d = 0; d < 512; ++d) a = fmaf(s_u[l * 516 + d], wx[d * 48], a);
    s_dbc[l * 48 + jj] = a;
    if (jj >= 16) {
      int q = jj - 16;
      size_t gb = ((size_t)(b * LC) + l0 + l) * 16;
      if (q < 16) Bm_c[gb + q] = f2b(a);
      else        Cm_c[gb + (q - 16)] = f2b(a);
    }
  }
  __syncthreads();
  for (int i = tid; i < 8 * 512; i += 256) {
    int l = i >> 9, d = i & 511;
    float a = bdt[d];
#pragma unroll
    for (int r = 0; r < 16; ++r)
      a = fmaf(s_dbc[l * 48 + r], Wdt[r * 512 + d], a);
    dt_c[((size_t)(b * 32 + (d >> 4)) * LC + l0 + l) * 16 + (d & 15)] =
        f2b(softplusf(a));
  }
}

// --- final: out = relu(BN(projW @ (xcat + yg_c@Wout) + proj_b)), fused -------
__global__ __launch_bounds__(256) void k_final(
    const float* __restrict__ xcat, const u16* __restrict__ yg_c,
    const float* __restrict__ Wt, const float* __restrict__ WP,
    const float* __restrict__ pb, const float* __restrict__ bng,
    const float* __restrict__ bnb, const float* __restrict__ bnm,
    const float* __restrict__ bnv, float* __restrict__ out) {
  __shared__ float s_xc[256 * 16];
  __shared__ float s_ygT[512 * 20];   // [d][l], stride 20
  int bid = blockIdx.x;  // B*144
  int b = bid / 144, tl = bid - b * 144;
  int l0 = tl * 16;
  int tid = threadIdx.x;
  for (int i = tid; i < 256 * 16; i += 256) {
    int c = i >> 4, l = i & 15;
    s_xc[i] = xcat[((size_t)(b * 256) + c) * LC + l0 + l];
  }
  for (int i = tid; i < 16 * 512; i += 256) {
    int l = i >> 9, d = i & 511;
    s_ygT[d * 20 + l] =
        b2f(yg_c[((size_t)(b * 32 + (d >> 4)) * LC + l0 + l) * 16 + (d & 15)]);
  }
  __syncthreads();
  int o = tid & 63, lg = (tid >> 6) * 4;
  float acc[4] = {0.f, 0.f, 0.f, 0.f};
  for (int c = 0; c < 256; ++c) {
    float w = Wt[c * 64 + o];
    float4 xv = *(const float4*)&s_xc[c * 16 + lg];
    acc[0] = fmaf(w, xv.x, acc[0]);
    acc[1] = fmaf(w, xv.y, acc[1]);
    acc[2] = fmaf(w, xv.z, acc[2]);
    acc[3] = fmaf(w, xv.w, acc[3]);
  }
  for (int d = 0; d < 512; ++d) {
    float w = WP[d * 64 + o];
    float4 yv = *(const float4*)&s_ygT[d * 20 + lg];
    acc[0] = fmaf(w, yv.x, acc[0]);
    acc[1] = fmaf(w, yv.y, acc[1]);
    acc[2] = fmaf(w, yv.z, acc[2]);
    acc[3] = fmaf(w, yv.w, acc[3]);
  }
  float bias = pb[o], m = bnm[o], g = bng[o], v = bnv[o], bb = bnb[o];
  float scl = g * (1.f / sqrtf(v + 1e-5f));
  float4 r;
  r.x = fmaxf((acc[0] + bias - m) * scl + bb, 0.f);
  r.y = fmaxf((acc[1] + bias - m) * scl + bb, 0.f);
  r.z = fmaxf((acc[2] + bias - m) * scl + bb, 0.f);
  r.w = fmaxf((acc[3] + bias - m) * scl + bb, 0.f);
  *(float4*)&out[((size_t)(b * 64) + o) * LC + l0 + lg] = r;
}

// -----------------------------------------------------------------------------
extern "C" void kernel_launch(void* const* d_in, const int* in_sizes, int n_in,
                              void* d_out, int out_size, void* d_ws,
                              size_t ws_size, hipStream_t stream) {
  (void)in_sizes; (void)n_in; (void)out_size; (void)ws_size;
  const float* f0 = (const float*)d_in[0];
  const float* f1 = (const float*)d_in[1];
  const float* f2 = (const float*)d_in[2];
  const float* f3 = (const float*)d_in[3];
  const float* lWin   = (const float*)d_in[4];
  const float* lWconv = (const float*)d_in[5];
  const float* lbconv = (const float*)d_in[6];
  const float* lWx    = (const float*)d_in[7];
  const float* lWdt   = (const float*)d_in[8];
  const float* lbdt   = (const float*)d_in[9];
  const float* lAlog  = (const float*)d_in[10];
  const float* lD     = (const float*)d_in[11];
  const float* lWout  = (const float*)d_in[12];
  const float* cWin   = (const float*)d_in[13];
  const float* cWconv = (const float*)d_in[14];
  const float* cbconv = (const float*)d_in[15];
  const float* cWx    = (const float*)d_in[16];
  const float* cWdt   = (const float*)d_in[17];
  const float* cbdt   = (const float*)d_in[18];
  const float* cAlog  = (const float*)d_in[19];
  const float* cD     = (const float*)d_in[20];
  const float* cWout  = (const float*)d_in[21];
  const float* projW  = (const float*)d_in[22];
  const float* projb  = (const float*)d_in[23];
  const float* bng    = (const float*)d_in[24];
  const float* bnb    = (const float*)d_in[25];
  const float* bnm    = (const float*)d_in[26];
  const float* bnv    = (const float*)d_in[27];
  float* out = (float*)d_out;

  float* ws = (float*)d_ws;
  size_t off = 0;
  auto allocf = [&](size_t n) { float* p = ws + off; off += (n + 7) & ~(size_t)7; return p; };
  auto allocb = [&](size_t n) { u16* p = (u16*)(ws + off); off += ((n + 1) / 2 + 7) & ~(size_t)7; return p; };

  float* Wt     = allocf(256 * 64);
  float* WP     = allocf(512 * 64);
  float* fout   = allocf((size_t)B_ * 64 * LTOT);
  float* xcat   = allocf((size_t)B_ * 256 * LC);
  float* hloc_l = allocf((size_t)B_ * NCHL * 128 * 16);
  float* S_l    = allocf((size_t)B_ * NCHL * 128);
  float* hin_l  = allocf((size_t)B_ * NCHL * 128 * 16);
  float* hloc_c = allocf((size_t)B_ * NCHC * 512 * 16);
  float* S_c    = allocf((size_t)B_ * NCHC * 512);
  float* hin_c  = allocf((size_t)B_ * NCHC * 512 * 16);

  u16* u_l2  = allocb((size_t)B_ * 8 * LTOT * 16);
  u16* dt_l2 = allocb((size_t)B_ * 8 * LTOT * 16);
  u16* z_l2  = allocb((size_t)B_ * 8 * LTOT * 16);
  u16* yg_l2 = allocb((size_t)B_ * 8 * LTOT * 16);
  u16* Bm_l2 = allocb((size_t)B_ * LTOT * 16);
  u16* Cm_l2 = allocb((size_t)B_ * LTOT * 16);
  u16* xs_c2 = allocb((size_t)B_ * LC * 512);
  u16* u_c2  = allocb((size_t)B_ * 32 * LC * 16);
  u16* dt_c2 = allocb((size_t)B_ * 32 * LC * 16);
  u16* z_c2  = allocb((size_t)B_ * 32 * LC * 16);
  u16* yg_c2 = allocb((size_t)B_ * 32 * LC * 16);
  u16* Bm_c2 = allocb((size_t)B_ * LC * 16);
  u16* Cm_c2 = allocb((size_t)B_ * LC * 16);

  k_prep1<<<64, 256, 0, stream>>>(projW, Wt);
  k_prep2<<<128, 256, 0, stream>>>(cWout, Wt, WP);

  k_front_lvl<<<B_ * NTT, 256, 0, stream>>>(f0, f1, f2, f3, lWin, lWconv,
                                            lbconv, lWx, lWdt, lbdt, u_l2,
                                            dt_l2, Bm_l2, Cm_l2, z_l2);

  k_scan<0, 0><<<B_ * 8 * NCHL, 256, 0, stream>>>(
      dt_l2, u_l2, Bm_l2, Cm_l2, nullptr, lAlog, lD, hloc_l, S_l, nullptr,
      nullptr);
  k_combine_lvl<<<64, 256, 0, stream>>>(lAlog, hloc_l, S_l, hin_l);
  k_scan<0, 1><<<B_ * 8 * NCHL, 256, 0, stream>>>(
      dt_l2, u_l2, Bm_l2, Cm_l2, z_l2, lAlog, lD, nullptr, nullptr, hin_l,
      yg_l2);

  k_out_lvl<<<B_ * NTT, 256, 0, stream>>>(yg_l2, lWout, f0, f1, f2, f3, fout);
  k_resize<<<(B_ * 256 * LC) / 256, 256, 0, stream>>>(fout, xcat);

  k_gemm_in_cr<<<B_ * 144 * 4, 256, 0, stream>>>(xcat, cWin, xs_c2, z_c2);
  k_mid_cr<<<B_ * 288, 256, 0, stream>>>(xs_c2, cWconv, cbconv, cWx, cWdt,
                                         cbdt, u_c2, dt_c2, Bm_c2, Cm_c2);

  k_scan<1, 0><<<B_ * 32 * NCHC, 256, 0, stream>>>(
      dt_c2, u_c2, Bm_c2, Cm_c2, nullptr, cAlog, cD, hloc_c, S_c, nullptr,
      nullptr);
  k_combine_cr<<<64, 256, 0, stream>>>(cAlog, hloc_c, S_c, hin_c);
  k_scan<1, 1><<<B_ * 32 * NCHC, 256, 0, stream>>>(
      dt_c2, u_c2, Bm_c2, Cm_c2, z_c2, cAlog, cD, nullptr, nullptr, hin_c,
      yg_c2);

  k_final<<<B_ * 144, 256, 0, stream>>>(xcat, yg_c2, Wt, WP, projb, bng, bnb,
                                        bnm, bnv, out);
}

// Round 3
// 390.792 us; speedup vs baseline: 1.1026x; 1.0187x over previous
//
#include <hip/hip_runtime.h>
#include <cmath>

#define DEV __device__ __forceinline__

typedef unsigned short u16;
typedef u16 u16x8 __attribute__((ext_vector_type(8)));
typedef u16 u16x4 __attribute__((ext_vector_type(4)));

constexpr int B_ = 2;
constexpr int S4[4]    = {48, 24, 12, 6};
constexpr int L4[4]    = {2304, 576, 144, 36};
constexpr int LOFF4[4] = {0, 2304, 2880, 3024};
constexpr int LTOT = 3060;
constexpr int TOFF4[4] = {0, 144, 180, 189};
constexpr int NTT = 192;
constexpr int NCH4[4]   = {36, 9, 3, 1};      // ceil(L/64)
constexpr int CHOFF4[4] = {0, 36, 45, 48};
constexpr int NCHL = 49;
constexpr int NCHC = 36;
constexpr int LC = 2304;
constexpr float LOG2E = 1.44269504088896f;

DEV float siluf(float x) { return x / (1.f + __expf(-x)); }
DEV float softplusf(float x) { return fmaxf(x, 0.f) + log1pf(__expf(-fabsf(x))); }
DEV float b2f(u16 x) { union { float f; unsigned u; } v; v.u = ((unsigned)x) << 16; return v.f; }
DEV u16 f2b(float f) {
  union { float f; unsigned u; } v; v.f = f;
  unsigned r = v.u + 0x7fffu + ((v.u >> 16) & 1u);
  return (u16)(r >> 16);
}

// ------ prep: Wt = projW^T (blocks 0..63); WP = cr_Wout @ projW^T (64..191) --
__global__ __launch_bounds__(256) void k_prep(const float* __restrict__ projW,
                                              const float* __restrict__ crWout,
                                              float* __restrict__ Wt,
                                              float* __restrict__ WP) {
  int blk = blockIdx.x;
  if (blk < 64) {
    int i = blk * 256 + threadIdx.x;   // 16384
    int o = i >> 8, c = i & 255;
    Wt[c * 64 + o] = projW[o * 256 + c];
  } else {
    int i = (blk - 64) * 256 + threadIdx.x;   // 32768
    int d = i >> 6, o = i & 63;
    float acc = 0.f;
#pragma unroll 4
    for (int c = 0; c < 256; ++c)
      acc = fmaf(crWout[d * 256 + c], projW[o * 256 + c], acc);
    WP[d * 64 + o] = acc;
  }
}

// ------------- level front: in-GEMM + conv + silu + dbc + dt (fused) ---------
__global__ __launch_bounds__(256) void k_front_lvl(
    const float* __restrict__ f0, const float* __restrict__ f1,
    const float* __restrict__ f2, const float* __restrict__ f3,
    const float* __restrict__ Win,   // (4,64,256)
    const float* __restrict__ Wconv, // (4,128,4)
    const float* __restrict__ bconv, // (4,128)
    const float* __restrict__ Wx,    // (4,128,36)
    const float* __restrict__ Wdt,   // (4,4,128)
    const float* __restrict__ bdt,   // (4,128)
    u16* __restrict__ u_l, u16* __restrict__ dt_l,
    u16* __restrict__ Bm_l, u16* __restrict__ Cm_l, u16* __restrict__ z_l) {
  __shared__ float s_x[64 * 20];
  __shared__ float s_xs[19 * 128];
  __shared__ float s_u[16 * 132];
  __shared__ float s_dbc[16 * 36];
  int bid = blockIdx.x;              // B*NTT
  int b = bid / NTT, t = bid - b * NTT;
  int lvl = 0;
  while (lvl < 3 && t >= TOFF4[lvl + 1]) ++lvl;
  int tl = t - TOFF4[lvl];
  int L = L4[lvl], loff = LOFF4[lvl];
  int l0 = tl * 16;
  int nl = min(16, L - l0);
  const float* fx = lvl == 0 ? f0 : lvl == 1 ? f1 : lvl == 2 ? f2 : f3;
  int tid = threadIdx.x;

  for (int i = tid; i < 64 * 20; i += 256) {
    int c = i / 20, r = i - c * 20;
    int l = l0 - 3 + r;
    float v = 0.f;
    if (r < 19 && l >= 0 && l < L) v = fx[(size_t)(b * 64 + c) * L + l];
    s_x[i] = v;
  }
  __syncthreads();
  {  // xz GEMM: 19 rows x 256 cols, K=64
    int j = tid;
    float acc[19];
#pragma unroll
    for (int r = 0; r < 19; ++r) acc[r] = 0.f;
    const float* W = Win + lvl * 64 * 256 + j;
    for (int c = 0; c < 64; ++c) {
      float w = W[c * 256];
#pragma unroll
      for (int r = 0; r < 19; ++r) acc[r] = fmaf(w, s_x[c * 20 + r], acc[r]);
    }
    if (j < 128) {
#pragma unroll
      for (int r = 0; r < 19; ++r) s_xs[r * 128 + j] = acc[r];
    } else {
      int d = j - 128;
      int dti = d >> 4, jj = d & 15;
      for (int r = 3; r < 19; ++r) {
        int l = l0 - 3 + r;
        if (l < l0 + nl)
          z_l[((size_t)(b * 8 + dti) * LTOT + loff + l) * 16 + jj] = f2b(acc[r]);
      }
    }
  }
  __syncthreads();
  for (int i = tid; i < 16 * 128; i += 256) {
    int l = i >> 7, d = i & 127;
    if (l < nl) {
      const float* wc = Wconv + (lvl * 128 + d) * 4;
      float a = bconv[lvl * 128 + d];
#pragma unroll
      for (int k = 0; k < 4; ++k) a = fmaf(wc[k], s_xs[(l + k) * 128 + d], a);
      float uu = siluf(a);
      s_u[l * 132 + d] = uu;
      u_l[((size_t)(b * 8 + (d >> 4)) * LTOT + loff + l0 + l) * 16 + (d & 15)] = f2b(uu);
    }
  }
  __syncthreads();
  for (int i = tid; i < 16 * 36; i += 256) {
    int l = i & 15, jj = i >> 4;
    if (l < nl) {
      const float* wx = Wx + lvl * 128 * 36 + jj;
      float a = 0.f;
      for (int d = 0; d < 128; ++d) a = fmaf(s_u[l * 132 + d], wx[d * 36], a);
      s_dbc[l * 36 + jj] = a;
      if (jj >= 4) {
        int q = jj - 4;
        size_t gb = ((size_t)(b * LTOT) + loff + l0 + l) * 16;
        if (q < 16) Bm_l[gb + q] = f2b(a);
        else        Cm_l[gb + (q - 16)] = f2b(a);
      }
    }
  }
  __syncthreads();
  for (int i = tid; i < 16 * 128; i += 256) {
    int l = i >> 7, d = i & 127;
    if (l < nl) {
      float a = bdt[lvl * 128 + d];
#pragma unroll
      for (int r = 0; r < 4; ++r)
        a = fmaf(s_dbc[l * 36 + r], Wdt[(lvl * 4 + r) * 128 + d], a);
      dt_l[((size_t)(b * 8 + (d >> 4)) * LTOT + loff + l0 + l) * 16 + (d & 15)] =
          f2b(softplusf(a));
    }
  }
}

// ----------------------------- chunked scan (CH=64) --------------------------
// MODE 0 = levels (DI=128), MODE 1 = cross (DI=512). PASSC: emit gated y.
template <int MODE, int PASSC>
__global__ __launch_bounds__(256) void k_scan(
    const u16* __restrict__ dtb, const u16* __restrict__ ub,
    const u16* __restrict__ Bmb, const u16* __restrict__ Cmb,
    const u16* __restrict__ zb,
    const float* __restrict__ Alog, const float* __restrict__ Dsk,
    float* __restrict__ hloc, float* __restrict__ Ssum,
    const float* __restrict__ hin, u16* __restrict__ yg) {
  constexpr int DI = MODE ? 512 : 128;
  constexpr int NDT = DI / 16;
  constexpr int NCHT = MODE ? NCHC : NCHL;
  constexpr int LT = MODE ? LC : LTOT;
  constexpr int NARR = PASSC ? 5 : 3;
  __shared__ __align__(16) u16 smem[NARR * 1024];
  u16* s_dt = smem;
  u16* s_u = smem + 1024;
  u16* s_B = smem + 2048;
  u16* s_C = PASSC ? smem + 3072 : nullptr;
  u16* s_y = PASSC ? smem + 4096 : nullptr;

  int bid = blockIdx.x;
  int dti = bid % NDT;
  int rem = bid / NDT;
  int gc = rem % NCHT;
  int b = rem / NCHT;
  int lvl = 0, ch = gc, Lq = LC, loff = 0;
  if (MODE == 0) {
    while (lvl < 3 && gc >= CHOFF4[lvl + 1]) ++lvl;
    ch = gc - CHOFF4[lvl];
    Lq = L4[lvl];
    loff = LOFF4[lvl];
  }
  int l0 = ch * 64;
  int len = min(64, Lq - l0);
  int labs0 = loff + l0;
  int tid = threadIdx.x;
  int n = tid & 15, dd = tid >> 4;
  int d = dti * 16 + dd;

  size_t base2 = ((size_t)(b * NDT + dti) * LT + labs0) * 16;
  size_t baseB = ((size_t)b * LT + labs0) * 16;
  {
    int nv = len * 2;   // ushort8 vectors per array
    const u16x8* pdt = (const u16x8*)(dtb + base2);
    const u16x8* pu  = (const u16x8*)(ub + base2);
    const u16x8* pB  = (const u16x8*)(Bmb + baseB);
    u16x8* qdt = (u16x8*)s_dt;
    u16x8* qu  = (u16x8*)s_u;
    u16x8* qB  = (u16x8*)s_B;
    for (int i = tid; i < nv; i += 256) {
      qdt[i] = pdt[i];
      qu[i]  = pu[i];
      qB[i]  = pB[i];
    }
    if (PASSC) {
      const u16x8* pC = (const u16x8*)(Cmb + baseB);
      u16x8* qC = (u16x8*)s_C;
      for (int i = tid; i < nv; i += 256) qC[i] = pC[i];
    }
  }
  __syncthreads();

  int ai = (MODE ? d : lvl * 128 + d);
  float kA2 = -__expf(Alog[ai * 16 + n]) * LOG2E;
  size_t hix = (((size_t)(b * NCHT) + gc) * DI + d) * 16 + n;
  float h = 0.f, ss = 0.f;
  if (PASSC) h = hin[hix];
  float dsk = PASSC ? Dsk[ai] : 0.f;

#pragma unroll 2
  for (int l = 0; l < len; ++l) {
    float dt = b2f(s_dt[l * 16 + dd]);
    float uu = b2f(s_u[l * 16 + dd]);
    float bm = b2f(s_B[l * 16 + n]);
    float dA = exp2f(kA2 * dt);
    h = fmaf(dA, h, dt * uu * bm);
    if (PASSC) {
      float p = h * b2f(s_C[l * 16 + n]);
      p += __shfl_xor(p, 1, 16);
      p += __shfl_xor(p, 2, 16);
      p += __shfl_xor(p, 4, 16);
      p += __shfl_xor(p, 8, 16);
      if (n == 0) s_y[l * 16 + dd] = f2b(fmaf(uu, dsk, p));
    } else {
      ss += dt;
    }
  }
  if (!PASSC) {
    hloc[hix] = h;
    if (n == 0) Ssum[((size_t)(b * NCHT) + gc) * DI + d] = ss;
  } else {
    __syncthreads();
    for (int i = tid; i < len * 16; i += 256) {
      float z = b2f(zb[base2 + i]);
      float gate = z / (1.f + __expf(-z));
      yg[base2 + i] = f2b(b2f(s_y[i]) * gate);
    }
  }
}

__global__ __launch_bounds__(256) void k_combine_lvl(
    const float* __restrict__ Alog, const float* __restrict__ hloc,
    const float* __restrict__ Ssum, float* __restrict__ hin) {
  int i = blockIdx.x * 256 + threadIdx.x;   // 16384
  int n = i & 15, d = (i >> 4) & 127, lvl = (i >> 11) & 3, b = i >> 13;
  float kA2 = -__expf(Alog[(lvl * 128 + d) * 16 + n]) * LOG2E;
  float h = 0.f;
  int nch = NCH4[lvl];
  for (int ch = 0; ch < nch; ++ch) {
    int gc = CHOFF4[lvl] + ch;
    size_t ix = (((size_t)(b * NCHL) + gc) * 128 + d) * 16 + n;
    hin[ix] = h;
    float S = Ssum[((size_t)(b * NCHL) + gc) * 128 + d];
    h = fmaf(exp2f(kA2 * S), h, hloc[ix]);
  }
}

__global__ __launch_bounds__(256) void k_combine_cr(
    const float* __restrict__ Alog, const float* __restrict__ hloc,
    const float* __restrict__ Ssum, float* __restrict__ hin) {
  int i = blockIdx.x * 256 + threadIdx.x;   // 16384
  int n = i & 15, d = (i >> 4) & 511, b = i >> 13;
  float kA2 = -__expf(Alog[d * 16 + n]) * LOG2E;
  float h = 0.f;
  for (int ch = 0; ch < NCHC; ++ch) {
    size_t ix = (((size_t)(b * NCHC) + ch) * 512 + d) * 16 + n;
    hin[ix] = h;
    float S = Ssum[((size_t)(b * NCHC) + ch) * 512 + d];
    h = fmaf(exp2f(kA2 * S), h, hloc[ix]);
  }
}

// --------------- level out-GEMM + residual, store (B,C,L) CHW ----------------
__global__ __launch_bounds__(256) void k_out_lvl(
    const u16* __restrict__ yg_l, const float* __restrict__ Wout, // (4,128,64)
    const float* __restrict__ f0, const float* __restrict__ f1,
    const float* __restrict__ f2, const float* __restrict__ f3,
    float* __restrict__ fout) {
  __shared__ float s_ygT[128 * 20];   // [d][l], stride 20
  __shared__ float s_o[16 * 64];
  int bid = blockIdx.x;  // B*NTT
  int b = bid / NTT, t = bid - b * NTT;
  int lvl = 0;
  while (lvl < 3 && t >= TOFF4[lvl + 1]) ++lvl;
  int tl = t - TOFF4[lvl];
  int L = L4[lvl], loff = LOFF4[lvl];
  int l0 = tl * 16, nl = min(16, L - l0);
  const float* fx = lvl == 0 ? f0 : lvl == 1 ? f1 : lvl == 2 ? f2 : f3;
  int tid = threadIdx.x;
  for (int i = tid; i < 16 * 128; i += 256) {
    int d = i & 127, l = i >> 7;
    float v = 0.f;
    if (l < nl)
      v = b2f(yg_l[((size_t)(b * 8 + (d >> 4)) * LTOT + loff + l0 + l) * 16 + (d & 15)]);
    s_ygT[d * 20 + l] = v;
  }
  __syncthreads();
  {
    int c = tid & 63, lg = (tid >> 6) * 4;
    float acc[4] = {0.f, 0.f, 0.f, 0.f};
    const float* W = Wout + lvl * 128 * 64 + c;
    for (int dq = 0; dq < 128; ++dq) {
      float w = W[dq * 64];
      float4 yv = *(const float4*)&s_ygT[dq * 20 + lg];
      acc[0] = fmaf(w, yv.x, acc[0]);
      acc[1] = fmaf(w, yv.y, acc[1]);
      acc[2] = fmaf(w, yv.z, acc[2]);
      acc[3] = fmaf(w, yv.w, acc[3]);
    }
#pragma unroll
    for (int a = 0; a < 4; ++a) s_o[(lg + a) * 64 + c] = acc[a];
  }
  __syncthreads();
  for (int i = tid; i < 16 * 64; i += 256) {
    int c = i >> 4, l = i & 15;
    if (l < nl)
      fout[((size_t)(b * 64) + c) * LTOT + loff + l0 + l] =
          s_o[l * 64 + c] + fx[((size_t)(b * 64) + c) * L + l0 + l];
  }
}

// --------------------------- bilinear resize + concat ------------------------
__global__ __launch_bounds__(256) void k_resize(const float* __restrict__ fout,
                                                float* __restrict__ xcat) {
  int i = blockIdx.x * 256 + threadIdx.x;   // B*256*2304
  int hw = i % 2304;
  int rem = i / 2304;
  int ch = rem & 255;
  int b = rem >> 8;
  int oh = hw / 48, ow = hw - oh * 48;
  int lvl = ch >> 6, c = ch & 63;
  int s = S4[lvl];
  const float* base = fout + ((size_t)(b * 64) + c) * LTOT + LOFF4[lvl];
  float scl = (float)(s - 1) * (1.f / 47.f);
  float fy = oh * scl, fxx = ow * scl;
  int y0 = (int)floorf(fy), x0 = (int)floorf(fxx);
  float wy = fy - y0, wx = fxx - x0;
  int y1 = min(y0 + 1, s - 1), x1 = min(x0 + 1, s - 1);
  float v00 = base[y0 * s + x0], v01 = base[y0 * s + x1];
  float v10 = base[y1 * s + x0], v11 = base[y1 * s + x1];
  float top = v00 * (1.f - wx) + v01 * wx;
  float bot = v10 * (1.f - wx) + v11 * wx;
  xcat[i] = top * (1.f - wy) + bot * wy;
}

// ------------------- cross input GEMM: xcat @ cr_Win -------------------------
// 576 blocks: b x 144 l-tiles(16) x 2 j-halves(512). LDS-staged K-tiles of Win
// with register prefetch; 8j x 4l per thread.
__global__ __launch_bounds__(256) void k_gemm_in_cr(
    const float* __restrict__ xcat,  // (B,256,2304)
    const float* __restrict__ Win,   // (256,1024)
    u16* __restrict__ xs_c, u16* __restrict__ z_c) {
  __shared__ __align__(16) float s_x[256 * 16];   // [c][l]  16 KB
  __shared__ __align__(16) float s_w[16 * 512];   // K-tile  32 KB
  int bid = blockIdx.x;  // B*144*2
  int jb = bid & 1;
  int rem = bid >> 1;
  int tl = rem % 144, b = rem / 144;
  int l0 = tl * 16;
  int tid = threadIdx.x;
  for (int i = tid; i < 256 * 16; i += 256) {
    int c = i >> 4, l = i & 15;
    s_x[i] = xcat[((size_t)(b * 256) + c) * LC + l0 + l];
  }
  const float* Wb = Win + jb * 512;
  float4 r0, r1, r2, r3, r4, r5, r6, r7;
  auto ldW = [&](int kt, float4& a0, float4& a1, float4& a2, float4& a3,
                 float4& a4, float4& a5, float4& a6, float4& a7) {
    // tile = rows kt*16..+15, 512 cols; 2048 float4s, 8 per thread
    const float* base = Wb + kt * 16 * 1024;
#pragma unroll
    for (int s = 0; s < 8; ++s) {
      int idx = s * 256 + tid;
      int row = idx >> 7, c4 = (idx & 127) << 2;
      float4 v = *(const float4*)&base[row * 1024 + c4];
      if (s == 0) a0 = v; else if (s == 1) a1 = v; else if (s == 2) a2 = v;
      else if (s == 3) a3 = v; else if (s == 4) a4 = v; else if (s == 5) a5 = v;
      else if (s == 6) a6 = v; else a7 = v;
    }
  };
  auto stW = [&](const float4& a0, const float4& a1, const float4& a2,
                 const float4& a3, const float4& a4, const float4& a5,
                 const float4& a6, const float4& a7) {
#pragma unroll
    for (int s = 0; s < 8; ++s) {
      int idx = s * 256 + tid;
      int row = idx >> 7, c4 = (idx & 127) << 2;
      const float4& v = s == 0 ? a0 : s == 1 ? a1 : s == 2 ? a2 : s == 3 ? a3
                      : s == 4 ? a4 : s == 5 ? a5 : s == 6 ? a6 : a7;
      *(float4*)&s_w[row * 512 + c4] = v;
    }
  };

  int j0 = (tid & 63) * 4;
  int lg = (tid >> 6) * 4;
  float acc[4][8];
#pragma unroll
  for (int a = 0; a < 4; ++a)
#pragma unroll
    for (int q = 0; q < 8; ++q) acc[a][q] = 0.f;

  ldW(0, r0, r1, r2, r3, r4, r5, r6, r7);
  stW(r0, r1, r2, r3, r4, r5, r6, r7);
  __syncthreads();
  for (int kt = 0; kt < 16; ++kt) {
    if (kt < 15) ldW(kt + 1, r0, r1, r2, r3, r4, r5, r6, r7);
#pragma unroll
    for (int cc = 0; cc < 16; ++cc) {
      int c = kt * 16 + cc;
      float4 xv = *(const float4*)&s_x[c * 16 + lg];
      float4 w0 = *(const float4*)&s_w[cc * 512 + j0];
      float4 w1 = *(const float4*)&s_w[cc * 512 + j0 + 256];
      float xr[4] = {xv.x, xv.y, xv.z, xv.w};
      float wf[8] = {w0.x, w0.y, w0.z, w0.w, w1.x, w1.y, w1.z, w1.w};
#pragma unroll
      for (int a = 0; a < 4; ++a)
#pragma unroll
        for (int q = 0; q < 8; ++q)
          acc[a][q] = fmaf(xr[a], wf[q], acc[a][q]);
    }
    __syncthreads();
    if (kt < 15) {
      stW(r0, r1, r2, r3, r4, r5, r6, r7);
      __syncthreads();
    }
  }

#pragma unroll
  for (int a = 0; a < 4; ++a) {
    int l = l0 + lg + a;
    u16x4 v0, v1;
    v0.x = f2b(acc[a][0]); v0.y = f2b(acc[a][1]);
    v0.z = f2b(acc[a][2]); v0.w = f2b(acc[a][3]);
    v1.x = f2b(acc[a][4]); v1.y = f2b(acc[a][5]);
    v1.z = f2b(acc[a][6]); v1.w = f2b(acc[a][7]);
    if (jb == 0) {
      *(u16x4*)&xs_c[((size_t)(b * LC) + l) * 512 + j0] = v0;
      *(u16x4*)&xs_c[((size_t)(b * LC) + l) * 512 + j0 + 256] = v1;
    } else {
      int dz0 = j0, dz1 = j0 + 256;
      *(u16x4*)&z_c[((size_t)(b * 32 + (dz0 >> 4)) * LC + l) * 16 + (dz0 & 15)] = v0;
      *(u16x4*)&z_c[((size_t)(b * 32 + (dz1 >> 4)) * LC + l) * 16 + (dz1 & 15)] = v1;
    }
  }
}

// ------------- cross mid: conv + silu + dbc + dt (tile of 8 l) ---------------
__global__ __launch_bounds__(256) void k_mid_cr(
    const u16* __restrict__ xs_c,    // (B,2304,512) bf16
    const float* __restrict__ Wconv, // (512,4)
    const float* __restrict__ bconv, const float* __restrict__ Wx, // (512,48)
    const float* __restrict__ Wdt,   // (16,512)
    const float* __restrict__ bdt, u16* __restrict__ u_c,
    u16* __restrict__ dt_c, u16* __restrict__ Bm_c, u16* __restrict__ Cm_c) {
  __shared__ __align__(16) u16 s_xs[11 * 512];
  __shared__ float s_u[8 * 516];
  __shared__ float s_dbc[8 * 48];
  int bid = blockIdx.x;  // B*288
  int b = bid / 288, tl = bid - b * 288;
  int l0 = tl * 8;
  int tid = threadIdx.x;
  for (int i = tid; i < 704; i += 256) {  // 11*512/8 ushort8 vectors
    int r = i >> 6;
    int l = l0 - 3 + r;
    u16x8 v = {0, 0, 0, 0, 0, 0, 0, 0};
    if (l >= 0)
      v = *(const u16x8*)&xs_c[((size_t)(b * LC) + l) * 512 + (i & 63) * 8];
    *(u16x8*)&s_xs[i * 8] = v;
  }
  __syncthreads();
  for (int i = tid; i < 8 * 512; i += 256) {
    int l = i >> 9, d = i & 511;
    const float* wc = Wconv + d * 4;
    float a = bconv[d];
#pragma unroll
    for (int k = 0; k < 4; ++k) a = fmaf(wc[k], b2f(s_xs[(l + k) * 512 + d]), a);
    float uu = siluf(a);
    s_u[l * 516 + d] = uu;
    u_c[((size_t)(b * 32 + (d >> 4)) * LC + l0 + l) * 16 + (d & 15)] = f2b(uu);
  }
  __syncthreads();
  for (int i = tid; i < 8 * 48; i += 256) {
    int jj = i >> 3, l = i & 7;
    const float* wx = Wx + jj;
    float a = 0.f;
    for (int d = 0; d < 512; ++d) a = fmaf(s_u[l * 516 + d], wx[d * 48], a);
    s_dbc[l * 48 + jj] = a;
    if (jj >= 16) {
      int q = jj - 16;
      size_t gb = ((size_t)(b * LC) + l0 + l) * 16;
      if (q < 16) Bm_c[gb + q] = f2b(a);
      else        Cm_c[gb + (q - 16)] = f2b(a);
    }
  }
  __syncthreads();
  for (int i = tid; i < 8 * 512; i += 256) {
    int l = i >> 9, d = i & 511;
    float a = bdt[d];
#pragma unroll
    for (int r = 0; r < 16; ++r)
      a = fmaf(s_dbc[l * 48 + r], Wdt[r * 512 + d], a);
    dt_c[((size_t)(b * 32 + (d >> 4)) * LC + l0 + l) * 16 + (d & 15)] =
        f2b(softplusf(a));
  }
}

// --- final: out = relu(BN(projW @ (xcat + yg_c@Wout) + proj_b)), fused -------
// Weights (Wt 256x64, WP 512x64) staged in LDS K-tiles of 32 w/ reg prefetch.
__global__ __launch_bounds__(256) void k_final(
    const float* __restrict__ xcat, const u16* __restrict__ yg_c,
    const float* __restrict__ Wt, const float* __restrict__ WP,
    const float* __restrict__ pb, const float* __restrict__ bng,
    const float* __restrict__ bnb, const float* __restrict__ bnm,
    const float* __restrict__ bnv, float* __restrict__ out) {
  __shared__ float s_xc[256 * 16];    // [c][l] 16 KB
  __shared__ float s_ygT[512 * 16];   // [d][l] 32 KB
  __shared__ float s_w[32 * 64];      // weight K-tile 8 KB
  int bid = blockIdx.x;  // B*144
  int b = bid / 144, tl = bid - b * 144;
  int l0 = tl * 16;
  int tid = threadIdx.x;
  for (int i = tid; i < 256 * 16; i += 256) {
    int c = i >> 4, l = i & 15;
    s_xc[i] = xcat[((size_t)(b * 256) + c) * LC + l0 + l];
  }
  for (int i = tid; i < 16 * 512; i += 256) {
    int d = i >> 4, l = i & 15;
    s_ygT[i] =
        b2f(yg_c[((size_t)(b * 32 + (d >> 4)) * LC + l0 + l) * 16 + (d & 15)]);
  }
  int o = tid & 63, lg = (tid >> 6) * 4;
  float acc[4] = {0.f, 0.f, 0.f, 0.f};
  float4 r0, r1;
  auto ldT = [&](const float* W, int kt, float4& a0, float4& a1) {
    // tile rows kt*32..+31, 64 cols = 512 float4, 2 per thread
#pragma unroll
    for (int s = 0; s < 2; ++s) {
      int idx = s * 256 + tid;
      int row = idx >> 4, c4 = (idx & 15) << 2;
      float4 v = *(const float4*)&W[(kt * 32 + row) * 64 + c4];
      if (s == 0) a0 = v; else a1 = v;
    }
  };
  auto stT = [&](const float4& a0, const float4& a1) {
#pragma unroll
    for (int s = 0; s < 2; ++s) {
      int idx = s * 256 + tid;
      int row = idx >> 4, c4 = (idx & 15) << 2;
      *(float4*)&s_w[row * 64 + c4] = (s == 0) ? a0 : a1;
    }
  };
  ldT(Wt, 0, r0, r1);
  __syncthreads();           // staging of s_xc/s_ygT complete
  stT(r0, r1);
  __syncthreads();
  // Phase A: K = 256 over c (8 tiles of 32), x from s_xc
  for (int kt = 0; kt < 8; ++kt) {
    if (kt < 7) ldT(Wt, kt + 1, r0, r1);
    else ldT(WP, 0, r0, r1);
#pragma unroll
    for (int cc = 0; cc < 32; ++cc) {
      float w = s_w[cc * 64 + o];
      float4 xv = *(const float4*)&s_xc[(kt * 32 + cc) * 16 + lg];
      acc[0] = fmaf(w, xv.x, acc[0]);
      acc[1] = fmaf(w, xv.y, acc[1]);
      acc[2] = fmaf(w, xv.z, acc[2]);
      acc[3] = fmaf(w, xv.w, acc[3]);
    }
    __syncthreads();
    stT(r0, r1);
    __syncthreads();
  }
  // Phase B: K = 512 over d (16 tiles of 32), x from s_ygT
  for (int kt = 0; kt < 16; ++kt) {
    if (kt < 15) ldT(WP, kt + 1, r0, r1);
#pragma unroll
    for (int cc = 0; cc < 32; ++cc) {
      float w = s_w[cc * 64 + o];
      float4 yv = *(const float4*)&s_ygT[(kt * 32 + cc) * 16 + lg];
      acc[0] = fmaf(w, yv.x, acc[0]);
      acc[1] = fmaf(w, yv.y, acc[1]);
      acc[2] = fmaf(w, yv.z, acc[2]);
      acc[3] = fmaf(w, yv.w, acc[3]);
    }
    __syncthreads();
    if (kt < 15) {
      stT(r0, r1);
      __syncthreads();
    }
  }
  float bias = pb[o], m = bnm[o], g = bng[o], v = bnv[o], bb = bnb[o];
  float scl = g * (1.f / sqrtf(v + 1e-5f));
  float4 r;
  r.x = fmaxf((acc[0] + bias - m) * scl + bb, 0.f);
  r.y = fmaxf((acc[1] + bias - m) * scl + bb, 0.f);
  r.z = fmaxf((acc[2] + bias - m) * scl + bb, 0.f);
  r.w = fmaxf((acc[3] + bias - m) * scl + bb, 0.f);
  *(float4*)&out[((size_t)(b * 64) + o) * LC + l0 + lg] = r;
}

// -----------------------------------------------------------------------------
extern "C" void kernel_launch(void* const* d_in, const int* in_sizes, int n_in,
                              void* d_out, int out_size, void* d_ws,
                              size_t ws_size, hipStream_t stream) {
  (void)in_sizes; (void)n_in; (void)out_size; (void)ws_size;
  const float* f0 = (const float*)d_in[0];
  const float* f1 = (const float*)d_in[1];
  const float* f2 = (const float*)d_in[2];
  const float* f3 = (const float*)d_in[3];
  const float* lWin   = (const float*)d_in[4];
  const float* lWconv = (const float*)d_in[5];
  const float* lbconv = (const float*)d_in[6];
  const float* lWx    = (const float*)d_in[7];
  const float* lWdt   = (const float*)d_in[8];
  const float* lbdt   = (const float*)d_in[9];
  const float* lAlog  = (const float*)d_in[10];
  const float* lD     = (const float*)d_in[11];
  const float* lWout  = (const float*)d_in[12];
  const float* cWin   = (const float*)d_in[13];
  const float* cWconv = (const float*)d_in[14];
  const float* cbconv = (const float*)d_in[15];
  const float* cWx    = (const float*)d_in[16];
  const float* cWdt   = (const float*)d_in[17];
  const float* cbdt   = (const float*)d_in[18];
  const float* cAlog  = (const float*)d_in[19];
  const float* cD     = (const float*)d_in[20];
  const float* cWout  = (const float*)d_in[21];
  const float* projW  = (const float*)d_in[22];
  const float* projb  = (const float*)d_in[23];
  const float* bng    = (const float*)d_in[24];
  const float* bnb    = (const float*)d_in[25];
  const float* bnm    = (const float*)d_in[26];
  const float* bnv    = (const float*)d_in[27];
  float* out = (float*)d_out;

  float* ws = (float*)d_ws;
  size_t off = 0;
  auto allocf = [&](size_t n) { float* p = ws + off; off += (n + 7) & ~(size_t)7; return p; };
  auto allocb = [&](size_t n) { u16* p = (u16*)(ws + off); off += ((n + 1) / 2 + 7) & ~(size_t)7; return p; };

  float* Wt     = allocf(256 * 64);
  float* WP     = allocf(512 * 64);
  float* fout   = allocf((size_t)B_ * 64 * LTOT);
  float* xcat   = allocf((size_t)B_ * 256 * LC);
  float* hloc_l = allocf((size_t)B_ * NCHL * 128 * 16);
  float* S_l    = allocf((size_t)B_ * NCHL * 128);
  float* hin_l  = allocf((size_t)B_ * NCHL * 128 * 16);
  float* hloc_c = allocf((size_t)B_ * NCHC * 512 * 16);
  float* S_c    = allocf((size_t)B_ * NCHC * 512);
  float* hin_c  = allocf((size_t)B_ * NCHC * 512 * 16);

  u16* u_l2  = allocb((size_t)B_ * 8 * LTOT * 16);
  u16* dt_l2 = allocb((size_t)B_ * 8 * LTOT * 16);
  u16* z_l2  = allocb((size_t)B_ * 8 * LTOT * 16);
  u16* yg_l2 = allocb((size_t)B_ * 8 * LTOT * 16);
  u16* Bm_l2 = allocb((size_t)B_ * LTOT * 16);
  u16* Cm_l2 = allocb((size_t)B_ * LTOT * 16);
  u16* xs_c2 = allocb((size_t)B_ * LC * 512);
  u16* u_c2  = allocb((size_t)B_ * 32 * LC * 16);
  u16* dt_c2 = allocb((size_t)B_ * 32 * LC * 16);
  u16* z_c2  = allocb((size_t)B_ * 32 * LC * 16);
  u16* yg_c2 = allocb((size_t)B_ * 32 * LC * 16);
  u16* Bm_c2 = allocb((size_t)B_ * LC * 16);
  u16* Cm_c2 = allocb((size_t)B_ * LC * 16);

  k_prep<<<192, 256, 0, stream>>>(projW, cWout, Wt, WP);

  k_front_lvl<<<B_ * NTT, 256, 0, stream>>>(f0, f1, f2, f3, lWin, lWconv,
                                            lbconv, lWx, lWdt, lbdt, u_l2,
                                            dt_l2, Bm_l2, Cm_l2, z_l2);

  k_scan<0, 0><<<B_ * 8 * NCHL, 256, 0, stream>>>(
      dt_l2, u_l2, Bm_l2, Cm_l2, nullptr, lAlog, lD, hloc_l, S_l, nullptr,
      nullptr);
  k_combine_lvl<<<64, 256, 0, stream>>>(lAlog, hloc_l, S_l, hin_l);
  k_scan<0, 1><<<B_ * 8 * NCHL, 256, 0, stream>>>(
      dt_l2, u_l2, Bm_l2, Cm_l2, z_l2, lAlog, lD, nullptr, nullptr, hin_l,
      yg_l2);

  k_out_lvl<<<B_ * NTT, 256, 0, stream>>>(yg_l2, lWout, f0, f1, f2, f3, fout);
  k_resize<<<(B_ * 256 * LC) / 256, 256, 0, stream>>>(fout, xcat);

  k_gemm_in_cr<<<B_ * 144 * 2, 256, 0, stream>>>(xcat, cWin, xs_c2, z_c2);
  k_mid_cr<<<B_ * 288, 256, 0, stream>>>(xs_c2, cWconv, cbconv, cWx, cWdt,
                                         cbdt, u_c2, dt_c2, Bm_c2, Cm_c2);

  k_scan<1, 0><<<B_ * 32 * NCHC, 256, 0, stream>>>(
      dt_c2, u_c2, Bm_c2, Cm_c2, nullptr, cAlog, cD, hloc_c, S_c, nullptr,
      nullptr);
  k_combine_cr<<<64, 256, 0, stream>>>(cAlog, hloc_c, S_c, hin_c);
  k_scan<1, 1><<<B_ * 32 * NCHC, 256, 0, stream>>>(
      dt_c2, u_c2, Bm_c2, Cm_c2, z_c2, cAlog, cD, nullptr, nullptr, hin_c,
      yg_c2);

  k_final<<<B_ * 144, 256, 0, stream>>>(xcat, yg_c2, Wt, WP, projb, bng, bnb,
                                        bnm, bnv, out);
}

// Round 6
// 357.614 us; speedup vs baseline: 1.2049x; 1.0928x over previous
//
#include <hip/hip_runtime.h>
#include <cmath>

#define DEV __device__ __forceinline__

typedef unsigned short u16;
typedef u16 u16x8 __attribute__((ext_vector_type(8)));
typedef u16 u16x4 __attribute__((ext_vector_type(4)));
typedef short bf16x8 __attribute__((ext_vector_type(8)));
typedef float f32x4 __attribute__((ext_vector_type(4)));

constexpr int B_ = 2;
constexpr int S4[4]    = {48, 24, 12, 6};
constexpr int L4[4]    = {2304, 576, 144, 36};
constexpr int LOFF4[4] = {0, 2304, 2880, 3024};
constexpr int LTOT = 3060;
constexpr int TOFF4[4] = {0, 144, 180, 189};
constexpr int NTT = 192;
constexpr int NCH4[4]   = {36, 9, 3, 1};      // ceil(L/64)
constexpr int CHOFF4[4] = {0, 36, 45, 48};
constexpr int NCHL = 49;
constexpr int NCHC = 36;
constexpr int LC = 2304;
constexpr float LOG2E = 1.44269504088896f;

DEV float siluf(float x) { return x / (1.f + __expf(-x)); }
DEV float softplusf(float x) { return fmaxf(x, 0.f) + log1pf(__expf(-fabsf(x))); }
DEV float b2f(u16 x) { union { float f; unsigned u; } v; v.u = ((unsigned)x) << 16; return v.f; }
DEV u16 f2b(float f) {
  union { float f; unsigned u; } v; v.f = f;
  unsigned r = v.u + 0x7fffu + ((v.u >> 16) & 1u);
  return (u16)(r >> 16);
}

// ---- prep: Wt=projW^T | WP=cr_Wout@projW^T | WinT bf16 | WxT ---------------
__global__ __launch_bounds__(256) void k_prep(
    const float* __restrict__ projW, const float* __restrict__ crWout,
    const float* __restrict__ cWin, const float* __restrict__ cWx,
    float* __restrict__ Wt, float* __restrict__ WP,
    u16* __restrict__ WinT, float* __restrict__ WxT) {
  __shared__ float sm[64 * 65];
  int blk = blockIdx.x;
  int tid = threadIdx.x;
  if (blk < 64) {
    int i = blk * 256 + tid;   // 16384
    int o = i >> 8, c = i & 255;
    Wt[c * 64 + o] = projW[o * 256 + c];
  } else if (blk < 192) {
    int i = (blk - 64) * 256 + tid;   // 32768
    int d = i >> 6, o = i & 63;
    float acc = 0.f;
#pragma unroll 4
    for (int c = 0; c < 256; ++c)
      acc = fmaf(crWout[d * 256 + c], projW[o * 256 + c], acc);
    WP[d * 64 + o] = acc;
  } else if (blk < 256) {
    // transpose cr_Win (256,1024) -> WinT (1024,256) bf16, 64x64 tiles
    int t = blk - 192;
    int ct = t & 3, nt = t >> 2;
    int c0 = ct * 64, n0 = nt * 64;
    for (int i = tid; i < 4096; i += 256) {
      int cc = i >> 6, nn = i & 63;
      sm[cc * 65 + nn] = cWin[(size_t)(c0 + cc) * 1024 + n0 + nn];
    }
    __syncthreads();
    for (int i = tid; i < 4096; i += 256) {
      int nn = i >> 6, cc = i & 63;
      WinT[(size_t)(n0 + nn) * 256 + c0 + cc] = f2b(sm[cc * 65 + nn]);
    }
  } else {
    // WxT (48,512) from cr_Wx (512,48)
    int i = (blk - 256) * 256 + tid;   // 24576
    int d = i & 511, j = i >> 9;
    WxT[j * 512 + d] = cWx[d * 48 + j];
  }
}

// ------------- level front: in-GEMM + conv + silu + dbc + dt (fused) ---------
__global__ __launch_bounds__(256) void k_front_lvl(
    const float* __restrict__ f0, const float* __restrict__ f1,
    const float* __restrict__ f2, const float* __restrict__ f3,
    const float* __restrict__ Win,   // (4,64,256)
    const float* __restrict__ Wconv, // (4,128,4)
    const float* __restrict__ bconv, // (4,128)
    const float* __restrict__ Wx,    // (4,128,36)
    const float* __restrict__ Wdt,   // (4,4,128)
    const float* __restrict__ bdt,   // (4,128)
    u16* __restrict__ u_l, u16* __restrict__ dt_l,
    u16* __restrict__ Bm_l, u16* __restrict__ Cm_l, u16* __restrict__ z_l) {
  __shared__ float s_x[64 * 20];
  __shared__ float s_xs[19 * 128];
  __shared__ float s_u[16 * 132];
  __shared__ float s_dbc[16 * 36];
  int bid = blockIdx.x;              // B*NTT
  int b = bid / NTT, t = bid - b * NTT;
  int lvl = 0;
  while (lvl < 3 && t >= TOFF4[lvl + 1]) ++lvl;
  int tl = t - TOFF4[lvl];
  int L = L4[lvl], loff = LOFF4[lvl];
  int l0 = tl * 16;
  int nl = min(16, L - l0);
  const float* fx = lvl == 0 ? f0 : lvl == 1 ? f1 : lvl == 2 ? f2 : f3;
  int tid = threadIdx.x;

  for (int i = tid; i < 64 * 20; i += 256) {
    int c = i / 20, r = i - c * 20;
    int l = l0 - 3 + r;
    float v = 0.f;
    if (r < 19 && l >= 0 && l < L) v = fx[(size_t)(b * 64 + c) * L + l];
    s_x[i] = v;
  }
  __syncthreads();
  {  // xz GEMM: 19 rows x 256 cols, K=64
    int j = tid;
    float acc[19];
#pragma unroll
    for (int r = 0; r < 19; ++r) acc[r] = 0.f;
    const float* W = Win + lvl * 64 * 256 + j;
    for (int c = 0; c < 64; ++c) {
      float w = W[c * 256];
#pragma unroll
      for (int r = 0; r < 19; ++r) acc[r] = fmaf(w, s_x[c * 20 + r], acc[r]);
    }
    if (j < 128) {
#pragma unroll
      for (int r = 0; r < 19; ++r) s_xs[r * 128 + j] = acc[r];
    } else {
      int d = j - 128;
      int dti = d >> 4, jj = d & 15;
      for (int r = 3; r < 19; ++r) {
        int l = l0 - 3 + r;
        if (l < l0 + nl)
          z_l[((size_t)(b * 8 + dti) * LTOT + loff + l) * 16 + jj] = f2b(acc[r]);
      }
    }
  }
  __syncthreads();
  for (int i = tid; i < 16 * 128; i += 256) {
    int l = i >> 7, d = i & 127;
    if (l < nl) {
      const float* wc = Wconv + (lvl * 128 + d) * 4;
      float a = bconv[lvl * 128 + d];
#pragma unroll
      for (int k = 0; k < 4; ++k) a = fmaf(wc[k], s_xs[(l + k) * 128 + d], a);
      float uu = siluf(a);
      s_u[l * 132 + d] = uu;
      u_l[((size_t)(b * 8 + (d >> 4)) * LTOT + loff + l0 + l) * 16 + (d & 15)] = f2b(uu);
    }
  }
  __syncthreads();
  for (int i = tid; i < 16 * 36; i += 256) {
    int l = i & 15, jj = i >> 4;
    if (l < nl) {
      const float* wx = Wx + lvl * 128 * 36 + jj;
      float a = 0.f;
      for (int d = 0; d < 128; ++d) a = fmaf(s_u[l * 132 + d], wx[d * 36], a);
      s_dbc[l * 36 + jj] = a;
      if (jj >= 4) {
        int q = jj - 4;
        size_t gb = ((size_t)(b * LTOT) + loff + l0 + l) * 16;
        if (q < 16) Bm_l[gb + q] = f2b(a);
        else        Cm_l[gb + (q - 16)] = f2b(a);
      }
    }
  }
  __syncthreads();
  for (int i = tid; i < 16 * 128; i += 256) {
    int l = i >> 7, d = i & 127;
    if (l < nl) {
      float a = bdt[lvl * 128 + d];
#pragma unroll
      for (int r = 0; r < 4; ++r)
        a = fmaf(s_dbc[l * 36 + r], Wdt[(lvl * 4 + r) * 128 + d], a);
      dt_l[((size_t)(b * 8 + (d >> 4)) * LTOT + loff + l0 + l) * 16 + (d & 15)] =
          f2b(softplusf(a));
    }
  }
}

// ----------------------------- chunked scan (CH=64) --------------------------
template <int MODE, int PASSC>
__global__ __launch_bounds__(256) void k_scan(
    const u16* __restrict__ dtb, const u16* __restrict__ ub,
    const u16* __restrict__ Bmb, const u16* __restrict__ Cmb,
    const u16* __restrict__ zb,
    const float* __restrict__ Alog, const float* __restrict__ Dsk,
    float* __restrict__ hloc, float* __restrict__ Ssum,
    const float* __restrict__ hin, u16* __restrict__ yg) {
  constexpr int DI = MODE ? 512 : 128;
  constexpr int NDT = DI / 16;
  constexpr int NCHT = MODE ? NCHC : NCHL;
  constexpr int LT = MODE ? LC : LTOT;
  constexpr int NARR = PASSC ? 5 : 3;
  __shared__ __align__(16) u16 smem[NARR * 1024];
  u16* s_dt = smem;
  u16* s_u = smem + 1024;
  u16* s_B = smem + 2048;
  u16* s_C = PASSC ? smem + 3072 : nullptr;
  u16* s_y = PASSC ? smem + 4096 : nullptr;

  int bid = blockIdx.x;
  int dti = bid % NDT;
  int rem = bid / NDT;
  int gc = rem % NCHT;
  int b = rem / NCHT;
  int lvl = 0, ch = gc, Lq = LC, loff = 0;
  if (MODE == 0) {
    while (lvl < 3 && gc >= CHOFF4[lvl + 1]) ++lvl;
    ch = gc - CHOFF4[lvl];
    Lq = L4[lvl];
    loff = LOFF4[lvl];
  }
  int l0 = ch * 64;
  int len = min(64, Lq - l0);
  int labs0 = loff + l0;
  int tid = threadIdx.x;
  int n = tid & 15, dd = tid >> 4;
  int d = dti * 16 + dd;

  size_t base2 = ((size_t)(b * NDT + dti) * LT + labs0) * 16;
  size_t baseB = ((size_t)b * LT + labs0) * 16;
  {
    int nv = len * 2;
    const u16x8* pdt = (const u16x8*)(dtb + base2);
    const u16x8* pu  = (const u16x8*)(ub + base2);
    const u16x8* pB  = (const u16x8*)(Bmb + baseB);
    u16x8* qdt = (u16x8*)s_dt;
    u16x8* qu  = (u16x8*)s_u;
    u16x8* qB  = (u16x8*)s_B;
    for (int i = tid; i < nv; i += 256) {
      qdt[i] = pdt[i];
      qu[i]  = pu[i];
      qB[i]  = pB[i];
    }
    if (PASSC) {
      const u16x8* pC = (const u16x8*)(Cmb + baseB);
      u16x8* qC = (u16x8*)s_C;
      for (int i = tid; i < nv; i += 256) qC[i] = pC[i];
    }
  }
  __syncthreads();

  int ai = (MODE ? d : lvl * 128 + d);
  float kA2 = -__expf(Alog[ai * 16 + n]) * LOG2E;
  size_t hix = (((size_t)(b * NCHT) + gc) * DI + d) * 16 + n;
  float h = 0.f, ss = 0.f;
  if (PASSC) h = hin[hix];
  float dsk = PASSC ? Dsk[ai] : 0.f;

#pragma unroll 2
  for (int l = 0; l < len; ++l) {
    float dt = b2f(s_dt[l * 16 + dd]);
    float uu = b2f(s_u[l * 16 + dd]);
    float bm = b2f(s_B[l * 16 + n]);
    float dA = exp2f(kA2 * dt);
    h = fmaf(dA, h, dt * uu * bm);
    if (PASSC) {
      float p = h * b2f(s_C[l * 16 + n]);
      p += __shfl_xor(p, 1, 16);
      p += __shfl_xor(p, 2, 16);
      p += __shfl_xor(p, 4, 16);
      p += __shfl_xor(p, 8, 16);
      if (n == 0) s_y[l * 16 + dd] = f2b(fmaf(uu, dsk, p));
    } else {
      ss += dt;
    }
  }
  if (!PASSC) {
    hloc[hix] = h;
    if (n == 0) Ssum[((size_t)(b * NCHT) + gc) * DI + d] = ss;
  } else {
    __syncthreads();
    for (int i = tid; i < len * 16; i += 256) {
      float z = b2f(zb[base2 + i]);
      float gate = z / (1.f + __expf(-z));
      yg[base2 + i] = f2b(b2f(s_y[i]) * gate);
    }
  }
}

__global__ __launch_bounds__(256) void k_combine_lvl(
    const float* __restrict__ Alog, const float* __restrict__ hloc,
    const float* __restrict__ Ssum, float* __restrict__ hin) {
  int i = blockIdx.x * 256 + threadIdx.x;   // 16384
  int n = i & 15, d = (i >> 4) & 127, lvl = (i >> 11) & 3, b = i >> 13;
  float kA2 = -__expf(Alog[(lvl * 128 + d) * 16 + n]) * LOG2E;
  float h = 0.f;
  int nch = NCH4[lvl];
  for (int ch = 0; ch < nch; ++ch) {
    int gc = CHOFF4[lvl] + ch;
    size_t ix = (((size_t)(b * NCHL) + gc) * 128 + d) * 16 + n;
    hin[ix] = h;
    float S = Ssum[((size_t)(b * NCHL) + gc) * 128 + d];
    h = fmaf(exp2f(kA2 * S), h, hloc[ix]);
  }
}

__global__ __launch_bounds__(256) void k_combine_cr(
    const float* __restrict__ Alog, const float* __restrict__ hloc,
    const float* __restrict__ Ssum, float* __restrict__ hin) {
  int i = blockIdx.x * 256 + threadIdx.x;   // 16384
  int n = i & 15, d = (i >> 4) & 511, b = i >> 13;
  float kA2 = -__expf(Alog[d * 16 + n]) * LOG2E;
  float h = 0.f;
  for (int ch = 0; ch < NCHC; ++ch) {
    size_t ix = (((size_t)(b * NCHC) + ch) * 512 + d) * 16 + n;
    hin[ix] = h;
    float S = Ssum[((size_t)(b * NCHC) + ch) * 512 + d];
    h = fmaf(exp2f(kA2 * S), h, hloc[ix]);
  }
}

// --------------- level out-GEMM + residual, store (B,C,L) CHW ----------------
__global__ __launch_bounds__(256) void k_out_lvl(
    const u16* __restrict__ yg_l, const float* __restrict__ Wout, // (4,128,64)
    const float* __restrict__ f0, const float* __restrict__ f1,
    const float* __restrict__ f2, const float* __restrict__ f3,
    float* __restrict__ fout) {
  __shared__ float s_ygT[128 * 20];   // [d][l], stride 20
  __shared__ float s_o[16 * 64];
  int bid = blockIdx.x;  // B*NTT
  int b = bid / NTT, t = bid - b * NTT;
  int lvl = 0;
  while (lvl < 3 && t >= TOFF4[lvl + 1]) ++lvl;
  int tl = t - TOFF4[lvl];
  int L = L4[lvl], loff = LOFF4[lvl];
  int l0 = tl * 16, nl = min(16, L - l0);
  const float* fx = lvl == 0 ? f0 : lvl == 1 ? f1 : lvl == 2 ? f2 : f3;
  int tid = threadIdx.x;
  for (int i = tid; i < 16 * 128; i += 256) {
    int d = i & 127, l = i >> 7;
    float v = 0.f;
    if (l < nl)
      v = b2f(yg_l[((size_t)(b * 8 + (d >> 4)) * LTOT + loff + l0 + l) * 16 + (d & 15)]);
    s_ygT[d * 20 + l] = v;
  }
  __syncthreads();
  {
    int c = tid & 63, lg = (tid >> 6) * 4;
    float acc[4] = {0.f, 0.f, 0.f, 0.f};
    const float* W = Wout + lvl * 128 * 64 + c;
    for (int dq = 0; dq < 128; ++dq) {
      float w = W[dq * 64];
      float4 yv = *(const float4*)&s_ygT[dq * 20 + lg];
      acc[0] = fmaf(w, yv.x, acc[0]);
      acc[1] = fmaf(w, yv.y, acc[1]);
      acc[2] = fmaf(w, yv.z, acc[2]);
      acc[3] = fmaf(w, yv.w, acc[3]);
    }
#pragma unroll
    for (int a = 0; a < 4; ++a) s_o[(lg + a) * 64 + c] = acc[a];
  }
  __syncthreads();
  for (int i = tid; i < 16 * 64; i += 256) {
    int c = i >> 4, l = i & 15;
    if (l < nl)
      fout[((size_t)(b * 64) + c) * LTOT + loff + l0 + l] =
          s_o[l * 64 + c] + fx[((size_t)(b * 64) + c) * L + l0 + l];
  }
}

// ----------- bilinear resize + concat -> (b,l,c) fp32 + bf16 -----------------
__global__ __launch_bounds__(256) void k_resize(const float* __restrict__ fout,
                                                float* __restrict__ xTf,
                                                u16* __restrict__ xTb) {
  int i = blockIdx.x * 256 + threadIdx.x;   // B*2304*256, ch fastest
  int ch = i & 255;
  int rem = i >> 8;
  int hw = rem % 2304;
  int b = rem / 2304;
  int oh = hw / 48, ow = hw - oh * 48;
  int lvl = ch >> 6, c = ch & 63;
  int s = S4[lvl];
  const float* base = fout + ((size_t)(b * 64) + c) * LTOT + LOFF4[lvl];
  float scl = (float)(s - 1) * (1.f / 47.f);
  float fy = oh * scl, fxx = ow * scl;
  int y0 = (int)floorf(fy), x0 = (int)floorf(fxx);
  float wy = fy - y0, wx = fxx - x0;
  int y1 = min(y0 + 1, s - 1), x1 = min(x0 + 1, s - 1);
  float v00 = base[y0 * s + x0], v01 = base[y0 * s + x1];
  float v10 = base[y1 * s + x0], v11 = base[y1 * s + x1];
  float top = v00 * (1.f - wx) + v01 * wx;
  float bot = v10 * (1.f - wx) + v11 * wx;
  float v = top * (1.f - wy) + bot * wy;
  xTf[i] = v;
  xTb[i] = f2b(v);
}

// ----------------- cross input GEMM via MFMA: xT @ WinT^T --------------------
// M=4608 (b*l), N=1024 (j), K=256 (c). BM=64 BN=128 BK=64, 4 waves (32x64).
__global__ __launch_bounds__(256) void k_gemm_mfma(
    const u16* __restrict__ xT,   // (4608, 256) bf16
    const u16* __restrict__ WT,   // (1024, 256) bf16
    u16* __restrict__ xs_c, u16* __restrict__ z_c) {
  __shared__ __align__(16) u16 s_a[64 * 72];
  __shared__ __align__(16) u16 s_b[128 * 72];
  int bid = blockIdx.x;            // 72 * 8
  int nj = bid & 7, bm = bid >> 3;
  int tid = threadIdx.x;
  int lane = tid & 63, w = tid >> 6;
  int wm = (w & 1) * 32, wn = (w >> 1) * 64;
  const int m_base = bm * 64;
  const int n_base = nj * 128;

  f32x4 acc[2][4];
#pragma unroll
  for (int mi = 0; mi < 2; ++mi)
#pragma unroll
    for (int ni = 0; ni < 4; ++ni) acc[mi][ni] = {0.f, 0.f, 0.f, 0.f};

  // A tile: 64 rows x 64 k = 512 u16x8 vectors (2/thread)
  // B tile: 128 rows x 64 k = 1024 u16x8 vectors (4/thread)
  u16x8 ra0, ra1, rb0, rb1, rb2, rb3;
  auto ld = [&](int c0) {
#pragma unroll
    for (int s = 0; s < 2; ++s) {
      int v = s * 256 + tid;
      int row = v >> 3, kc = (v & 7) * 8;
      u16x8 t = *(const u16x8*)&xT[(size_t)(m_base + row) * 256 + c0 + kc];
      if (s == 0) ra0 = t; else ra1 = t;
    }
#pragma unroll
    for (int s = 0; s < 4; ++s) {
      int v = s * 256 + tid;
      int row = v >> 3, kc = (v & 7) * 8;
      u16x8 t = *(const u16x8*)&WT[(size_t)(n_base + row) * 256 + c0 + kc];
      if (s == 0) rb0 = t; else if (s == 1) rb1 = t;
      else if (s == 2) rb2 = t; else rb3 = t;
    }
  };
  auto st = [&]() {
#pragma unroll
    for (int s = 0; s < 2; ++s) {
      int v = s * 256 + tid;
      int row = v >> 3, kc = (v & 7) * 8;
      *(u16x8*)&s_a[row * 72 + kc] = (s == 0) ? ra0 : ra1;
    }
#pragma unroll
    for (int s = 0; s < 4; ++s) {
      int v = s * 256 + tid;
      int row = v >> 3, kc = (v & 7) * 8;
      const u16x8& t = (s == 0) ? rb0 : (s == 1) ? rb1 : (s == 2) ? rb2 : rb3;
      *(u16x8*)&s_b[row * 72 + kc] = t;
    }
  };
  ld(0);
  int mlane = lane & 15, kg = (lane >> 4) * 8;
  for (int kt = 0; kt < 4; ++kt) {
    st();
    __syncthreads();
    if (kt < 3) ld((kt + 1) * 64);
#pragma unroll
    for (int kk = 0; kk < 2; ++kk) {
      int k0 = kk * 32 + kg;
      bf16x8 af[2], bfr[4];
#pragma unroll
      for (int mi = 0; mi < 2; ++mi)
        af[mi] = *(const bf16x8*)&s_a[(wm + mi * 16 + mlane) * 72 + k0];
#pragma unroll
      for (int ni = 0; ni < 4; ++ni)
        bfr[ni] = *(const bf16x8*)&s_b[(wn + ni * 16 + mlane) * 72 + k0];
#pragma unroll
      for (int mi = 0; mi < 2; ++mi)
#pragma unroll
        for (int ni = 0; ni < 4; ++ni)
          acc[mi][ni] = __builtin_amdgcn_mfma_f32_16x16x32_bf16(
              af[mi], bfr[ni], acc[mi][ni], 0, 0, 0);
    }
    __syncthreads();
  }
  int rgrp = (lane >> 4) * 4;
#pragma unroll
  for (int mi = 0; mi < 2; ++mi) {
#pragma unroll
    for (int ni = 0; ni < 4; ++ni) {
      int n = n_base + wn + ni * 16 + mlane;
#pragma unroll
      for (int r = 0; r < 4; ++r) {
        int gm = m_base + wm + mi * 16 + rgrp + r;
        int b = gm >= 2304;
        int l = gm - b * 2304;
        u16 v = f2b(acc[mi][ni][r]);
        if (n < 512) {
          xs_c[((size_t)(b * LC) + l) * 512 + n] = v;
        } else {
          int dz = n - 512;
          z_c[((size_t)(b * 32 + (dz >> 4)) * LC + l) * 16 + (dz & 15)] = v;
        }
      }
    }
  }
}

// ------------- cross mid: conv + silu + dbc + dt (tile of 8 l) ---------------
__global__ __launch_bounds__(256) void k_mid_cr(
    const u16* __restrict__ xs_c,    // (B,2304,512) bf16
    const float* __restrict__ Wconv, // (512,4)
    const float* __restrict__ bconv,
    const float* __restrict__ WxT,   // (48,512)
    const float* __restrict__ Wdt,   // (16,512)
    const float* __restrict__ bdt, u16* __restrict__ u_c,
    u16* __restrict__ dt_c, u16* __restrict__ Bm_c, u16* __restrict__ Cm_c) {
  __shared__ __align__(16) u16 s_xs[11 * 512];
  __shared__ __align__(16) float s_u[8 * 516];
  __shared__ float s_dbc[8 * 48];
  int bid = blockIdx.x;  // B*288
  int b = bid / 288, tl = bid - b * 288;
  int l0 = tl * 8;
  int tid = threadIdx.x;
  for (int i = tid; i < 704; i += 256) {
    int r = i >> 6;
    int l = l0 - 3 + r;
    u16x8 v = {0, 0, 0, 0, 0, 0, 0, 0};
    if (l >= 0)
      v = *(const u16x8*)&xs_c[((size_t)(b * LC) + l) * 512 + (i & 63) * 8];
    *(u16x8*)&s_xs[i * 8] = v;
  }
  __syncthreads();
  for (int i = tid; i < 8 * 512; i += 256) {
    int l = i >> 9, d = i & 511;
    const float* wc = Wconv + d * 4;
    float a = bconv[d];
#pragma unroll
    for (int k = 0; k < 4; ++k) a = fmaf(wc[k], b2f(s_xs[(l + k) * 512 + d]), a);
    float uu = siluf(a);
    s_u[l * 516 + d] = uu;
    u_c[((size_t)(b * 32 + (d >> 4)) * LC + l0 + l) * 16 + (d & 15)] = f2b(uu);
  }
  __syncthreads();
  for (int i = tid; i < 8 * 48; i += 256) {
    int jj = i >> 3, l = i & 7;
    const float* wx = WxT + jj * 512;
    float a = 0.f;
#pragma unroll 4
    for (int d = 0; d < 512; d += 4) {
      float4 w4 = *(const float4*)&wx[d];
      float4 u4 = *(const float4*)&s_u[l * 516 + d];
      a = fmaf(w4.x, u4.x, a);
      a = fmaf(w4.y, u4.y, a);
      a = fmaf(w4.z, u4.z, a);
      a = fmaf(w4.w, u4.w, a);
    }
    s_dbc[l * 48 + jj] = a;
    if (jj >= 16) {
      int q = jj - 16;
      size_t gb = ((size_t)(b * LC) + l0 + l) * 16;
      if (q < 16) Bm_c[gb + q] = f2b(a);
      else        Cm_c[gb + (q - 16)] = f2b(a);
    }
  }
  __syncthreads();
  for (int i = tid; i < 8 * 512; i += 256) {
    int l = i >> 9, d = i & 511;
    float a = bdt[d];
#pragma unroll
    for (int r = 0; r < 16; ++r)
      a = fmaf(s_dbc[l * 48 + r], Wdt[r * 512 + d], a);
    dt_c[((size_t)(b * 32 + (d >> 4)) * LC + l0 + l) * 16 + (d & 15)] =
        f2b(softplusf(a));
  }
}

// --- final: out = relu(BN(projW @ (x + yg_c@Wout) + proj_b)), 8-l tiles ------
__global__ __launch_bounds__(256) void k_final(
    const float* __restrict__ xTf, const u16* __restrict__ yg_c,
    const float* __restrict__ Wt, const float* __restrict__ WP,
    const float* __restrict__ pb, const float* __restrict__ bng,
    const float* __restrict__ bnb, const float* __restrict__ bnm,
    const float* __restrict__ bnv, float* __restrict__ out) {
  __shared__ float s_xc[256 * 8];    // [c][l] 8 KB
  __shared__ float s_yg[512 * 8];    // [d][l] 16 KB
  __shared__ float s_w[32 * 64];     // weight K-tile 8 KB
  int bid = blockIdx.x;  // B*288
  int b = bid / 288, tl = bid - b * 288;
  int l0 = tl * 8;
  int tid = threadIdx.x;
  for (int i = tid; i < 2048; i += 256) {
    int c = i & 255, l = i >> 8;
    s_xc[c * 8 + l] = xTf[((size_t)(b * 2304) + l0 + l) * 256 + c];
  }
  for (int i = tid; i < 4096; i += 256) {
    int j = i & 15, l = (i >> 4) & 7, dt = i >> 7;
    s_yg[(dt * 16 + j) * 8 + l] =
        b2f(yg_c[((size_t)(b * 32 + dt) * LC + l0 + l) * 16 + j]);
  }
  int o = tid & 63, lg = (tid >> 6) * 2;
  float acc0 = 0.f, acc1 = 0.f;
  float4 r0, r1;
  auto ldT = [&](const float* W, int kt, float4& a0, float4& a1) {
#pragma unroll
    for (int s = 0; s < 2; ++s) {
      int idx = s * 256 + tid;
      int row = idx >> 4, c4 = (idx & 15) << 2;
      float4 v = *(const float4*)&W[(kt * 32 + row) * 64 + c4];
      if (s == 0) a0 = v; else a1 = v;
    }
  };
  auto stT = [&](const float4& a0, const float4& a1) {
#pragma unroll
    for (int s = 0; s < 2; ++s) {
      int idx = s * 256 + tid;
      int row = idx >> 4, c4 = (idx & 15) << 2;
      *(float4*)&s_w[row * 64 + c4] = (s == 0) ? a0 : a1;
    }
  };
  ldT(Wt, 0, r0, r1);
  __syncthreads();
  stT(r0, r1);
  __syncthreads();
  for (int kt = 0; kt < 8; ++kt) {
    if (kt < 7) ldT(Wt, kt + 1, r0, r1);
    else ldT(WP, 0, r0, r1);
#pragma unroll
    for (int cc = 0; cc < 32; ++cc) {
      float w = s_w[cc * 64 + o];
      float2 xv = *(const float2*)&s_xc[(kt * 32 + cc) * 8 + lg];
      acc0 = fmaf(w, xv.x, acc0);
      acc1 = fmaf(w, xv.y, acc1);
    }
    __syncthreads();
    stT(r0, r1);
    __syncthreads();
  }
  for (int kt = 0; kt < 16; ++kt) {
    if (kt < 15) ldT(WP, kt + 1, r0, r1);
#pragma unroll
    for (int cc = 0; cc < 32; ++cc) {
      float w = s_w[cc * 64 + o];
      float2 yv = *(const float2*)&s_yg[(kt * 32 + cc) * 8 + lg];
      acc0 = fmaf(w, yv.x, acc0);
      acc1 = fmaf(w, yv.y, acc1);
    }
    __syncthreads();
    if (kt < 15) {
      stT(r0, r1);
      __syncthreads();
    }
  }
  float bias = pb[o], m = bnm[o], g = bng[o], v = bnv[o], bb = bnb[o];
  float scl = g * (1.f / sqrtf(v + 1e-5f));
  float2 r;
  r.x = fmaxf((acc0 + bias - m) * scl + bb, 0.f);
  r.y = fmaxf((acc1 + bias - m) * scl + bb, 0.f);
  *(float2*)&out[((size_t)(b * 64) + o) * LC + l0 + lg] = r;
}

// -----------------------------------------------------------------------------
extern "C" void kernel_launch(void* const* d_in, const int* in_sizes, int n_in,
                              void* d_out, int out_size, void* d_ws,
                              size_t ws_size, hipStream_t stream) {
  (void)in_sizes; (void)n_in; (void)out_size; (void)ws_size;
  const float* f0 = (const float*)d_in[0];
  const float* f1 = (const float*)d_in[1];
  const float* f2 = (const float*)d_in[2];
  const float* f3 = (const float*)d_in[3];
  const float* lWin   = (const float*)d_in[4];
  const float* lWconv = (const float*)d_in[5];
  const float* lbconv = (const float*)d_in[6];
  const float* lWx    = (const float*)d_in[7];
  const float* lWdt   = (const float*)d_in[8];
  const float* lbdt   = (const float*)d_in[9];
  const float* lAlog  = (const float*)d_in[10];
  const float* lD     = (const float*)d_in[11];
  const float* lWout  = (const float*)d_in[12];
  const float* cWin   = (const float*)d_in[13];
  const float* cWconv = (const float*)d_in[14];
  const float* cbconv = (const float*)d_in[15];
  const float* cWx    = (const float*)d_in[16];
  const float* cWdt   = (const float*)d_in[17];
  const float* cbdt   = (const float*)d_in[18];
  const float* cAlog  = (const float*)d_in[19];
  const float* cD     = (const float*)d_in[20];
  const float* cWout  = (const float*)d_in[21];
  const float* projW  = (const float*)d_in[22];
  const float* projb  = (const float*)d_in[23];
  const float* bng    = (const float*)d_in[24];
  const float* bnb    = (const float*)d_in[25];
  const float* bnm    = (const float*)d_in[26];
  const float* bnv    = (const float*)d_in[27];
  float* out = (float*)d_out;

  float* ws = (float*)d_ws;
  size_t off = 0;
  auto allocf = [&](size_t n) { float* p = ws + off; off += (n + 7) & ~(size_t)7; return p; };
  auto allocb = [&](size_t n) { u16* p = (u16*)(ws + off); off += ((n + 1) / 2 + 7) & ~(size_t)7; return p; };

  float* Wt     = allocf(256 * 64);
  float* WP     = allocf(512 * 64);
  float* WxT    = allocf(48 * 512);
  float* fout   = allocf((size_t)B_ * 64 * LTOT);
  float* xTf    = allocf((size_t)B_ * LC * 256);
  float* hloc_l = allocf((size_t)B_ * NCHL * 128 * 16);
  float* S_l    = allocf((size_t)B_ * NCHL * 128);
  float* hin_l  = allocf((size_t)B_ * NCHL * 128 * 16);
  float* hloc_c = allocf((size_t)B_ * NCHC * 512 * 16);
  float* S_c    = allocf((size_t)B_ * NCHC * 512);
  float* hin_c  = allocf((size_t)B_ * NCHC * 512 * 16);

  u16* WinT  = allocb(1024 * 256);
  u16* xTb   = allocb((size_t)B_ * LC * 256);
  u16* u_l2  = allocb((size_t)B_ * 8 * LTOT * 16);
  u16* dt_l2 = allocb((size_t)B_ * 8 * LTOT * 16);
  u16* z_l2  = allocb((size_t)B_ * 8 * LTOT * 16);
  u16* yg_l2 = allocb((size_t)B_ * 8 * LTOT * 16);
  u16* Bm_l2 = allocb((size_t)B_ * LTOT * 16);
  u16* Cm_l2 = allocb((size_t)B_ * LTOT * 16);
  u16* xs_c2 = allocb((size_t)B_ * LC * 512);
  u16* u_c2  = allocb((size_t)B_ * 32 * LC * 16);
  u16* dt_c2 = allocb((size_t)B_ * 32 * LC * 16);
  u16* z_c2  = allocb((size_t)B_ * 32 * LC * 16);
  u16* yg_c2 = allocb((size_t)B_ * 32 * LC * 16);
  u16* Bm_c2 = allocb((size_t)B_ * LC * 16);
  u16* Cm_c2 = allocb((size_t)B_ * LC * 16);

  k_prep<<<352, 256, 0, stream>>>(projW, cWout, cWin, cWx, Wt, WP, WinT, WxT);

  k_front_lvl<<<B_ * NTT, 256, 0, stream>>>(f0, f1, f2, f3, lWin, lWconv,
                                            lbconv, lWx, lWdt, lbdt, u_l2,
                                            dt_l2, Bm_l2, Cm_l2, z_l2);

  k_scan<0, 0><<<B_ * 8 * NCHL, 256, 0, stream>>>(
      dt_l2, u_l2, Bm_l2, Cm_l2, nullptr, lAlog, lD, hloc_l, S_l, nullptr,
      nullptr);
  k_combine_lvl<<<64, 256, 0, stream>>>(lAlog, hloc_l, S_l, hin_l);
  k_scan<0, 1><<<B_ * 8 * NCHL, 256, 0, stream>>>(
      dt_l2, u_l2, Bm_l2, Cm_l2, z_l2, lAlog, lD, nullptr, nullptr, hin_l,
      yg_l2);

  k_out_lvl<<<B_ * NTT, 256, 0, stream>>>(yg_l2, lWout, f0, f1, f2, f3, fout);
  k_resize<<<(B_ * 256 * LC) / 256, 256, 0, stream>>>(fout, xTf, xTb);

  k_gemm_mfma<<<72 * 8, 256, 0, stream>>>(xTb, WinT, xs_c2, z_c2);
  k_mid_cr<<<B_ * 288, 256, 0, stream>>>(xs_c2, cWconv, cbconv, WxT, cWdt,
                                         cbdt, u_c2, dt_c2, Bm_c2, Cm_c2);

  k_scan<1, 0><<<B_ * 32 * NCHC, 256, 0, stream>>>(
      dt_c2, u_c2, Bm_c2, Cm_c2, nullptr, cAlog, cD, hloc_c, S_c, nullptr,
      nullptr);
  k_combine_cr<<<64, 256, 0, stream>>>(cAlog, hloc_c, S_c, hin_c);
  k_scan<1, 1><<<B_ * 32 * NCHC, 256, 0, stream>>>(
      dt_c2, u_c2, Bm_c2, Cm_c2, z_c2, cAlog, cD, nullptr, nullptr, hin_c,
      yg_c2);

  k_final<<<B_ * 288, 256, 0, stream>>>(xTf, yg_c2, Wt, WP, projb, bng, bnb,
                                        bnm, bnv, out);
}

// Round 7
// 350.599 us; speedup vs baseline: 1.2290x; 1.0200x over previous
//
#include <hip/hip_runtime.h>
#include <cmath>

#define DEV __device__ __forceinline__

typedef unsigned short u16;
typedef u16 u16x8 __attribute__((ext_vector_type(8)));
typedef u16 u16x4 __attribute__((ext_vector_type(4)));
typedef short bf16x8 __attribute__((ext_vector_type(8)));
typedef float f32x4 __attribute__((ext_vector_type(4)));

constexpr int B_ = 2;
constexpr int S4[4]    = {48, 24, 12, 6};
constexpr int L4[4]    = {2304, 576, 144, 36};
constexpr int LOFF4[4] = {0, 2304, 2880, 3024};
constexpr int LTOT = 3060;
constexpr int TOFF4[4] = {0, 144, 180, 189};
constexpr int NTT = 192;
constexpr int NCH4[4]   = {36, 9, 3, 1};      // ceil(L/64)
constexpr int CHOFF4[4] = {0, 36, 45, 48};
constexpr int NCHL = 49;
constexpr int NCHC = 36;
constexpr int LC = 2304;
constexpr float LOG2E = 1.44269504088896f;

DEV float siluf(float x) { return x / (1.f + __expf(-x)); }
DEV float softplusf(float x) { return fmaxf(x, 0.f) + log1pf(__expf(-fabsf(x))); }
DEV float b2f(u16 x) { union { float f; unsigned u; } v; v.u = ((unsigned)x) << 16; return v.f; }
DEV u16 f2b(float f) {
  union { float f; unsigned u; } v; v.f = f;
  unsigned r = v.u + 0x7fffu + ((v.u >> 16) & 1u);
  return (u16)(r >> 16);
}

// ---- prep: Wt=projW^T | WP=cr_Wout@projW^T | WinT bf16 | WxT ---------------
__global__ __launch_bounds__(256) void k_prep(
    const float* __restrict__ projW, const float* __restrict__ crWout,
    const float* __restrict__ cWin, const float* __restrict__ cWx,
    float* __restrict__ Wt, float* __restrict__ WP,
    u16* __restrict__ WinT, float* __restrict__ WxT) {
  __shared__ float sm[64 * 65];
  int blk = blockIdx.x;
  int tid = threadIdx.x;
  if (blk < 64) {
    int i = blk * 256 + tid;   // 16384
    int o = i >> 8, c = i & 255;
    Wt[c * 64 + o] = projW[o * 256 + c];
  } else if (blk < 192) {
    int i = (blk - 64) * 256 + tid;   // 32768
    int d = i >> 6, o = i & 63;
    float acc = 0.f;
#pragma unroll 4
    for (int c = 0; c < 256; ++c)
      acc = fmaf(crWout[d * 256 + c], projW[o * 256 + c], acc);
    WP[d * 64 + o] = acc;
  } else if (blk < 256) {
    // transpose cr_Win (256,1024) -> WinT (1024,256) bf16, 64x64 tiles
    int t = blk - 192;
    int ct = t & 3, nt = t >> 2;
    int c0 = ct * 64, n0 = nt * 64;
    for (int i = tid; i < 4096; i += 256) {
      int cc = i >> 6, nn = i & 63;
      sm[cc * 65 + nn] = cWin[(size_t)(c0 + cc) * 1024 + n0 + nn];
    }
    __syncthreads();
    for (int i = tid; i < 4096; i += 256) {
      int nn = i >> 6, cc = i & 63;
      WinT[(size_t)(n0 + nn) * 256 + c0 + cc] = f2b(sm[cc * 65 + nn]);
    }
  } else {
    // WxT (48,512) from cr_Wx (512,48)
    int i = (blk - 256) * 256 + tid;   // 24576
    int d = i & 511, j = i >> 9;
    WxT[j * 512 + d] = cWx[d * 48 + j];
  }
}

// ------------- level front: in-GEMM + conv + silu + dbc + dt (fused) ---------
__global__ __launch_bounds__(256) void k_front_lvl(
    const float* __restrict__ f0, const float* __restrict__ f1,
    const float* __restrict__ f2, const float* __restrict__ f3,
    const float* __restrict__ Win,   // (4,64,256)
    const float* __restrict__ Wconv, // (4,128,4)
    const float* __restrict__ bconv, // (4,128)
    const float* __restrict__ Wx,    // (4,128,36)
    const float* __restrict__ Wdt,   // (4,4,128)
    const float* __restrict__ bdt,   // (4,128)
    u16* __restrict__ u_l, u16* __restrict__ dt_l,
    u16* __restrict__ Bm_l, u16* __restrict__ Cm_l, u16* __restrict__ z_l) {
  __shared__ float s_x[64 * 20];
  __shared__ float s_xs[19 * 128];
  __shared__ float s_u[16 * 132];
  __shared__ float s_dbc[16 * 36];
  int bid = blockIdx.x;              // B*NTT
  int b = bid / NTT, t = bid - b * NTT;
  int lvl = 0;
  while (lvl < 3 && t >= TOFF4[lvl + 1]) ++lvl;
  int tl = t - TOFF4[lvl];
  int L = L4[lvl], loff = LOFF4[lvl];
  int l0 = tl * 16;
  int nl = min(16, L - l0);
  const float* fx = lvl == 0 ? f0 : lvl == 1 ? f1 : lvl == 2 ? f2 : f3;
  int tid = threadIdx.x;

  for (int i = tid; i < 64 * 20; i += 256) {
    int c = i / 20, r = i - c * 20;
    int l = l0 - 3 + r;
    float v = 0.f;
    if (r < 19 && l >= 0 && l < L) v = fx[(size_t)(b * 64 + c) * L + l];
    s_x[i] = v;
  }
  __syncthreads();
  {  // xz GEMM: 19 rows x 256 cols, K=64
    int j = tid;
    float acc[19];
#pragma unroll
    for (int r = 0; r < 19; ++r) acc[r] = 0.f;
    const float* W = Win + lvl * 64 * 256 + j;
    for (int c = 0; c < 64; ++c) {
      float w = W[c * 256];
#pragma unroll
      for (int r = 0; r < 19; ++r) acc[r] = fmaf(w, s_x[c * 20 + r], acc[r]);
    }
    if (j < 128) {
#pragma unroll
      for (int r = 0; r < 19; ++r) s_xs[r * 128 + j] = acc[r];
    } else {
      int d = j - 128;
      int dti = d >> 4, jj = d & 15;
      for (int r = 3; r < 19; ++r) {
        int l = l0 - 3 + r;
        if (l < l0 + nl)
          z_l[((size_t)(b * 8 + dti) * LTOT + loff + l) * 16 + jj] = f2b(acc[r]);
      }
    }
  }
  __syncthreads();
  for (int i = tid; i < 16 * 128; i += 256) {
    int l = i >> 7, d = i & 127;
    if (l < nl) {
      const float* wc = Wconv + (lvl * 128 + d) * 4;
      float a = bconv[lvl * 128 + d];
#pragma unroll
      for (int k = 0; k < 4; ++k) a = fmaf(wc[k], s_xs[(l + k) * 128 + d], a);
      float uu = siluf(a);
      s_u[l * 132 + d] = uu;
      u_l[((size_t)(b * 8 + (d >> 4)) * LTOT + loff + l0 + l) * 16 + (d & 15)] = f2b(uu);
    }
  }
  __syncthreads();
  for (int i = tid; i < 16 * 36; i += 256) {
    int l = i & 15, jj = i >> 4;
    if (l < nl) {
      const float* wx = Wx + lvl * 128 * 36 + jj;
      float a = 0.f;
      for (int d = 0; d < 128; ++d) a = fmaf(s_u[l * 132 + d], wx[d * 36], a);
      s_dbc[l * 36 + jj] = a;
      if (jj >= 4) {
        int q = jj - 4;
        size_t gb = ((size_t)(b * LTOT) + loff + l0 + l) * 16;
        if (q < 16) Bm_l[gb + q] = f2b(a);
        else        Cm_l[gb + (q - 16)] = f2b(a);
      }
    }
  }
  __syncthreads();
  for (int i = tid; i < 16 * 128; i += 256) {
    int l = i >> 7, d = i & 127;
    if (l < nl) {
      float a = bdt[lvl * 128 + d];
#pragma unroll
      for (int r = 0; r < 4; ++r)
        a = fmaf(s_dbc[l * 36 + r], Wdt[(lvl * 4 + r) * 128 + d], a);
      dt_l[((size_t)(b * 8 + (d >> 4)) * LTOT + loff + l0 + l) * 16 + (d & 15)] =
          f2b(softplusf(a));
    }
  }
}

// ------------------ chunked scan (CH=64), 4 states/thread --------------------
// Block = 256 thr = 64 d x 4 lanes; each thread owns n = n0..n0+3 of one d.
// MODE 0 = levels (DI=128, NB=2), MODE 1 = cross (DI=512, NB=8).
template <int MODE, int PASSC>
__global__ __launch_bounds__(256) void k_scan(
    const u16* __restrict__ dtb, const u16* __restrict__ ub,
    const u16* __restrict__ Bmb, const u16* __restrict__ Cmb,
    const u16* __restrict__ zb,
    const float* __restrict__ Alog, const float* __restrict__ Dsk,
    float* __restrict__ hloc, float* __restrict__ Ssum,
    const float* __restrict__ hin, u16* __restrict__ yg) {
  constexpr int DI = MODE ? 512 : 128;
  constexpr int NDT = DI / 16;
  constexpr int NB = DI / 64;
  constexpr int NCHT = MODE ? NCHC : NCHL;
  constexpr int LT = MODE ? LC : LTOT;
  __shared__ __align__(16) u16 smem[PASSC ? 14336 : 9216];
  u16* s_dt = smem;                 // [4][64*16]
  u16* s_u  = smem + 4096;          // [4][64*16]
  u16* s_B  = smem + 8192;          // [64][16]
  u16* s_C  = PASSC ? smem + 9216 : nullptr;   // [64][16]
  u16* s_y  = PASSC ? smem + 10240 : nullptr;  // [64][64]

  int bid = blockIdx.x;
  int dblk = bid % NB;
  int rem = bid / NB;
  int gc = rem % NCHT;
  int b = rem / NCHT;
  int lvl = 0, ch = gc, Lq = LC, loff = 0;
  if (MODE == 0) {
    while (lvl < 3 && gc >= CHOFF4[lvl + 1]) ++lvl;
    ch = gc - CHOFF4[lvl];
    Lq = L4[lvl];
    loff = LOFF4[lvl];
  }
  int l0 = ch * 64;
  int len = min(64, Lq - l0);
  int labs0 = loff + l0;
  int tid = threadIdx.x;
  int q = tid & 3;                 // n-group lane
  int dl = (tid >> 2) & 15;        // d within tile
  int ti_l = tid >> 6;             // local d-tile 0..3
  int dti = dblk * 4 + ti_l;
  int d = dti * 16 + dl;
  int n0 = q * 4;

  // stage dt/u (4 d-tiles) and B (+C)
  for (int ti = 0; ti < 4; ++ti) {
    size_t g2 = ((size_t)(b * NDT + dblk * 4 + ti) * LT + labs0) * 16;
    const u16x8* pdt = (const u16x8*)(dtb + g2);
    const u16x8* pu  = (const u16x8*)(ub + g2);
    for (int i = tid; i < len * 2; i += 256) {
      *(u16x8*)&s_dt[ti * 1024 + i * 8] = pdt[i];
      *(u16x8*)&s_u [ti * 1024 + i * 8] = pu[i];
    }
  }
  {
    size_t gB = ((size_t)b * LT + labs0) * 16;
    for (int i = tid; i < len * 2; i += 256) {
      *(u16x8*)&s_B[i * 8] = *(const u16x8*)&Bmb[gB + i * 8];
      if (PASSC) *(u16x8*)&s_C[i * 8] = *(const u16x8*)&Cmb[gB + i * 8];
    }
  }
  __syncthreads();

  int ai = (MODE ? d : lvl * 128 + d);
  float4 al = *(const float4*)&Alog[ai * 16 + n0];
  float kA2[4] = {-__expf(al.x) * LOG2E, -__expf(al.y) * LOG2E,
                  -__expf(al.z) * LOG2E, -__expf(al.w) * LOG2E};
  size_t hix = (((size_t)(b * NCHT) + gc) * DI + d) * 16 + n0;
  float h[4] = {0.f, 0.f, 0.f, 0.f};
  if (PASSC) {
    float4 hv = *(const float4*)&hin[hix];
    h[0] = hv.x; h[1] = hv.y; h[2] = hv.z; h[3] = hv.w;
  }
  float dsk = PASSC ? Dsk[ai] : 0.f;
  float ss = 0.f;

  for (int l = 0; l < len; ++l) {
    float dt = b2f(s_dt[ti_l * 1024 + l * 16 + dl]);
    float uu = b2f(s_u [ti_l * 1024 + l * 16 + dl]);
    float dtu = dt * uu;
    u16x4 Bv = *(const u16x4*)&s_B[l * 16 + n0];
    if (PASSC) {
      u16x4 Cv = *(const u16x4*)&s_C[l * 16 + n0];
      float p = 0.f;
#pragma unroll
      for (int i = 0; i < 4; ++i) {
        float dA = exp2f(kA2[i] * dt);
        h[i] = fmaf(dA, h[i], dtu * b2f(Bv[i]));
        p = fmaf(h[i], b2f(Cv[i]), p);
      }
      p += __shfl_xor(p, 1, 4);
      p += __shfl_xor(p, 2, 4);
      if (q == 0) s_y[l * 64 + ti_l * 16 + dl] = f2b(fmaf(uu, dsk, p));
    } else {
#pragma unroll
      for (int i = 0; i < 4; ++i) {
        float dA = exp2f(kA2[i] * dt);
        h[i] = fmaf(dA, h[i], dtu * b2f(Bv[i]));
      }
      ss += dt;
    }
  }
  if (!PASSC) {
    f32x4 hv = {h[0], h[1], h[2], h[3]};
    *(f32x4*)&hloc[hix] = hv;
    if (q == 0) Ssum[((size_t)(b * NCHT) + gc) * DI + d] = ss;
  } else {
    __syncthreads();
    for (int ti = 0; ti < 4; ++ti) {
      size_t g2 = ((size_t)(b * NDT + dblk * 4 + ti) * LT + labs0) * 16;
      for (int i = tid; i < len * 2; i += 256) {
        u16x8 zv = *(const u16x8*)&zb[g2 + i * 8];
        u16x8 yv = *(const u16x8*)&s_y[(i >> 1) * 64 + ti * 16 + (i & 1) * 8];
        u16x8 o;
#pragma unroll
        for (int j = 0; j < 8; ++j) {
          float z = b2f(zv[j]);
          float gate = z / (1.f + __expf(-z));
          o[j] = f2b(b2f(yv[j]) * gate);
        }
        *(u16x8*)&yg[g2 + i * 8] = o;
      }
    }
  }
}

__global__ __launch_bounds__(256) void k_combine_lvl(
    const float* __restrict__ Alog, const float* __restrict__ hloc,
    const float* __restrict__ Ssum, float* __restrict__ hin) {
  int i = blockIdx.x * 256 + threadIdx.x;   // 16384
  int n = i & 15, d = (i >> 4) & 127, lvl = (i >> 11) & 3, b = i >> 13;
  float kA2 = -__expf(Alog[(lvl * 128 + d) * 16 + n]) * LOG2E;
  float h = 0.f;
  int nch = NCH4[lvl];
  for (int ch = 0; ch < nch; ++ch) {
    int gc = CHOFF4[lvl] + ch;
    size_t ix = (((size_t)(b * NCHL) + gc) * 128 + d) * 16 + n;
    hin[ix] = h;
    float S = Ssum[((size_t)(b * NCHL) + gc) * 128 + d];
    h = fmaf(exp2f(kA2 * S), h, hloc[ix]);
  }
}

__global__ __launch_bounds__(256) void k_combine_cr(
    const float* __restrict__ Alog, const float* __restrict__ hloc,
    const float* __restrict__ Ssum, float* __restrict__ hin) {
  int i = blockIdx.x * 256 + threadIdx.x;   // 16384
  int n = i & 15, d = (i >> 4) & 511, b = i >> 13;
  float kA2 = -__expf(Alog[d * 16 + n]) * LOG2E;
  float h = 0.f;
  for (int ch = 0; ch < NCHC; ++ch) {
    size_t ix = (((size_t)(b * NCHC) + ch) * 512 + d) * 16 + n;
    hin[ix] = h;
    float S = Ssum[((size_t)(b * NCHC) + ch) * 512 + d];
    h = fmaf(exp2f(kA2 * S), h, hloc[ix]);
  }
}

// --------------- level out-GEMM + residual, store (B,C,L) CHW ----------------
__global__ __launch_bounds__(256) void k_out_lvl(
    const u16* __restrict__ yg_l, const float* __restrict__ Wout, // (4,128,64)
    const float* __restrict__ f0, const float* __restrict__ f1,
    const float* __restrict__ f2, const float* __restrict__ f3,
    float* __restrict__ fout) {
  __shared__ float s_ygT[128 * 20];   // [d][l], stride 20
  __shared__ float s_o[16 * 64];
  int bid = blockIdx.x;  // B*NTT
  int b = bid / NTT, t = bid - b * NTT;
  int lvl = 0;
  while (lvl < 3 && t >= TOFF4[lvl + 1]) ++lvl;
  int tl = t - TOFF4[lvl];
  int L = L4[lvl], loff = LOFF4[lvl];
  int l0 = tl * 16, nl = min(16, L - l0);
  const float* fx = lvl == 0 ? f0 : lvl == 1 ? f1 : lvl == 2 ? f2 : f3;
  int tid = threadIdx.x;
  for (int i = tid; i < 16 * 128; i += 256) {
    int d = i & 127, l = i >> 7;
    float v = 0.f;
    if (l < nl)
      v = b2f(yg_l[((size_t)(b * 8 + (d >> 4)) * LTOT + loff + l0 + l) * 16 + (d & 15)]);
    s_ygT[d * 20 + l] = v;
  }
  __syncthreads();
  {
    int c = tid & 63, lg = (tid >> 6) * 4;
    float acc[4] = {0.f, 0.f, 0.f, 0.f};
    const float* W = Wout + lvl * 128 * 64 + c;
    for (int dq = 0; dq < 128; ++dq) {
      float w = W[dq * 64];
      float4 yv = *(const float4*)&s_ygT[dq * 20 + lg];
      acc[0] = fmaf(w, yv.x, acc[0]);
      acc[1] = fmaf(w, yv.y, acc[1]);
      acc[2] = fmaf(w, yv.z, acc[2]);
      acc[3] = fmaf(w, yv.w, acc[3]);
    }
#pragma unroll
    for (int a = 0; a < 4; ++a) s_o[(lg + a) * 64 + c] = acc[a];
  }
  __syncthreads();
  for (int i = tid; i < 16 * 64; i += 256) {
    int c = i >> 4, l = i & 15;
    if (l < nl)
      fout[((size_t)(b * 64) + c) * LTOT + loff + l0 + l] =
          s_o[l * 64 + c] + fx[((size_t)(b * 64) + c) * L + l0 + l];
  }
}

// ----------- bilinear resize + concat -> (b,l,c) fp32 + bf16 -----------------
__global__ __launch_bounds__(256) void k_resize(const float* __restrict__ fout,
                                                float* __restrict__ xTf,
                                                u16* __restrict__ xTb) {
  int i = blockIdx.x * 256 + threadIdx.x;   // B*2304*256, ch fastest
  int ch = i & 255;
  int rem = i >> 8;
  int hw = rem % 2304;
  int b = rem / 2304;
  int oh = hw / 48, ow = hw - oh * 48;
  int lvl = ch >> 6, c = ch & 63;
  int s = S4[lvl];
  const float* base = fout + ((size_t)(b * 64) + c) * LTOT + LOFF4[lvl];
  float scl = (float)(s - 1) * (1.f / 47.f);
  float fy = oh * scl, fxx = ow * scl;
  int y0 = (int)floorf(fy), x0 = (int)floorf(fxx);
  float wy = fy - y0, wx = fxx - x0;
  int y1 = min(y0 + 1, s - 1), x1 = min(x0 + 1, s - 1);
  float v00 = base[y0 * s + x0], v01 = base[y0 * s + x1];
  float v10 = base[y1 * s + x0], v11 = base[y1 * s + x1];
  float top = v00 * (1.f - wx) + v01 * wx;
  float bot = v10 * (1.f - wx) + v11 * wx;
  float v = top * (1.f - wy) + bot * wy;
  xTf[i] = v;
  xTb[i] = f2b(v);
}

// ----------------- cross input GEMM via MFMA: xT @ WinT^T --------------------
// M=4608 (b*l), N=1024 (j), K=256 (c). BM=64 BN=128 BK=64, 4 waves (32x64).
__global__ __launch_bounds__(256) void k_gemm_mfma(
    const u16* __restrict__ xT,   // (4608, 256) bf16
    const u16* __restrict__ WT,   // (1024, 256) bf16
    u16* __restrict__ xs_c, u16* __restrict__ z_c) {
  __shared__ __align__(16) u16 s_a[64 * 72];
  __shared__ __align__(16) u16 s_b[128 * 72];
  int bid = blockIdx.x;            // 72 * 8
  int nj = bid & 7, bm = bid >> 3;
  int tid = threadIdx.x;
  int lane = tid & 63, w = tid >> 6;
  int wm = (w & 1) * 32, wn = (w >> 1) * 64;
  const int m_base = bm * 64;
  const int n_base = nj * 128;

  f32x4 acc[2][4];
#pragma unroll
  for (int mi = 0; mi < 2; ++mi)
#pragma unroll
    for (int ni = 0; ni < 4; ++ni) acc[mi][ni] = {0.f, 0.f, 0.f, 0.f};

  // A tile: 64 rows x 64 k = 512 u16x8 vectors (2/thread)
  // B tile: 128 rows x 64 k = 1024 u16x8 vectors (4/thread)
  u16x8 ra0, ra1, rb0, rb1, rb2, rb3;
  auto ld = [&](int c0) {
#pragma unroll
    for (int s = 0; s < 2; ++s) {
      int v = s * 256 + tid;
      int row = v >> 3, kc = (v & 7) * 8;
      u16x8 t = *(const u16x8*)&xT[(size_t)(m_base + row) * 256 + c0 + kc];
      if (s == 0) ra0 = t; else ra1 = t;
    }
#pragma unroll
    for (int s = 0; s < 4; ++s) {
      int v = s * 256 + tid;
      int row = v >> 3, kc = (v & 7) * 8;
      u16x8 t = *(const u16x8*)&WT[(size_t)(n_base + row) * 256 + c0 + kc];
      if (s == 0) rb0 = t; else if (s == 1) rb1 = t;
      else if (s == 2) rb2 = t; else rb3 = t;
    }
  };
  auto st = [&]() {
#pragma unroll
    for (int s = 0; s < 2; ++s) {
      int v = s * 256 + tid;
      int row = v >> 3, kc = (v & 7) * 8;
      *(u16x8*)&s_a[row * 72 + kc] = (s == 0) ? ra0 : ra1;
    }
#pragma unroll
    for (int s = 0; s < 4; ++s) {
      int v = s * 256 + tid;
      int row = v >> 3, kc = (v & 7) * 8;
      const u16x8& t = (s == 0) ? rb0 : (s == 1) ? rb1 : (s == 2) ? rb2 : rb3;
      *(u16x8*)&s_b[row * 72 + kc] = t;
    }
  };
  ld(0);
  int mlane = lane & 15, kg = (lane >> 4) * 8;
  for (int kt = 0; kt < 4; ++kt) {
    st();
    __syncthreads();
    if (kt < 3) ld((kt + 1) * 64);
#pragma unroll
    for (int kk = 0; kk < 2; ++kk) {
      int k0 = kk * 32 + kg;
      bf16x8 af[2], bfr[4];
#pragma unroll
      for (int mi = 0; mi < 2; ++mi)
        af[mi] = *(const bf16x8*)&s_a[(wm + mi * 16 + mlane) * 72 + k0];
#pragma unroll
      for (int ni = 0; ni < 4; ++ni)
        bfr[ni] = *(const bf16x8*)&s_b[(wn + ni * 16 + mlane) * 72 + k0];
#pragma unroll
      for (int mi = 0; mi < 2; ++mi)
#pragma unroll
        for (int ni = 0; ni < 4; ++ni)
          acc[mi][ni] = __builtin_amdgcn_mfma_f32_16x16x32_bf16(
              af[mi], bfr[ni], acc[mi][ni], 0, 0, 0);
    }
    __syncthreads();
  }
  int rgrp = (lane >> 4) * 4;
#pragma unroll
  for (int mi = 0; mi < 2; ++mi) {
#pragma unroll
    for (int ni = 0; ni < 4; ++ni) {
      int n = n_base + wn + ni * 16 + mlane;
#pragma unroll
      for (int r = 0; r < 4; ++r) {
        int gm = m_base + wm + mi * 16 + rgrp + r;
        int b = gm >= 2304;
        int l = gm - b * 2304;
        u16 v = f2b(acc[mi][ni][r]);
        if (n < 512) {
          xs_c[((size_t)(b * LC) + l) * 512 + n] = v;
        } else {
          int dz = n - 512;
          z_c[((size_t)(b * 32 + (dz >> 4)) * LC + l) * 16 + (dz & 15)] = v;
        }
      }
    }
  }
}

// ------------- cross mid: conv + silu + dbc + dt (tile of 8 l) ---------------
__global__ __launch_bounds__(256) void k_mid_cr(
    const u16* __restrict__ xs_c,    // (B,2304,512) bf16
    const float* __restrict__ Wconv, // (512,4)
    const float* __restrict__ bconv,
    const float* __restrict__ WxT,   // (48,512)
    const float* __restrict__ Wdt,   // (16,512)
    const float* __restrict__ bdt, u16* __restrict__ u_c,
    u16* __restrict__ dt_c, u16* __restrict__ Bm_c, u16* __restrict__ Cm_c) {
  __shared__ __align__(16) u16 s_xs[11 * 512];
  __shared__ __align__(16) float s_u[8 * 516];
  __shared__ float s_dbc[8 * 48];
  int bid = blockIdx.x;  // B*288
  int b = bid / 288, tl = bid - b * 288;
  int l0 = tl * 8;
  int tid = threadIdx.x;
  for (int i = tid; i < 704; i += 256) {
    int r = i >> 6;
    int l = l0 - 3 + r;
    u16x8 v = {0, 0, 0, 0, 0, 0, 0, 0};
    if (l >= 0)
      v = *(const u16x8*)&xs_c[((size_t)(b * LC) + l) * 512 + (i & 63) * 8];
    *(u16x8*)&s_xs[i * 8] = v;
  }
  __syncthreads();
  for (int i = tid; i < 8 * 512; i += 256) {
    int l = i >> 9, d = i & 511;
    const float* wc = Wconv + d * 4;
    float a = bconv[d];
#pragma unroll
    for (int k = 0; k < 4; ++k) a = fmaf(wc[k], b2f(s_xs[(l + k) * 512 + d]), a);
    float uu = siluf(a);
    s_u[l * 516 + d] = uu;
    u_c[((size_t)(b * 32 + (d >> 4)) * LC + l0 + l) * 16 + (d & 15)] = f2b(uu);
  }
  __syncthreads();
  for (int i = tid; i < 8 * 48; i += 256) {
    int jj = i >> 3, l = i & 7;
    const float* wx = WxT + jj * 512;
    float a = 0.f;
#pragma unroll 4
    for (int d = 0; d < 512; d += 4) {
      float4 w4 = *(const float4*)&wx[d];
      float4 u4 = *(const float4*)&s_u[l * 516 + d];
      a = fmaf(w4.x, u4.x, a);
      a = fmaf(w4.y, u4.y, a);
      a = fmaf(w4.z, u4.z, a);
      a = fmaf(w4.w, u4.w, a);
    }
    s_dbc[l * 48 + jj] = a;
    if (jj >= 16) {
      int q = jj - 16;
      size_t gb = ((size_t)(b * LC) + l0 + l) * 16;
      if (q < 16) Bm_c[gb + q] = f2b(a);
      else        Cm_c[gb + (q - 16)] = f2b(a);
    }
  }
  __syncthreads();
  for (int i = tid; i < 8 * 512; i += 256) {
    int l = i >> 9, d = i & 511;
    float a = bdt[d];
#pragma unroll
    for (int r = 0; r < 16; ++r)
      a = fmaf(s_dbc[l * 48 + r], Wdt[r * 512 + d], a);
    dt_c[((size_t)(b * 32 + (d >> 4)) * LC + l0 + l) * 16 + (d & 15)] =
        f2b(softplusf(a));
  }
}

// --- final: out = relu(BN(projW @ (x + yg_c@Wout) + proj_b)), 8-l tiles ------
__global__ __launch_bounds__(256) void k_final(
    const float* __restrict__ xTf, const u16* __restrict__ yg_c,
    const float* __restrict__ Wt, const float* __restrict__ WP,
    const float* __restrict__ pb, const float* __restrict__ bng,
    const float* __restrict__ bnb, const float* __restrict__ bnm,
    const float* __restrict__ bnv, float* __restrict__ out) {
  __shared__ float s_xc[256 * 8];    // [c][l] 8 KB
  __shared__ float s_yg[512 * 8];    // [d][l] 16 KB
  __shared__ float s_w[32 * 64];     // weight K-tile 8 KB
  int bid = blockIdx.x;  // B*288
  int b = bid / 288, tl = bid - b * 288;
  int l0 = tl * 8;
  int tid = threadIdx.x;
  for (int i = tid; i < 2048; i += 256) {
    int c = i & 255, l = i >> 8;
    s_xc[c * 8 + l] = xTf[((size_t)(b * 2304) + l0 + l) * 256 + c];
  }
  for (int i = tid; i < 4096; i += 256) {
    int j = i & 15, l = (i >> 4) & 7, dt = i >> 7;
    s_yg[(dt * 16 + j) * 8 + l] =
        b2f(yg_c[((size_t)(b * 32 + dt) * LC + l0 + l) * 16 + j]);
  }
  int o = tid & 63, lg = (tid >> 6) * 2;
  float acc0 = 0.f, acc1 = 0.f;
  float4 r0, r1;
  auto ldT = [&](const float* W, int kt, float4& a0, float4& a1) {
#pragma unroll
    for (int s = 0; s < 2; ++s) {
      int idx = s * 256 + tid;
      int row = idx >> 4, c4 = (idx & 15) << 2;
      float4 v = *(const float4*)&W[(kt * 32 + row) * 64 + c4];
      if (s == 0) a0 = v; else a1 = v;
    }
  };
  auto stT = [&](const float4& a0, const float4& a1) {
#pragma unroll
    for (int s = 0; s < 2; ++s) {
      int idx = s * 256 + tid;
      int row = idx >> 4, c4 = (idx & 15) << 2;
      *(float4*)&s_w[row * 64 + c4] = (s == 0) ? a0 : a1;
    }
  };
  ldT(Wt, 0, r0, r1);
  __syncthreads();
  stT(r0, r1);
  __syncthreads();
  for (int kt = 0; kt < 8; ++kt) {
    if (kt < 7) ldT(Wt, kt + 1, r0, r1);
    else ldT(WP, 0, r0, r1);
#pragma unroll
    for (int cc = 0; cc < 32; ++cc) {
      float w = s_w[cc * 64 + o];
      float2 xv = *(const float2*)&s_xc[(kt * 32 + cc) * 8 + lg];
      acc0 = fmaf(w, xv.x, acc0);
      acc1 = fmaf(w, xv.y, acc1);
    }
    __syncthreads();
    stT(r0, r1);
    __syncthreads();
  }
  for (int kt = 0; kt < 16; ++kt) {
    if (kt < 15) ldT(WP, kt + 1, r0, r1);
#pragma unroll
    for (int cc = 0; cc < 32; ++cc) {
      float w = s_w[cc * 64 + o];
      float2 yv = *(const float2*)&s_yg[(kt * 32 + cc) * 8 + lg];
      acc0 = fmaf(w, yv.x, acc0);
      acc1 = fmaf(w, yv.y, acc1);
    }
    __syncthreads();
    if (kt < 15) {
      stT(r0, r1);
      __syncthreads();
    }
  }
  float bias = pb[o], m = bnm[o], g = bng[o], v = bnv[o], bb = bnb[o];
  float scl = g * (1.f / sqrtf(v + 1e-5f));
  float2 r;
  r.x = fmaxf((acc0 + bias - m) * scl + bb, 0.f);
  r.y = fmaxf((acc1 + bias - m) * scl + bb, 0.f);
  *(float2*)&out[((size_t)(b * 64) + o) * LC + l0 + lg] = r;
}

// -----------------------------------------------------------------------------
extern "C" void kernel_launch(void* const* d_in, const int* in_sizes, int n_in,
                              void* d_out, int out_size, void* d_ws,
                              size_t ws_size, hipStream_t stream) {
  (void)in_sizes; (void)n_in; (void)out_size; (void)ws_size;
  const float* f0 = (const float*)d_in[0];
  const float* f1 = (const float*)d_in[1];
  const float* f2 = (const float*)d_in[2];
  const float* f3 = (const float*)d_in[3];
  const float* lWin   = (const float*)d_in[4];
  const float* lWconv = (const float*)d_in[5];
  const float* lbconv = (const float*)d_in[6];
  const float* lWx    = (const float*)d_in[7];
  const float* lWdt   = (const float*)d_in[8];
  const float* lbdt   = (const float*)d_in[9];
  const float* lAlog  = (const float*)d_in[10];
  const float* lD     = (const float*)d_in[11];
  const float* lWout  = (const float*)d_in[12];
  const float* cWin   = (const float*)d_in[13];
  const float* cWconv = (const float*)d_in[14];
  const float* cbconv = (const float*)d_in[15];
  const float* cWx    = (const float*)d_in[16];
  const float* cWdt   = (const float*)d_in[17];
  const float* cbdt   = (const float*)d_in[18];
  const float* cAlog  = (const float*)d_in[19];
  const float* cD     = (const float*)d_in[20];
  const float* cWout  = (const float*)d_in[21];
  const float* projW  = (const float*)d_in[22];
  const float* projb  = (const float*)d_in[23];
  const float* bng    = (const float*)d_in[24];
  const float* bnb    = (const float*)d_in[25];
  const float* bnm    = (const float*)d_in[26];
  const float* bnv    = (const float*)d_in[27];
  float* out = (float*)d_out;

  float* ws = (float*)d_ws;
  size_t off = 0;
  auto allocf = [&](size_t n) { float* p = ws + off; off += (n + 7) & ~(size_t)7; return p; };
  auto allocb = [&](size_t n) { u16* p = (u16*)(ws + off); off += ((n + 1) / 2 + 7) & ~(size_t)7; return p; };

  float* Wt     = allocf(256 * 64);
  float* WP     = allocf(512 * 64);
  float* WxT    = allocf(48 * 512);
  float* fout   = allocf((size_t)B_ * 64 * LTOT);
  float* xTf    = allocf((size_t)B_ * LC * 256);
  float* hloc_l = allocf((size_t)B_ * NCHL * 128 * 16);
  float* S_l    = allocf((size_t)B_ * NCHL * 128);
  float* hin_l  = allocf((size_t)B_ * NCHL * 128 * 16);
  float* hloc_c = allocf((size_t)B_ * NCHC * 512 * 16);
  float* S_c    = allocf((size_t)B_ * NCHC * 512);
  float* hin_c  = allocf((size_t)B_ * NCHC * 512 * 16);

  u16* WinT  = allocb(1024 * 256);
  u16* xTb   = allocb((size_t)B_ * LC * 256);
  u16* u_l2  = allocb((size_t)B_ * 8 * LTOT * 16);
  u16* dt_l2 = allocb((size_t)B_ * 8 * LTOT * 16);
  u16* z_l2  = allocb((size_t)B_ * 8 * LTOT * 16);
  u16* yg_l2 = allocb((size_t)B_ * 8 * LTOT * 16);
  u16* Bm_l2 = allocb((size_t)B_ * LTOT * 16);
  u16* Cm_l2 = allocb((size_t)B_ * LTOT * 16);
  u16* xs_c2 = allocb((size_t)B_ * LC * 512);
  u16* u_c2  = allocb((size_t)B_ * 32 * LC * 16);
  u16* dt_c2 = allocb((size_t)B_ * 32 * LC * 16);
  u16* z_c2  = allocb((size_t)B_ * 32 * LC * 16);
  u16* yg_c2 = allocb((size_t)B_ * 32 * LC * 16);
  u16* Bm_c2 = allocb((size_t)B_ * LC * 16);
  u16* Cm_c2 = allocb((size_t)B_ * LC * 16);

  k_prep<<<352, 256, 0, stream>>>(projW, cWout, cWin, cWx, Wt, WP, WinT, WxT);

  k_front_lvl<<<B_ * NTT, 256, 0, stream>>>(f0, f1, f2, f3, lWin, lWconv,
                                            lbconv, lWx, lWdt, lbdt, u_l2,
                                            dt_l2, Bm_l2, Cm_l2, z_l2);

  k_scan<0, 0><<<B_ * NCHL * 2, 256, 0, stream>>>(
      dt_l2, u_l2, Bm_l2, Cm_l2, nullptr, lAlog, lD, hloc_l, S_l, nullptr,
      nullptr);
  k_combine_lvl<<<64, 256, 0, stream>>>(lAlog, hloc_l, S_l, hin_l);
  k_scan<0, 1><<<B_ * NCHL * 2, 256, 0, stream>>>(
      dt_l2, u_l2, Bm_l2, Cm_l2, z_l2, lAlog, lD, nullptr, nullptr, hin_l,
      yg_l2);

  k_out_lvl<<<B_ * NTT, 256, 0, stream>>>(yg_l2, lWout, f0, f1, f2, f3, fout);
  k_resize<<<(B_ * 256 * LC) / 256, 256, 0, stream>>>(fout, xTf, xTb);

  k_gemm_mfma<<<72 * 8, 256, 0, stream>>>(xTb, WinT, xs_c2, z_c2);
  k_mid_cr<<<B_ * 288, 256, 0, stream>>>(xs_c2, cWconv, cbconv, WxT, cWdt,
                                         cbdt, u_c2, dt_c2, Bm_c2, Cm_c2);

  k_scan<1, 0><<<B_ * NCHC * 8, 256, 0, stream>>>(
      dt_c2, u_c2, Bm_c2, Cm_c2, nullptr, cAlog, cD, hloc_c, S_c, nullptr,
      nullptr);
  k_combine_cr<<<64, 256, 0, stream>>>(cAlog, hloc_c, S_c, hin_c);
  k_scan<1, 1><<<B_ * NCHC * 8, 256, 0, stream>>>(
      dt_c2, u_c2, Bm_c2, Cm_c2, z_c2, cAlog, cD, nullptr, nullptr, hin_c,
      yg_c2);

  k_final<<<B_ * 288, 256, 0, stream>>>(xTf, yg_c2, Wt, WP, projb, bng, bnb,
                                        bnm, bnv, out);
}

// Round 8
// 342.938 us; speedup vs baseline: 1.2565x; 1.0223x over previous
//
#include <hip/hip_runtime.h>
#include <cmath>

#define DEV __device__ __forceinline__

typedef unsigned short u16;
typedef u16 u16x8 __attribute__((ext_vector_type(8)));
typedef u16 u16x4 __attribute__((ext_vector_type(4)));
typedef short bf16x8 __attribute__((ext_vector_type(8)));
typedef float f32x4 __attribute__((ext_vector_type(4)));

constexpr int B_ = 2;
constexpr int S4[4]    = {48, 24, 12, 6};
constexpr int L4[4]    = {2304, 576, 144, 36};
constexpr int LOFF4[4] = {0, 2304, 2880, 3024};
constexpr int LTOT = 3060;
constexpr int TOFF4[4] = {0, 144, 180, 189};
constexpr int NTT = 192;
constexpr int NCH4[4]   = {36, 9, 3, 1};      // ceil(L/64)
constexpr int CHOFF4[4] = {0, 36, 45, 48};
constexpr int NCHL = 49;
constexpr int NCHC = 36;
constexpr int LC = 2304;
constexpr float LOG2E = 1.44269504088896f;

DEV float siluf(float x) { return x / (1.f + __expf(-x)); }
DEV float softplusf(float x) { return fmaxf(x, 0.f) + log1pf(__expf(-fabsf(x))); }
DEV float b2f(u16 x) { union { float f; unsigned u; } v; v.u = ((unsigned)x) << 16; return v.f; }
DEV u16 f2b(float f) {
  union { float f; unsigned u; } v; v.f = f;
  unsigned r = v.u + 0x7fffu + ((v.u >> 16) & 1u);
  return (u16)(r >> 16);
}

// ---- prep: Wt=projW^T | WP=cr_Wout@projW^T | WinT bf16 | WxT ---------------
__global__ __launch_bounds__(256) void k_prep(
    const float* __restrict__ projW, const float* __restrict__ crWout,
    const float* __restrict__ cWin, const float* __restrict__ cWx,
    float* __restrict__ Wt, float* __restrict__ WP,
    u16* __restrict__ WinT, float* __restrict__ WxT) {
  __shared__ float sm[64 * 65];
  int blk = blockIdx.x;
  int tid = threadIdx.x;
  if (blk < 64) {
    int i = blk * 256 + tid;   // 16384
    int o = i >> 8, c = i & 255;
    Wt[c * 64 + o] = projW[o * 256 + c];
  } else if (blk < 192) {
    int i = (blk - 64) * 256 + tid;   // 32768
    int d = i >> 6, o = i & 63;
    float acc = 0.f;
#pragma unroll 4
    for (int c = 0; c < 256; ++c)
      acc = fmaf(crWout[d * 256 + c], projW[o * 256 + c], acc);
    WP[d * 64 + o] = acc;
  } else if (blk < 256) {
    // transpose cr_Win (256,1024) -> WinT (1024,256) bf16, 64x64 tiles
    int t = blk - 192;
    int ct = t & 3, nt = t >> 2;
    int c0 = ct * 64, n0 = nt * 64;
    for (int i = tid; i < 4096; i += 256) {
      int cc = i >> 6, nn = i & 63;
      sm[cc * 65 + nn] = cWin[(size_t)(c0 + cc) * 1024 + n0 + nn];
    }
    __syncthreads();
    for (int i = tid; i < 4096; i += 256) {
      int nn = i >> 6, cc = i & 63;
      WinT[(size_t)(n0 + nn) * 256 + c0 + cc] = f2b(sm[cc * 65 + nn]);
    }
  } else {
    // WxT (48,512) from cr_Wx (512,48)
    int i = (blk - 256) * 256 + tid;   // 24576
    int d = i & 511, j = i >> 9;
    WxT[j * 512 + d] = cWx[d * 48 + j];
  }
}

// ------------- level front: in-GEMM + conv + silu + dbc + dt (fused) ---------
__global__ __launch_bounds__(256) void k_front_lvl(
    const float* __restrict__ f0, const float* __restrict__ f1,
    const float* __restrict__ f2, const float* __restrict__ f3,
    const float* __restrict__ Win,   // (4,64,256)
    const float* __restrict__ Wconv, // (4,128,4)
    const float* __restrict__ bconv, // (4,128)
    const float* __restrict__ Wx,    // (4,128,36)
    const float* __restrict__ Wdt,   // (4,4,128)
    const float* __restrict__ bdt,   // (4,128)
    u16* __restrict__ u_l, u16* __restrict__ dt_l,
    u16* __restrict__ Bm_l, u16* __restrict__ Cm_l, u16* __restrict__ z_l) {
  __shared__ float s_x[64 * 20];
  __shared__ float s_xs[19 * 128];
  __shared__ float s_u[16 * 132];
  __shared__ float s_dbc[16 * 36];
  int bid = blockIdx.x;              // B*NTT
  int b = bid / NTT, t = bid - b * NTT;
  int lvl = 0;
  while (lvl < 3 && t >= TOFF4[lvl + 1]) ++lvl;
  int tl = t - TOFF4[lvl];
  int L = L4[lvl], loff = LOFF4[lvl];
  int l0 = tl * 16;
  int nl = min(16, L - l0);
  const float* fx = lvl == 0 ? f0 : lvl == 1 ? f1 : lvl == 2 ? f2 : f3;
  int tid = threadIdx.x;

  for (int i = tid; i < 64 * 20; i += 256) {
    int c = i / 20, r = i - c * 20;
    int l = l0 - 3 + r;
    float v = 0.f;
    if (r < 19 && l >= 0 && l < L) v = fx[(size_t)(b * 64 + c) * L + l];
    s_x[i] = v;
  }
  __syncthreads();
  {  // xz GEMM: 19 rows x 256 cols, K=64
    int j = tid;
    float acc[19];
#pragma unroll
    for (int r = 0; r < 19; ++r) acc[r] = 0.f;
    const float* W = Win + lvl * 64 * 256 + j;
    for (int c = 0; c < 64; ++c) {
      float w = W[c * 256];
#pragma unroll
      for (int r = 0; r < 19; ++r) acc[r] = fmaf(w, s_x[c * 20 + r], acc[r]);
    }
    if (j < 128) {
#pragma unroll
      for (int r = 0; r < 19; ++r) s_xs[r * 128 + j] = acc[r];
    } else {
      int d = j - 128;
      int dti = d >> 4, jj = d & 15;
      for (int r = 3; r < 19; ++r) {
        int l = l0 - 3 + r;
        if (l < l0 + nl)
          z_l[((size_t)(b * 8 + dti) * LTOT + loff + l) * 16 + jj] = f2b(acc[r]);
      }
    }
  }
  __syncthreads();
  for (int i = tid; i < 16 * 128; i += 256) {
    int l = i >> 7, d = i & 127;
    if (l < nl) {
      const float* wc = Wconv + (lvl * 128 + d) * 4;
      float a = bconv[lvl * 128 + d];
#pragma unroll
      for (int k = 0; k < 4; ++k) a = fmaf(wc[k], s_xs[(l + k) * 128 + d], a);
      float uu = siluf(a);
      s_u[l * 132 + d] = uu;
      u_l[((size_t)(b * 8 + (d >> 4)) * LTOT + loff + l0 + l) * 16 + (d & 15)] = f2b(uu);
    }
  }
  __syncthreads();
  for (int i = tid; i < 16 * 36; i += 256) {
    int l = i & 15, jj = i >> 4;
    if (l < nl) {
      const float* wx = Wx + lvl * 128 * 36 + jj;
      float a = 0.f;
      for (int d = 0; d < 128; ++d) a = fmaf(s_u[l * 132 + d], wx[d * 36], a);
      s_dbc[l * 36 + jj] = a;
      if (jj >= 4) {
        int q = jj - 4;
        size_t gb = ((size_t)(b * LTOT) + loff + l0 + l) * 16;
        if (q < 16) Bm_l[gb + q] = f2b(a);
        else        Cm_l[gb + (q - 16)] = f2b(a);
      }
    }
  }
  __syncthreads();
  for (int i = tid; i < 16 * 128; i += 256) {
    int l = i >> 7, d = i & 127;
    if (l < nl) {
      float a = bdt[lvl * 128 + d];
#pragma unroll
      for (int r = 0; r < 4; ++r)
        a = fmaf(s_dbc[l * 36 + r], Wdt[(lvl * 4 + r) * 128 + d], a);
      dt_l[((size_t)(b * 8 + (d >> 4)) * LTOT + loff + l0 + l) * 16 + (d & 15)] =
          f2b(softplusf(a));
    }
  }
}

// ------------------ chunked scan (CH=64), 4 states/thread --------------------
// Block = 256 thr = 64 d x 4 lanes; each thread owns n = n0..n0+3 of one d.
// MODE 0 = levels (DI=128, NB=2), MODE 1 = cross (DI=512, NB=8).
template <int MODE, int PASSC>
__global__ __launch_bounds__(256) void k_scan(
    const u16* __restrict__ dtb, const u16* __restrict__ ub,
    const u16* __restrict__ Bmb, const u16* __restrict__ Cmb,
    const u16* __restrict__ zb,
    const float* __restrict__ Alog, const float* __restrict__ Dsk,
    float* __restrict__ hloc, float* __restrict__ Ssum,
    const float* __restrict__ hin, u16* __restrict__ yg) {
  constexpr int DI = MODE ? 512 : 128;
  constexpr int NDT = DI / 16;
  constexpr int NB = DI / 64;
  constexpr int NCHT = MODE ? NCHC : NCHL;
  constexpr int LT = MODE ? LC : LTOT;
  __shared__ __align__(16) u16 smem[PASSC ? 14336 : 9216];
  u16* s_dt = smem;                 // [4][64*16]
  u16* s_u  = smem + 4096;          // [4][64*16]
  u16* s_B  = smem + 8192;          // [64][16]
  u16* s_C  = PASSC ? smem + 9216 : nullptr;   // [64][16]
  u16* s_y  = PASSC ? smem + 10240 : nullptr;  // [64][64]

  int bid = blockIdx.x;
  int dblk = bid % NB;
  int rem = bid / NB;
  int gc = rem % NCHT;
  int b = rem / NCHT;
  int lvl = 0, ch = gc, Lq = LC, loff = 0;
  if (MODE == 0) {
    while (lvl < 3 && gc >= CHOFF4[lvl + 1]) ++lvl;
    ch = gc - CHOFF4[lvl];
    Lq = L4[lvl];
    loff = LOFF4[lvl];
  }
  int l0 = ch * 64;
  int len = min(64, Lq - l0);
  int labs0 = loff + l0;
  int tid = threadIdx.x;
  int q = tid & 3;                 // n-group lane
  int dl = (tid >> 2) & 15;        // d within tile
  int ti_l = tid >> 6;             // local d-tile 0..3
  int dti = dblk * 4 + ti_l;
  int d = dti * 16 + dl;
  int n0 = q * 4;

  // stage dt/u (4 d-tiles) and B (+C)
  for (int ti = 0; ti < 4; ++ti) {
    size_t g2 = ((size_t)(b * NDT + dblk * 4 + ti) * LT + labs0) * 16;
    const u16x8* pdt = (const u16x8*)(dtb + g2);
    const u16x8* pu  = (const u16x8*)(ub + g2);
    for (int i = tid; i < len * 2; i += 256) {
      *(u16x8*)&s_dt[ti * 1024 + i * 8] = pdt[i];
      *(u16x8*)&s_u [ti * 1024 + i * 8] = pu[i];
    }
  }
  {
    size_t gB = ((size_t)b * LT + labs0) * 16;
    for (int i = tid; i < len * 2; i += 256) {
      *(u16x8*)&s_B[i * 8] = *(const u16x8*)&Bmb[gB + i * 8];
      if (PASSC) *(u16x8*)&s_C[i * 8] = *(const u16x8*)&Cmb[gB + i * 8];
    }
  }
  __syncthreads();

  int ai = (MODE ? d : lvl * 128 + d);
  float4 al = *(const float4*)&Alog[ai * 16 + n0];
  float kA2[4] = {-__expf(al.x) * LOG2E, -__expf(al.y) * LOG2E,
                  -__expf(al.z) * LOG2E, -__expf(al.w) * LOG2E};
  size_t hix = (((size_t)(b * NCHT) + gc) * DI + d) * 16 + n0;
  float h[4] = {0.f, 0.f, 0.f, 0.f};
  if (PASSC) {
    float4 hv = *(const float4*)&hin[hix];
    h[0] = hv.x; h[1] = hv.y; h[2] = hv.z; h[3] = hv.w;
  }
  float dsk = PASSC ? Dsk[ai] : 0.f;
  float ss = 0.f;

  for (int l = 0; l < len; ++l) {
    float dt = b2f(s_dt[ti_l * 1024 + l * 16 + dl]);
    float uu = b2f(s_u [ti_l * 1024 + l * 16 + dl]);
    float dtu = dt * uu;
    u16x4 Bv = *(const u16x4*)&s_B[l * 16 + n0];
    if (PASSC) {
      u16x4 Cv = *(const u16x4*)&s_C[l * 16 + n0];
      float p = 0.f;
#pragma unroll
      for (int i = 0; i < 4; ++i) {
        float dA = exp2f(kA2[i] * dt);
        h[i] = fmaf(dA, h[i], dtu * b2f(Bv[i]));
        p = fmaf(h[i], b2f(Cv[i]), p);
      }
      p += __shfl_xor(p, 1, 4);
      p += __shfl_xor(p, 2, 4);
      if (q == 0) s_y[l * 64 + ti_l * 16 + dl] = f2b(fmaf(uu, dsk, p));
    } else {
#pragma unroll
      for (int i = 0; i < 4; ++i) {
        float dA = exp2f(kA2[i] * dt);
        h[i] = fmaf(dA, h[i], dtu * b2f(Bv[i]));
      }
      ss += dt;
    }
  }
  if (!PASSC) {
    f32x4 hv = {h[0], h[1], h[2], h[3]};
    *(f32x4*)&hloc[hix] = hv;
    if (q == 0) Ssum[((size_t)(b * NCHT) + gc) * DI + d] = ss;
  } else {
    __syncthreads();
    for (int ti = 0; ti < 4; ++ti) {
      size_t g2 = ((size_t)(b * NDT + dblk * 4 + ti) * LT + labs0) * 16;
      for (int i = tid; i < len * 2; i += 256) {
        u16x8 zv = *(const u16x8*)&zb[g2 + i * 8];
        u16x8 yv = *(const u16x8*)&s_y[(i >> 1) * 64 + ti * 16 + (i & 1) * 8];
        u16x8 o;
#pragma unroll
        for (int j = 0; j < 8; ++j) {
          float z = b2f(zv[j]);
          float gate = z / (1.f + __expf(-z));
          o[j] = f2b(b2f(yv[j]) * gate);
        }
        *(u16x8*)&yg[g2 + i * 8] = o;
      }
    }
  }
}

__global__ __launch_bounds__(256) void k_combine_lvl(
    const float* __restrict__ Alog, const float* __restrict__ hloc,
    const float* __restrict__ Ssum, float* __restrict__ hin) {
  int i = blockIdx.x * 256 + threadIdx.x;   // 16384
  int n = i & 15, d = (i >> 4) & 127, lvl = (i >> 11) & 3, b = i >> 13;
  float kA2 = -__expf(Alog[(lvl * 128 + d) * 16 + n]) * LOG2E;
  float h = 0.f;
  int nch = NCH4[lvl];
  for (int ch = 0; ch < nch; ++ch) {
    int gc = CHOFF4[lvl] + ch;
    size_t ix = (((size_t)(b * NCHL) + gc) * 128 + d) * 16 + n;
    hin[ix] = h;
    float S = Ssum[((size_t)(b * NCHL) + gc) * 128 + d];
    h = fmaf(exp2f(kA2 * S), h, hloc[ix]);
  }
}

__global__ __launch_bounds__(256) void k_combine_cr(
    const float* __restrict__ Alog, const float* __restrict__ hloc,
    const float* __restrict__ Ssum, float* __restrict__ hin) {
  int i = blockIdx.x * 256 + threadIdx.x;   // 16384
  int n = i & 15, d = (i >> 4) & 511, b = i >> 13;
  float kA2 = -__expf(Alog[d * 16 + n]) * LOG2E;
  float h = 0.f;
  for (int ch = 0; ch < NCHC; ++ch) {
    size_t ix = (((size_t)(b * NCHC) + ch) * 512 + d) * 16 + n;
    hin[ix] = h;
    float S = Ssum[((size_t)(b * NCHC) + ch) * 512 + d];
    h = fmaf(exp2f(kA2 * S), h, hloc[ix]);
  }
}

// --------------- level out-GEMM + residual, store (B,C,L) CHW ----------------
__global__ __launch_bounds__(256) void k_out_lvl(
    const u16* __restrict__ yg_l, const float* __restrict__ Wout, // (4,128,64)
    const float* __restrict__ f0, const float* __restrict__ f1,
    const float* __restrict__ f2, const float* __restrict__ f3,
    float* __restrict__ fout) {
  __shared__ float s_ygT[128 * 20];   // [d][l], stride 20
  __shared__ float s_o[16 * 64];
  int bid = blockIdx.x;  // B*NTT
  int b = bid / NTT, t = bid - b * NTT;
  int lvl = 0;
  while (lvl < 3 && t >= TOFF4[lvl + 1]) ++lvl;
  int tl = t - TOFF4[lvl];
  int L = L4[lvl], loff = LOFF4[lvl];
  int l0 = tl * 16, nl = min(16, L - l0);
  const float* fx = lvl == 0 ? f0 : lvl == 1 ? f1 : lvl == 2 ? f2 : f3;
  int tid = threadIdx.x;
  for (int i = tid; i < 16 * 128; i += 256) {
    int d = i & 127, l = i >> 7;
    float v = 0.f;
    if (l < nl)
      v = b2f(yg_l[((size_t)(b * 8 + (d >> 4)) * LTOT + loff + l0 + l) * 16 + (d & 15)]);
    s_ygT[d * 20 + l] = v;
  }
  __syncthreads();
  {
    int c = tid & 63, lg = (tid >> 6) * 4;
    float acc[4] = {0.f, 0.f, 0.f, 0.f};
    const float* W = Wout + lvl * 128 * 64 + c;
    for (int dq = 0; dq < 128; ++dq) {
      float w = W[dq * 64];
      float4 yv = *(const float4*)&s_ygT[dq * 20 + lg];
      acc[0] = fmaf(w, yv.x, acc[0]);
      acc[1] = fmaf(w, yv.y, acc[1]);
      acc[2] = fmaf(w, yv.z, acc[2]);
      acc[3] = fmaf(w, yv.w, acc[3]);
    }
#pragma unroll
    for (int a = 0; a < 4; ++a) s_o[(lg + a) * 64 + c] = acc[a];
  }
  __syncthreads();
  for (int i = tid; i < 16 * 64; i += 256) {
    int c = i >> 4, l = i & 15;
    if (l < nl)
      fout[((size_t)(b * 64) + c) * LTOT + loff + l0 + l] =
          s_o[l * 64 + c] + fx[((size_t)(b * 64) + c) * L + l0 + l];
  }
}

// ----------- bilinear resize + concat -> (b,l,c) fp32 + bf16 -----------------
__global__ __launch_bounds__(256) void k_resize(const float* __restrict__ fout,
                                                float* __restrict__ xTf,
                                                u16* __restrict__ xTb) {
  int i = blockIdx.x * 256 + threadIdx.x;   // B*2304*256, ch fastest
  int ch = i & 255;
  int rem = i >> 8;
  int hw = rem % 2304;
  int b = rem / 2304;
  int oh = hw / 48, ow = hw - oh * 48;
  int lvl = ch >> 6, c = ch & 63;
  int s = S4[lvl];
  const float* base = fout + ((size_t)(b * 64) + c) * LTOT + LOFF4[lvl];
  float scl = (float)(s - 1) * (1.f / 47.f);
  float fy = oh * scl, fxx = ow * scl;
  int y0 = (int)floorf(fy), x0 = (int)floorf(fxx);
  float wy = fy - y0, wx = fxx - x0;
  int y1 = min(y0 + 1, s - 1), x1 = min(x0 + 1, s - 1);
  float v00 = base[y0 * s + x0], v01 = base[y0 * s + x1];
  float v10 = base[y1 * s + x0], v11 = base[y1 * s + x1];
  float top = v00 * (1.f - wx) + v01 * wx;
  float bot = v10 * (1.f - wx) + v11 * wx;
  float v = top * (1.f - wy) + bot * wy;
  xTf[i] = v;
  xTb[i] = f2b(v);
}

// ----------------- cross input GEMM via MFMA: xT @ WinT^T --------------------
// M=4608 (b*l), N=1024 (j), K=256 (c). BM=64 BN=128 BK=64, 4 waves (32x64).
__global__ __launch_bounds__(256) void k_gemm_mfma(
    const u16* __restrict__ xT,   // (4608, 256) bf16
    const u16* __restrict__ WT,   // (1024, 256) bf16
    u16* __restrict__ xs_c, u16* __restrict__ z_c) {
  __shared__ __align__(16) u16 s_a[64 * 72];
  __shared__ __align__(16) u16 s_b[128 * 72];
  int bid = blockIdx.x;            // 72 * 8
  int nj = bid & 7, bm = bid >> 3;
  int tid = threadIdx.x;
  int lane = tid & 63, w = tid >> 6;
  int wm = (w & 1) * 32, wn = (w >> 1) * 64;
  const int m_base = bm * 64;
  const int n_base = nj * 128;

  f32x4 acc[2][4];
#pragma unroll
  for (int mi = 0; mi < 2; ++mi)
#pragma unroll
    for (int ni = 0; ni < 4; ++ni) acc[mi][ni] = {0.f, 0.f, 0.f, 0.f};

  // A tile: 64 rows x 64 k = 512 u16x8 vectors (2/thread)
  // B tile: 128 rows x 64 k = 1024 u16x8 vectors (4/thread)
  u16x8 ra0, ra1, rb0, rb1, rb2, rb3;
  auto ld = [&](int c0) {
#pragma unroll
    for (int s = 0; s < 2; ++s) {
      int v = s * 256 + tid;
      int row = v >> 3, kc = (v & 7) * 8;
      u16x8 t = *(const u16x8*)&xT[(size_t)(m_base + row) * 256 + c0 + kc];
      if (s == 0) ra0 = t; else ra1 = t;
    }
#pragma unroll
    for (int s = 0; s < 4; ++s) {
      int v = s * 256 + tid;
      int row = v >> 3, kc = (v & 7) * 8;
      u16x8 t = *(const u16x8*)&WT[(size_t)(n_base + row) * 256 + c0 + kc];
      if (s == 0) rb0 = t; else if (s == 1) rb1 = t;
      else if (s == 2) rb2 = t; else rb3 = t;
    }
  };
  auto st = [&]() {
#pragma unroll
    for (int s = 0; s < 2; ++s) {
      int v = s * 256 + tid;
      int row = v >> 3, kc = (v & 7) * 8;
      *(u16x8*)&s_a[row * 72 + kc] = (s == 0) ? ra0 : ra1;
    }
#pragma unroll
    for (int s = 0; s < 4; ++s) {
      int v = s * 256 + tid;
      int row = v >> 3, kc = (v & 7) * 8;
      const u16x8& t = (s == 0) ? rb0 : (s == 1) ? rb1 : (s == 2) ? rb2 : rb3;
      *(u16x8*)&s_b[row * 72 + kc] = t;
    }
  };
  ld(0);
  int mlane = lane & 15, kg = (lane >> 4) * 8;
  for (int kt = 0; kt < 4; ++kt) {
    st();
    __syncthreads();
    if (kt < 3) ld((kt + 1) * 64);
#pragma unroll
    for (int kk = 0; kk < 2; ++kk) {
      int k0 = kk * 32 + kg;
      bf16x8 af[2], bfr[4];
#pragma unroll
      for (int mi = 0; mi < 2; ++mi)
        af[mi] = *(const bf16x8*)&s_a[(wm + mi * 16 + mlane) * 72 + k0];
#pragma unroll
      for (int ni = 0; ni < 4; ++ni)
        bfr[ni] = *(const bf16x8*)&s_b[(wn + ni * 16 + mlane) * 72 + k0];
#pragma unroll
      for (int mi = 0; mi < 2; ++mi)
#pragma unroll
        for (int ni = 0; ni < 4; ++ni)
          acc[mi][ni] = __builtin_amdgcn_mfma_f32_16x16x32_bf16(
              af[mi], bfr[ni], acc[mi][ni], 0, 0, 0);
    }
    __syncthreads();
  }
  int rgrp = (lane >> 4) * 4;
#pragma unroll
  for (int mi = 0; mi < 2; ++mi) {
#pragma unroll
    for (int ni = 0; ni < 4; ++ni) {
      int n = n_base + wn + ni * 16 + mlane;
#pragma unroll
      for (int r = 0; r < 4; ++r) {
        int gm = m_base + wm + mi * 16 + rgrp + r;
        int b = gm >= 2304;
        int l = gm - b * 2304;
        u16 v = f2b(acc[mi][ni][r]);
        if (n < 512) {
          xs_c[((size_t)(b * LC) + l) * 512 + n] = v;
        } else {
          int dz = n - 512;
          z_c[((size_t)(b * 32 + (dz >> 4)) * LC + l) * 16 + (dz & 15)] = v;
        }
      }
    }
  }
}

// -------- cross mid: conv + silu + dbc + dt, 16-l tiles, 1024 threads --------
__global__ __launch_bounds__(1024) void k_mid_cr(
    const u16* __restrict__ xs_c,    // (B,2304,512) bf16
    const float* __restrict__ Wconv, // (512,4)
    const float* __restrict__ bconv,
    const float* __restrict__ WxT,   // (48,512)
    const float* __restrict__ Wdt,   // (16,512)
    const float* __restrict__ bdt, u16* __restrict__ u_c,
    u16* __restrict__ dt_c, u16* __restrict__ Bm_c, u16* __restrict__ Cm_c) {
  __shared__ __align__(16) u16 s_xs[19 * 512];     // 19456 B
  __shared__ __align__(16) u16 s_ub[16 * 520];     // 16640 B (pad 8 -> 2-way free)
  __shared__ __align__(16) float s_wx[48 * 132];   // 25344 B (pad 4 banks/row)
  __shared__ float s_dbc[16 * 48];                 // 3072 B
  int bid = blockIdx.x;  // B*144
  int b = bid / 144, tl = bid - b * 144;
  int l0 = tl * 16;
  int tid = threadIdx.x;
  // stage xs rows l0-3 .. l0+15
  for (int i = tid; i < 19 * 64; i += 1024) {
    int r = i >> 6, c8 = (i & 63) * 8;
    int l = l0 - 3 + r;
    u16x8 v = {0, 0, 0, 0, 0, 0, 0, 0};
    if (l >= 0)
      v = *(const u16x8*)&xs_c[((size_t)(b * LC) + l) * 512 + c8];
    *(u16x8*)&s_xs[r * 512 + c8] = v;
  }
  __syncthreads();
  // conv + silu -> s_ub (bf16) + u_c global
  for (int i = tid; i < 16 * 512; i += 1024) {
    int l = i >> 9, d = i & 511;
    const float* wc = Wconv + d * 4;
    float a = bconv[d];
#pragma unroll
    for (int k = 0; k < 4; ++k) a = fmaf(wc[k], b2f(s_xs[(l + k) * 512 + d]), a);
    float uu = siluf(a);
    u16 ub = f2b(uu);
    s_ub[l * 520 + d] = ub;
    u_c[((size_t)(b * 32 + (d >> 4)) * LC + l0 + l) * 16 + (d & 15)] = ub;
  }
  // dbc: 16 l x 48 j dots over K=512, WxT staged in 4 K-chunks of 128
  int dl = tid & 15, jj = tid >> 4;   // valid for tid < 768
  float a8[8] = {0.f, 0.f, 0.f, 0.f, 0.f, 0.f, 0.f, 0.f};
  for (int kt = 0; kt < 4; ++kt) {
    __syncthreads();
    for (int i = tid; i < 1536; i += 1024) {
      int row = i >> 5, c4 = (i & 31) * 4;
      *(float4*)&s_wx[row * 132 + c4] =
          *(const float4*)&WxT[row * 512 + kt * 128 + c4];
    }
    __syncthreads();
    if (tid < 768) {
      const u16* ur = s_ub + dl * 520 + kt * 128;
      const float* wr = s_wx + jj * 132;
#pragma unroll 4
      for (int kb = 0; kb < 16; ++kb) {
        u16x8 uv = *(const u16x8*)&ur[kb * 8];
        float4 w0 = *(const float4*)&wr[kb * 8];
        float4 w1 = *(const float4*)&wr[kb * 8 + 4];
        a8[0] = fmaf(b2f(uv[0]), w0.x, a8[0]);
        a8[1] = fmaf(b2f(uv[1]), w0.y, a8[1]);
        a8[2] = fmaf(b2f(uv[2]), w0.z, a8[2]);
        a8[3] = fmaf(b2f(uv[3]), w0.w, a8[3]);
        a8[4] = fmaf(b2f(uv[4]), w1.x, a8[4]);
        a8[5] = fmaf(b2f(uv[5]), w1.y, a8[5]);
        a8[6] = fmaf(b2f(uv[6]), w1.z, a8[6]);
        a8[7] = fmaf(b2f(uv[7]), w1.w, a8[7]);
      }
    }
  }
  if (tid < 768) {
    float a = ((a8[0] + a8[1]) + (a8[2] + a8[3])) +
              ((a8[4] + a8[5]) + (a8[6] + a8[7]));
    s_dbc[dl * 48 + jj] = a;
    if (jj >= 16) {
      int q = jj - 16;
      size_t gb = ((size_t)(b * LC) + l0 + dl) * 16;
      if (q < 16) Bm_c[gb + q] = f2b(a);
      else        Cm_c[gb + (q - 16)] = f2b(a);
    }
  }
  __syncthreads();
  // dt = softplus(dbc[:, :16] @ Wdt + bdt)
  for (int i = tid; i < 16 * 512; i += 1024) {
    int l = i >> 9, d = i & 511;
    float a = bdt[d];
#pragma unroll
    for (int r = 0; r < 16; ++r)
      a = fmaf(s_dbc[l * 48 + r], Wdt[r * 512 + d], a);
    dt_c[((size_t)(b * 32 + (d >> 4)) * LC + l0 + l) * 16 + (d & 15)] =
        f2b(softplusf(a));
  }
}

// --- final: out = relu(BN(projW @ (x + yg_c@Wout) + proj_b)), 8-l tiles ------
__global__ __launch_bounds__(256) void k_final(
    const float* __restrict__ xTf, const u16* __restrict__ yg_c,
    const float* __restrict__ Wt, const float* __restrict__ WP,
    const float* __restrict__ pb, const float* __restrict__ bng,
    const float* __restrict__ bnb, const float* __restrict__ bnm,
    const float* __restrict__ bnv, float* __restrict__ out) {
  __shared__ float s_xc[256 * 8];    // [c][l] 8 KB
  __shared__ float s_yg[512 * 8];    // [d][l] 16 KB
  __shared__ float s_w[32 * 64];     // weight K-tile 8 KB
  int bid = blockIdx.x;  // B*288
  int b = bid / 288, tl = bid - b * 288;
  int l0 = tl * 8;
  int tid = threadIdx.x;
  for (int i = tid; i < 2048; i += 256) {
    int c = i & 255, l = i >> 8;
    s_xc[c * 8 + l] = xTf[((size_t)(b * 2304) + l0 + l) * 256 + c];
  }
  for (int i = tid; i < 4096; i += 256) {
    int j = i & 15, l = (i >> 4) & 7, dt = i >> 7;
    s_yg[(dt * 16 + j) * 8 + l] =
        b2f(yg_c[((size_t)(b * 32 + dt) * LC + l0 + l) * 16 + j]);
  }
  int o = tid & 63, lg = (tid >> 6) * 2;
  float acc0 = 0.f, acc1 = 0.f;
  float4 r0, r1;
  auto ldT = [&](const float* W, int kt, float4& a0, float4& a1) {
#pragma unroll
    for (int s = 0; s < 2; ++s) {
      int idx = s * 256 + tid;
      int row = idx >> 4, c4 = (idx & 15) << 2;
      float4 v = *(const float4*)&W[(kt * 32 + row) * 64 + c4];
      if (s == 0) a0 = v; else a1 = v;
    }
  };
  auto stT = [&](const float4& a0, const float4& a1) {
#pragma unroll
    for (int s = 0; s < 2; ++s) {
      int idx = s * 256 + tid;
      int row = idx >> 4, c4 = (idx & 15) << 2;
      *(float4*)&s_w[row * 64 + c4] = (s == 0) ? a0 : a1;
    }
  };
  ldT(Wt, 0, r0, r1);
  __syncthreads();
  stT(r0, r1);
  __syncthreads();
  for (int kt = 0; kt < 8; ++kt) {
    if (kt < 7) ldT(Wt, kt + 1, r0, r1);
    else ldT(WP, 0, r0, r1);
#pragma unroll
    for (int cc = 0; cc < 32; ++cc) {
      float w = s_w[cc * 64 + o];
      float2 xv = *(const float2*)&s_xc[(kt * 32 + cc) * 8 + lg];
      acc0 = fmaf(w, xv.x, acc0);
      acc1 = fmaf(w, xv.y, acc1);
    }
    __syncthreads();
    stT(r0, r1);
    __syncthreads();
  }
  for (int kt = 0; kt < 16; ++kt) {
    if (kt < 15) ldT(WP, kt + 1, r0, r1);
#pragma unroll
    for (int cc = 0; cc < 32; ++cc) {
      float w = s_w[cc * 64 + o];
      float2 yv = *(const float2*)&s_yg[(kt * 32 + cc) * 8 + lg];
      acc0 = fmaf(w, yv.x, acc0);
      acc1 = fmaf(w, yv.y, acc1);
    }
    __syncthreads();
    if (kt < 15) {
      stT(r0, r1);
      __syncthreads();
    }
  }
  float bias = pb[o], m = bnm[o], g = bng[o], v = bnv[o], bb = bnb[o];
  float scl = g * (1.f / sqrtf(v + 1e-5f));
  float2 r;
  r.x = fmaxf((acc0 + bias - m) * scl + bb, 0.f);
  r.y = fmaxf((acc1 + bias - m) * scl + bb, 0.f);
  *(float2*)&out[((size_t)(b * 64) + o) * LC + l0 + lg] = r;
}

// -----------------------------------------------------------------------------
extern "C" void kernel_launch(void* const* d_in, const int* in_sizes, int n_in,
                              void* d_out, int out_size, void* d_ws,
                              size_t ws_size, hipStream_t stream) {
  (void)in_sizes; (void)n_in; (void)out_size; (void)ws_size;
  const float* f0 = (const float*)d_in[0];
  const float* f1 = (const float*)d_in[1];
  const float* f2 = (const float*)d_in[2];
  const float* f3 = (const float*)d_in[3];
  const float* lWin   = (const float*)d_in[4];
  const float* lWconv = (const float*)d_in[5];
  const float* lbconv = (const float*)d_in[6];
  const float* lWx    = (const float*)d_in[7];
  const float* lWdt   = (const float*)d_in[8];
  const float* lbdt   = (const float*)d_in[9];
  const float* lAlog  = (const float*)d_in[10];
  const float* lD     = (const float*)d_in[11];
  const float* lWout  = (const float*)d_in[12];
  const float* cWin   = (const float*)d_in[13];
  const float* cWconv = (const float*)d_in[14];
  const float* cbconv = (const float*)d_in[15];
  const float* cWx    = (const float*)d_in[16];
  const float* cWdt   = (const float*)d_in[17];
  const float* cbdt   = (const float*)d_in[18];
  const float* cAlog  = (const float*)d_in[19];
  const float* cD     = (const float*)d_in[20];
  const float* cWout  = (const float*)d_in[21];
  const float* projW  = (const float*)d_in[22];
  const float* projb  = (const float*)d_in[23];
  const float* bng    = (const float*)d_in[24];
  const float* bnb    = (const float*)d_in[25];
  const float* bnm    = (const float*)d_in[26];
  const float* bnv    = (const float*)d_in[27];
  float* out = (float*)d_out;

  float* ws = (float*)d_ws;
  size_t off = 0;
  auto allocf = [&](size_t n) { float* p = ws + off; off += (n + 7) & ~(size_t)7; return p; };
  auto allocb = [&](size_t n) { u16* p = (u16*)(ws + off); off += ((n + 1) / 2 + 7) & ~(size_t)7; return p; };

  float* Wt     = allocf(256 * 64);
  float* WP     = allocf(512 * 64);
  float* WxT    = allocf(48 * 512);
  float* fout   = allocf((size_t)B_ * 64 * LTOT);
  float* xTf    = allocf((size_t)B_ * LC * 256);
  float* hloc_l = allocf((size_t)B_ * NCHL * 128 * 16);
  float* S_l    = allocf((size_t)B_ * NCHL * 128);
  float* hin_l  = allocf((size_t)B_ * NCHL * 128 * 16);
  float* hloc_c = allocf((size_t)B_ * NCHC * 512 * 16);
  float* S_c    = allocf((size_t)B_ * NCHC * 512);
  float* hin_c  = allocf((size_t)B_ * NCHC * 512 * 16);

  u16* WinT  = allocb(1024 * 256);
  u16* xTb   = allocb((size_t)B_ * LC * 256);
  u16* u_l2  = allocb((size_t)B_ * 8 * LTOT * 16);
  u16* dt_l2 = allocb((size_t)B_ * 8 * LTOT * 16);
  u16* z_l2  = allocb((size_t)B_ * 8 * LTOT * 16);
  u16* yg_l2 = allocb((size_t)B_ * 8 * LTOT * 16);
  u16* Bm_l2 = allocb((size_t)B_ * LTOT * 16);
  u16* Cm_l2 = allocb((size_t)B_ * LTOT * 16);
  u16* xs_c2 = allocb((size_t)B_ * LC * 512);
  u16* u_c2  = allocb((size_t)B_ * 32 * LC * 16);
  u16* dt_c2 = allocb((size_t)B_ * 32 * LC * 16);
  u16* z_c2  = allocb((size_t)B_ * 32 * LC * 16);
  u16* yg_c2 = allocb((size_t)B_ * 32 * LC * 16);
  u16* Bm_c2 = allocb((size_t)B_ * LC * 16);
  u16* Cm_c2 = allocb((size_t)B_ * LC * 16);

  k_prep<<<352, 256, 0, stream>>>(projW, cWout, cWin, cWx, Wt, WP, WinT, WxT);

  k_front_lvl<<<B_ * NTT, 256, 0, stream>>>(f0, f1, f2, f3, lWin, lWconv,
                                            lbconv, lWx, lWdt, lbdt, u_l2,
                                            dt_l2, Bm_l2, Cm_l2, z_l2);

  k_scan<0, 0><<<B_ * NCHL * 2, 256, 0, stream>>>(
      dt_l2, u_l2, Bm_l2, Cm_l2, nullptr, lAlog, lD, hloc_l, S_l, nullptr,
      nullptr);
  k_combine_lvl<<<64, 256, 0, stream>>>(lAlog, hloc_l, S_l, hin_l);
  k_scan<0, 1><<<B_ * NCHL * 2, 256, 0, stream>>>(
      dt_l2, u_l2, Bm_l2, Cm_l2, z_l2, lAlog, lD, nullptr, nullptr, hin_l,
      yg_l2);

  k_out_lvl<<<B_ * NTT, 256, 0, stream>>>(yg_l2, lWout, f0, f1, f2, f3, fout);
  k_resize<<<(B_ * 256 * LC) / 256, 256, 0, stream>>>(fout, xTf, xTb);

  k_gemm_mfma<<<72 * 8, 256, 0, stream>>>(xTb, WinT, xs_c2, z_c2);
  k_mid_cr<<<B_ * 144, 1024, 0, stream>>>(xs_c2, cWconv, cbconv, WxT, cWdt,
                                          cbdt, u_c2, dt_c2, Bm_c2, Cm_c2);

  k_scan<1, 0><<<B_ * NCHC * 8, 256, 0, stream>>>(
      dt_c2, u_c2, Bm_c2, Cm_c2, nullptr, cAlog, cD, hloc_c, S_c, nullptr,
      nullptr);
  k_combine_cr<<<64, 256, 0, stream>>>(cAlog, hloc_c, S_c, hin_c);
  k_scan<1, 1><<<B_ * NCHC * 8, 256, 0, stream>>>(
      dt_c2, u_c2, Bm_c2, Cm_c2, z_c2, cAlog, cD, nullptr, nullptr, hin_c,
      yg_c2);

  k_final<<<B_ * 288, 256, 0, stream>>>(xTf, yg_c2, Wt, WP, projb, bng, bnb,
                                        bnm, bnv, out);
}

// Round 9
// 315.790 us; speedup vs baseline: 1.3645x; 1.0860x over previous
//
#include <hip/hip_runtime.h>
#include <cmath>

#define DEV __device__ __forceinline__

typedef unsigned short u16;
typedef u16 u16x8 __attribute__((ext_vector_type(8)));
typedef u16 u16x4 __attribute__((ext_vector_type(4)));
typedef short bf16x8 __attribute__((ext_vector_type(8)));
typedef float f32x4 __attribute__((ext_vector_type(4)));

constexpr int B_ = 2;
constexpr int S4[4]    = {48, 24, 12, 6};
constexpr int L4[4]    = {2304, 576, 144, 36};
constexpr int LOFF4[4] = {0, 2304, 2880, 3024};
constexpr int LTOT = 3060;
constexpr int TOFF4[4] = {0, 144, 180, 189};
constexpr int NTT = 192;
constexpr int NCH4[4]   = {72, 18, 5, 2};     // ceil(L/32)
constexpr int CHOFF4[4] = {0, 72, 90, 95};
constexpr int NCHL = 97;
constexpr int NCHC = 72;
constexpr int LC = 2304;
constexpr float LOG2E = 1.44269504088896f;

DEV float siluf(float x) { return x / (1.f + __expf(-x)); }
DEV float softplusf(float x) { return fmaxf(x, 0.f) + log1pf(__expf(-fabsf(x))); }
DEV float b2f(u16 x) { union { float f; unsigned u; } v; v.u = ((unsigned)x) << 16; return v.f; }
DEV u16 f2b(float f) {
  union { float f; unsigned u; } v; v.f = f;
  unsigned r = v.u + 0x7fffu + ((v.u >> 16) & 1u);
  return (u16)(r >> 16);
}

// -- prep: WPB=(crWout@projW^T)^T bf16 | WtB=projW bf16 | WinT bf16 | WxT -----
__global__ __launch_bounds__(256) void k_prep(
    const float* __restrict__ projW, const float* __restrict__ crWout,
    const float* __restrict__ cWin, const float* __restrict__ cWx,
    u16* __restrict__ WPB, u16* __restrict__ WtB,
    u16* __restrict__ WinT, float* __restrict__ WxT) {
  __shared__ float sm[64 * 65];
  int blk = blockIdx.x;
  int tid = threadIdx.x;
  if (blk < 128) {
    int i = blk * 256 + tid;   // 32768
    int d = i >> 6, o = i & 63;
    float acc = 0.f;
#pragma unroll 4
    for (int c = 0; c < 256; ++c)
      acc = fmaf(crWout[d * 256 + c], projW[o * 256 + c], acc);
    WPB[o * 512 + d] = f2b(acc);
  } else if (blk < 192) {
    int i = (blk - 128) * 256 + tid;   // 16384, (64 o, 256 c) row-major
    WtB[i] = f2b(projW[i]);
  } else if (blk < 256) {
    // transpose cr_Win (256,1024) -> WinT (1024,256) bf16, 64x64 tiles
    int t = blk - 192;
    int ct = t & 3, nt = t >> 2;
    int c0 = ct * 64, n0 = nt * 64;
    for (int i = tid; i < 4096; i += 256) {
      int cc = i >> 6, nn = i & 63;
      sm[cc * 65 + nn] = cWin[(size_t)(c0 + cc) * 1024 + n0 + nn];
    }
    __syncthreads();
    for (int i = tid; i < 4096; i += 256) {
      int nn = i >> 6, cc = i & 63;
      WinT[(size_t)(n0 + nn) * 256 + c0 + cc] = f2b(sm[cc * 65 + nn]);
    }
  } else {
    // WxT (48,512) from cr_Wx (512,48)
    int i = (blk - 256) * 256 + tid;   // 24576
    int d = i & 511, j = i >> 9;
    WxT[j * 512 + d] = cWx[d * 48 + j];
  }
}

// ------------- level front: in-GEMM + conv + silu + dbc + dt (fused) ---------
__global__ __launch_bounds__(256) void k_front_lvl(
    const float* __restrict__ f0, const float* __restrict__ f1,
    const float* __restrict__ f2, const float* __restrict__ f3,
    const float* __restrict__ Win,   // (4,64,256)
    const float* __restrict__ Wconv, // (4,128,4)
    const float* __restrict__ bconv, // (4,128)
    const float* __restrict__ Wx,    // (4,128,36)
    const float* __restrict__ Wdt,   // (4,4,128)
    const float* __restrict__ bdt,   // (4,128)
    u16* __restrict__ u_l, u16* __restrict__ dt_l,
    u16* __restrict__ Bm_l, u16* __restrict__ Cm_l, u16* __restrict__ z_l) {
  __shared__ float s_x[64 * 20];
  __shared__ float s_xs[19 * 128];
  __shared__ float s_u[16 * 132];
  __shared__ float s_dbc[16 * 36];
  int bid = blockIdx.x;              // B*NTT
  int b = bid / NTT, t = bid - b * NTT;
  int lvl = 0;
  while (lvl < 3 && t >= TOFF4[lvl + 1]) ++lvl;
  int tl = t - TOFF4[lvl];
  int L = L4[lvl], loff = LOFF4[lvl];
  int l0 = tl * 16;
  int nl = min(16, L - l0);
  const float* fx = lvl == 0 ? f0 : lvl == 1 ? f1 : lvl == 2 ? f2 : f3;
  int tid = threadIdx.x;

  for (int i = tid; i < 64 * 20; i += 256) {
    int c = i / 20, r = i - c * 20;
    int l = l0 - 3 + r;
    float v = 0.f;
    if (r < 19 && l >= 0 && l < L) v = fx[(size_t)(b * 64 + c) * L + l];
    s_x[i] = v;
  }
  __syncthreads();
  {  // xz GEMM: 19 rows x 256 cols, K=64
    int j = tid;
    float acc[19];
#pragma unroll
    for (int r = 0; r < 19; ++r) acc[r] = 0.f;
    const float* W = Win + lvl * 64 * 256 + j;
    for (int c = 0; c < 64; ++c) {
      float w = W[c * 256];
#pragma unroll
      for (int r = 0; r < 19; ++r) acc[r] = fmaf(w, s_x[c * 20 + r], acc[r]);
    }
    if (j < 128) {
#pragma unroll
      for (int r = 0; r < 19; ++r) s_xs[r * 128 + j] = acc[r];
    } else {
      int d = j - 128;
      int dti = d >> 4, jj = d & 15;
      for (int r = 3; r < 19; ++r) {
        int l = l0 - 3 + r;
        if (l < l0 + nl)
          z_l[((size_t)(b * 8 + dti) * LTOT + loff + l) * 16 + jj] = f2b(acc[r]);
      }
    }
  }
  __syncthreads();
  for (int i = tid; i < 16 * 128; i += 256) {
    int l = i >> 7, d = i & 127;
    if (l < nl) {
      const float* wc = Wconv + (lvl * 128 + d) * 4;
      float a = bconv[lvl * 128 + d];
#pragma unroll
      for (int k = 0; k < 4; ++k) a = fmaf(wc[k], s_xs[(l + k) * 128 + d], a);
      float uu = siluf(a);
      s_u[l * 132 + d] = uu;
      u_l[((size_t)(b * 8 + (d >> 4)) * LTOT + loff + l0 + l) * 16 + (d & 15)] = f2b(uu);
    }
  }
  __syncthreads();
  for (int i = tid; i < 16 * 36; i += 256) {
    int l = i & 15, jj = i >> 4;
    if (l < nl) {
      const float* wx = Wx + lvl * 128 * 36 + jj;
      float a = 0.f;
      for (int d = 0; d < 128; ++d) a = fmaf(s_u[l * 132 + d], wx[d * 36], a);
      s_dbc[l * 36 + jj] = a;
      if (jj >= 4) {
        int q = jj - 4;
        size_t gb = ((size_t)(b * LTOT) + loff + l0 + l) * 16;
        if (q < 16) Bm_l[gb + q] = f2b(a);
        else        Cm_l[gb + (q - 16)] = f2b(a);
      }
    }
  }
  __syncthreads();
  for (int i = tid; i < 16 * 128; i += 256) {
    int l = i >> 7, d = i & 127;
    if (l < nl) {
      float a = bdt[lvl * 128 + d];
#pragma unroll
      for (int r = 0; r < 4; ++r)
        a = fmaf(s_dbc[l * 36 + r], Wdt[(lvl * 4 + r) * 128 + d], a);
      dt_l[((size_t)(b * 8 + (d >> 4)) * LTOT + loff + l0 + l) * 16 + (d & 15)] =
          f2b(softplusf(a));
    }
  }
}

// ------------------ chunked scan (CH=32), 4 states/thread --------------------
// Block = 256 thr = 64 d x 4 lanes; each thread owns n = n0..n0+3 of one d.
template <int MODE, int PASSC>
__global__ __launch_bounds__(256) void k_scan(
    const u16* __restrict__ dtb, const u16* __restrict__ ub,
    const u16* __restrict__ Bmb, const u16* __restrict__ Cmb,
    const u16* __restrict__ zb,
    const float* __restrict__ Alog, const float* __restrict__ Dsk,
    float* __restrict__ hloc, float* __restrict__ Ssum,
    const float* __restrict__ hin, u16* __restrict__ yg) {
  constexpr int DI = MODE ? 512 : 128;
  constexpr int NDT = DI / 16;
  constexpr int NB = DI / 64;
  constexpr int NCHT = MODE ? NCHC : NCHL;
  constexpr int LT = MODE ? LC : LTOT;
  __shared__ __align__(16) u16 smem[PASSC ? 7168 : 4608];
  u16* s_dt = smem;                 // [4][32*16]
  u16* s_u  = smem + 2048;          // [4][32*16]
  u16* s_B  = smem + 4096;          // [32][16]
  u16* s_C  = PASSC ? smem + 4608 : nullptr;   // [32][16]
  u16* s_y  = PASSC ? smem + 5120 : nullptr;   // [32][64]

  int bid = blockIdx.x;
  int dblk = bid % NB;
  int rem = bid / NB;
  int gc = rem % NCHT;
  int b = rem / NCHT;
  int lvl = 0, ch = gc, Lq = LC, loff = 0;
  if (MODE == 0) {
    while (lvl < 3 && gc >= CHOFF4[lvl + 1]) ++lvl;
    ch = gc - CHOFF4[lvl];
    Lq = L4[lvl];
    loff = LOFF4[lvl];
  }
  int l0 = ch * 32;
  int len = min(32, Lq - l0);
  int labs0 = loff + l0;
  int tid = threadIdx.x;
  int q = tid & 3;
  int dl = (tid >> 2) & 15;
  int ti_l = tid >> 6;
  int dti = dblk * 4 + ti_l;
  int d = dti * 16 + dl;
  int n0 = q * 4;

  for (int ti = 0; ti < 4; ++ti) {
    size_t g2 = ((size_t)(b * NDT + dblk * 4 + ti) * LT + labs0) * 16;
    const u16x8* pdt = (const u16x8*)(dtb + g2);
    const u16x8* pu  = (const u16x8*)(ub + g2);
    for (int i = tid; i < len * 2; i += 256) {
      *(u16x8*)&s_dt[ti * 512 + i * 8] = pdt[i];
      *(u16x8*)&s_u [ti * 512 + i * 8] = pu[i];
    }
  }
  {
    size_t gB = ((size_t)b * LT + labs0) * 16;
    for (int i = tid; i < len * 2; i += 256) {
      *(u16x8*)&s_B[i * 8] = *(const u16x8*)&Bmb[gB + i * 8];
      if (PASSC) *(u16x8*)&s_C[i * 8] = *(const u16x8*)&Cmb[gB + i * 8];
    }
  }
  __syncthreads();

  int ai = (MODE ? d : lvl * 128 + d);
  float4 al = *(const float4*)&Alog[ai * 16 + n0];
  float kA2[4] = {-__expf(al.x) * LOG2E, -__expf(al.y) * LOG2E,
                  -__expf(al.z) * LOG2E, -__expf(al.w) * LOG2E};
  size_t hix = (((size_t)(b * NCHT) + gc) * DI + d) * 16 + n0;
  float h[4] = {0.f, 0.f, 0.f, 0.f};
  if (PASSC) {
    float4 hv = *(const float4*)&hin[hix];
    h[0] = hv.x; h[1] = hv.y; h[2] = hv.z; h[3] = hv.w;
  }
  float dsk = PASSC ? Dsk[ai] : 0.f;
  float ss = 0.f;

  for (int l = 0; l < len; ++l) {
    float dt = b2f(s_dt[ti_l * 512 + l * 16 + dl]);
    float uu = b2f(s_u [ti_l * 512 + l * 16 + dl]);
    float dtu = dt * uu;
    u16x4 Bv = *(const u16x4*)&s_B[l * 16 + n0];
    if (PASSC) {
      u16x4 Cv = *(const u16x4*)&s_C[l * 16 + n0];
      float p = 0.f;
#pragma unroll
      for (int i = 0; i < 4; ++i) {
        float dA = exp2f(kA2[i] * dt);
        h[i] = fmaf(dA, h[i], dtu * b2f(Bv[i]));
        p = fmaf(h[i], b2f(Cv[i]), p);
      }
      p += __shfl_xor(p, 1, 4);
      p += __shfl_xor(p, 2, 4);
      if (q == 0) s_y[l * 64 + ti_l * 16 + dl] = f2b(fmaf(uu, dsk, p));
    } else {
#pragma unroll
      for (int i = 0; i < 4; ++i) {
        float dA = exp2f(kA2[i] * dt);
        h[i] = fmaf(dA, h[i], dtu * b2f(Bv[i]));
      }
      ss += dt;
    }
  }
  if (!PASSC) {
    f32x4 hv = {h[0], h[1], h[2], h[3]};
    *(f32x4*)&hloc[hix] = hv;
    if (q == 0) Ssum[((size_t)(b * NCHT) + gc) * DI + d] = ss;
  } else {
    __syncthreads();
    for (int ti = 0; ti < 4; ++ti) {
      size_t g2 = ((size_t)(b * NDT + dblk * 4 + ti) * LT + labs0) * 16;
      for (int i = tid; i < len * 2; i += 256) {
        u16x8 zv = *(const u16x8*)&zb[g2 + i * 8];
        u16x8 yv = *(const u16x8*)&s_y[(i >> 1) * 64 + ti * 16 + (i & 1) * 8];
        u16x8 o;
#pragma unroll
        for (int j = 0; j < 8; ++j) {
          float z = b2f(zv[j]);
          float gate = z / (1.f + __expf(-z));
          o[j] = f2b(b2f(yv[j]) * gate);
        }
        *(u16x8*)&yg[g2 + i * 8] = o;
      }
    }
  }
}

__global__ __launch_bounds__(256) void k_combine_lvl(
    const float* __restrict__ Alog, const float* __restrict__ hloc,
    const float* __restrict__ Ssum, float* __restrict__ hin) {
  int i = blockIdx.x * 256 + threadIdx.x;   // 16384
  int n = i & 15, d = (i >> 4) & 127, lvl = (i >> 11) & 3, b = i >> 13;
  float kA2 = -__expf(Alog[(lvl * 128 + d) * 16 + n]) * LOG2E;
  float h = 0.f;
  int nch = NCH4[lvl];
  for (int ch = 0; ch < nch; ++ch) {
    int gc = CHOFF4[lvl] + ch;
    size_t ix = (((size_t)(b * NCHL) + gc) * 128 + d) * 16 + n;
    hin[ix] = h;
    float S = Ssum[((size_t)(b * NCHL) + gc) * 128 + d];
    h = fmaf(exp2f(kA2 * S), h, hloc[ix]);
  }
}

__global__ __launch_bounds__(256) void k_combine_cr(
    const float* __restrict__ Alog, const float* __restrict__ hloc,
    const float* __restrict__ Ssum, float* __restrict__ hin) {
  int i = blockIdx.x * 256 + threadIdx.x;   // 16384
  int n = i & 15, d = (i >> 4) & 511, b = i >> 13;
  float kA2 = -__expf(Alog[d * 16 + n]) * LOG2E;
  float h = 0.f;
  for (int ch = 0; ch < NCHC; ++ch) {
    size_t ix = (((size_t)(b * NCHC) + ch) * 512 + d) * 16 + n;
    hin[ix] = h;
    float S = Ssum[((size_t)(b * NCHC) + ch) * 512 + d];
    h = fmaf(exp2f(kA2 * S), h, hloc[ix]);
  }
}

// --------------- level out-GEMM + residual, store (B,C,L) CHW ----------------
__global__ __launch_bounds__(256) void k_out_lvl(
    const u16* __restrict__ yg_l, const float* __restrict__ Wout, // (4,128,64)
    const float* __restrict__ f0, const float* __restrict__ f1,
    const float* __restrict__ f2, const float* __restrict__ f3,
    float* __restrict__ fout) {
  __shared__ float s_ygT[128 * 20];   // [d][l], stride 20
  __shared__ float s_o[16 * 64];
  int bid = blockIdx.x;  // B*NTT
  int b = bid / NTT, t = bid - b * NTT;
  int lvl = 0;
  while (lvl < 3 && t >= TOFF4[lvl + 1]) ++lvl;
  int tl = t - TOFF4[lvl];
  int L = L4[lvl], loff = LOFF4[lvl];
  int l0 = tl * 16, nl = min(16, L - l0);
  const float* fx = lvl == 0 ? f0 : lvl == 1 ? f1 : lvl == 2 ? f2 : f3;
  int tid = threadIdx.x;
  for (int i = tid; i < 16 * 128; i += 256) {
    int d = i & 127, l = i >> 7;
    float v = 0.f;
    if (l < nl)
      v = b2f(yg_l[((size_t)(b * 8 + (d >> 4)) * LTOT + loff + l0 + l) * 16 + (d & 15)]);
    s_ygT[d * 20 + l] = v;
  }
  __syncthreads();
  {
    int c = tid & 63, lg = (tid >> 6) * 4;
    float acc[4] = {0.f, 0.f, 0.f, 0.f};
    const float* W = Wout + lvl * 128 * 64 + c;
    for (int dq = 0; dq < 128; ++dq) {
      float w = W[dq * 64];
      float4 yv = *(const float4*)&s_ygT[dq * 20 + lg];
      acc[0] = fmaf(w, yv.x, acc[0]);
      acc[1] = fmaf(w, yv.y, acc[1]);
      acc[2] = fmaf(w, yv.z, acc[2]);
      acc[3] = fmaf(w, yv.w, acc[3]);
    }
#pragma unroll
    for (int a = 0; a < 4; ++a) s_o[(lg + a) * 64 + c] = acc[a];
  }
  __syncthreads();
  for (int i = tid; i < 16 * 64; i += 256) {
    int c = i >> 4, l = i & 15;
    if (l < nl)
      fout[((size_t)(b * 64) + c) * LTOT + loff + l0 + l] =
          s_o[l * 64 + c] + fx[((size_t)(b * 64) + c) * L + l0 + l];
  }
}

// ----------- bilinear resize + concat -> (b,l,c) bf16 ------------------------
__global__ __launch_bounds__(256) void k_resize(const float* __restrict__ fout,
                                                u16* __restrict__ xTb) {
  int i = blockIdx.x * 256 + threadIdx.x;   // B*2304*256, ch fastest
  int ch = i & 255;
  int rem = i >> 8;
  int hw = rem % 2304;
  int b = rem / 2304;
  int oh = hw / 48, ow = hw - oh * 48;
  int lvl = ch >> 6, c = ch & 63;
  int s = S4[lvl];
  const float* base = fout + ((size_t)(b * 64) + c) * LTOT + LOFF4[lvl];
  float scl = (float)(s - 1) * (1.f / 47.f);
  float fy = oh * scl, fxx = ow * scl;
  int y0 = (int)floorf(fy), x0 = (int)floorf(fxx);
  float wy = fy - y0, wx = fxx - x0;
  int y1 = min(y0 + 1, s - 1), x1 = min(x0 + 1, s - 1);
  float v00 = base[y0 * s + x0], v01 = base[y0 * s + x1];
  float v10 = base[y1 * s + x0], v11 = base[y1 * s + x1];
  float top = v00 * (1.f - wx) + v01 * wx;
  float bot = v10 * (1.f - wx) + v11 * wx;
  xTb[i] = f2b(top * (1.f - wy) + bot * wy);
}

// ----------------- cross input GEMM via MFMA: xT @ WinT^T --------------------
// M=4608 (b*l), N=1024 (j), K=256 (c). BM=64 BN=128 BK=64, 4 waves (32x64).
__global__ __launch_bounds__(256) void k_gemm_mfma(
    const u16* __restrict__ xT,   // (4608, 256) bf16
    const u16* __restrict__ WT,   // (1024, 256) bf16
    u16* __restrict__ xs_c, u16* __restrict__ z_c) {
  __shared__ __align__(16) u16 s_a[64 * 72];
  __shared__ __align__(16) u16 s_b[128 * 72];
  int bid = blockIdx.x;            // 72 * 8
  int nj = bid & 7, bm = bid >> 3;
  int tid = threadIdx.x;
  int lane = tid & 63, w = tid >> 6;
  int wm = (w & 1) * 32, wn = (w >> 1) * 64;
  const int m_base = bm * 64;
  const int n_base = nj * 128;

  f32x4 acc[2][4];
#pragma unroll
  for (int mi = 0; mi < 2; ++mi)
#pragma unroll
    for (int ni = 0; ni < 4; ++ni) acc[mi][ni] = {0.f, 0.f, 0.f, 0.f};

  u16x8 ra0, ra1, rb0, rb1, rb2, rb3;
  auto ld = [&](int c0) {
#pragma unroll
    for (int s = 0; s < 2; ++s) {
      int v = s * 256 + tid;
      int row = v >> 3, kc = (v & 7) * 8;
      u16x8 t = *(const u16x8*)&xT[(size_t)(m_base + row) * 256 + c0 + kc];
      if (s == 0) ra0 = t; else ra1 = t;
    }
#pragma unroll
    for (int s = 0; s < 4; ++s) {
      int v = s * 256 + tid;
      int row = v >> 3, kc = (v & 7) * 8;
      u16x8 t = *(const u16x8*)&WT[(size_t)(n_base + row) * 256 + c0 + kc];
      if (s == 0) rb0 = t; else if (s == 1) rb1 = t;
      else if (s == 2) rb2 = t; else rb3 = t;
    }
  };
  auto st = [&]() {
#pragma unroll
    for (int s = 0; s < 2; ++s) {
      int v = s * 256 + tid;
      int row = v >> 3, kc = (v & 7) * 8;
      *(u16x8*)&s_a[row * 72 + kc] = (s == 0) ? ra0 : ra1;
    }
#pragma unroll
    for (int s = 0; s < 4; ++s) {
      int v = s * 256 + tid;
      int row = v >> 3, kc = (v & 7) * 8;
      const u16x8& t = (s == 0) ? rb0 : (s == 1) ? rb1 : (s == 2) ? rb2 : rb3;
      *(u16x8*)&s_b[row * 72 + kc] = t;
    }
  };
  ld(0);
  int mlane = lane & 15, kg = (lane >> 4) * 8;
  for (int kt = 0; kt < 4; ++kt) {
    st();
    __syncthreads();
    if (kt < 3) ld((kt + 1) * 64);
#pragma unroll
    for (int kk = 0; kk < 2; ++kk) {
      int k0 = kk * 32 + kg;
      bf16x8 af[2], bfr[4];
#pragma unroll
      for (int mi = 0; mi < 2; ++mi)
        af[mi] = *(const bf16x8*)&s_a[(wm + mi * 16 + mlane) * 72 + k0];
#pragma unroll
      for (int ni = 0; ni < 4; ++ni)
        bfr[ni] = *(const bf16x8*)&s_b[(wn + ni * 16 + mlane) * 72 + k0];
#pragma unroll
      for (int mi = 0; mi < 2; ++mi)
#pragma unroll
        for (int ni = 0; ni < 4; ++ni)
          acc[mi][ni] = __builtin_amdgcn_mfma_f32_16x16x32_bf16(
              af[mi], bfr[ni], acc[mi][ni], 0, 0, 0);
    }
    __syncthreads();
  }
  int rgrp = (lane >> 4) * 4;
#pragma unroll
  for (int mi = 0; mi < 2; ++mi) {
#pragma unroll
    for (int ni = 0; ni < 4; ++ni) {
      int n = n_base + wn + ni * 16 + mlane;
#pragma unroll
      for (int r = 0; r < 4; ++r) {
        int gm = m_base + wm + mi * 16 + rgrp + r;
        int b = gm >= 2304;
        int l = gm - b * 2304;
        u16 v = f2b(acc[mi][ni][r]);
        if (n < 512) {
          xs_c[((size_t)(b * LC) + l) * 512 + n] = v;
        } else {
          int dz = n - 512;
          z_c[((size_t)(b * 32 + (dz >> 4)) * LC + l) * 16 + (dz & 15)] = v;
        }
      }
    }
  }
}

// -------- cross mid: conv + silu + dbc + dt, 16-l tiles, 1024 threads --------
__global__ __launch_bounds__(1024) void k_mid_cr(
    const u16* __restrict__ xs_c,    // (B,2304,512) bf16
    const float* __restrict__ Wconv, // (512,4)
    const float* __restrict__ bconv,
    const float* __restrict__ WxT,   // (48,512)
    const float* __restrict__ Wdt,   // (16,512)
    const float* __restrict__ bdt, u16* __restrict__ u_c,
    u16* __restrict__ dt_c, u16* __restrict__ Bm_c, u16* __restrict__ Cm_c) {
  __shared__ __align__(16) u16 s_xs[19 * 512];
  __shared__ __align__(16) u16 s_ub[16 * 520];
  __shared__ __align__(16) float s_wx[48 * 132];
  __shared__ float s_dbc[16 * 48];
  int bid = blockIdx.x;  // B*144
  int b = bid / 144, tl = bid - b * 144;
  int l0 = tl * 16;
  int tid = threadIdx.x;
  for (int i = tid; i < 19 * 64; i += 1024) {
    int r = i >> 6, c8 = (i & 63) * 8;
    int l = l0 - 3 + r;
    u16x8 v = {0, 0, 0, 0, 0, 0, 0, 0};
    if (l >= 0)
      v = *(const u16x8*)&xs_c[((size_t)(b * LC) + l) * 512 + c8];
    *(u16x8*)&s_xs[r * 512 + c8] = v;
  }
  __syncthreads();
  for (int i = tid; i < 16 * 512; i += 1024) {
    int l = i >> 9, d = i & 511;
    const float* wc = Wconv + d * 4;
    float a = bconv[d];
#pragma unroll
    for (int k = 0; k < 4; ++k) a = fmaf(wc[k], b2f(s_xs[(l + k) * 512 + d]), a);
    float uu = siluf(a);
    u16 ub = f2b(uu);
    s_ub[l * 520 + d] = ub;
    u_c[((size_t)(b * 32 + (d >> 4)) * LC + l0 + l) * 16 + (d & 15)] = ub;
  }
  int dl = tid & 15, jj = tid >> 4;
  float a8[8] = {0.f, 0.f, 0.f, 0.f, 0.f, 0.f, 0.f, 0.f};
  for (int kt = 0; kt < 4; ++kt) {
    __syncthreads();
    for (int i = tid; i < 1536; i += 1024) {
      int row = i >> 5, c4 = (i & 31) * 4;
      *(float4*)&s_wx[row * 132 + c4] =
          *(const float4*)&WxT[row * 512 + kt * 128 + c4];
    }
    __syncthreads();
    if (tid < 768) {
      const u16* ur = s_ub + dl * 520 + kt * 128;
      const float* wr = s_wx + jj * 132;
#pragma unroll 4
      for (int kb = 0; kb < 16; ++kb) {
        u16x8 uv = *(const u16x8*)&ur[kb * 8];
        float4 w0 = *(const float4*)&wr[kb * 8];
        float4 w1 = *(const float4*)&wr[kb * 8 + 4];
        a8[0] = fmaf(b2f(uv[0]), w0.x, a8[0]);
        a8[1] = fmaf(b2f(uv[1]), w0.y, a8[1]);
        a8[2] = fmaf(b2f(uv[2]), w0.z, a8[2]);
        a8[3] = fmaf(b2f(uv[3]), w0.w, a8[3]);
        a8[4] = fmaf(b2f(uv[4]), w1.x, a8[4]);
        a8[5] = fmaf(b2f(uv[5]), w1.y, a8[5]);
        a8[6] = fmaf(b2f(uv[6]), w1.z, a8[6]);
        a8[7] = fmaf(b2f(uv[7]), w1.w, a8[7]);
      }
    }
  }
  if (tid < 768) {
    float a = ((a8[0] + a8[1]) + (a8[2] + a8[3])) +
              ((a8[4] + a8[5]) + (a8[6] + a8[7]));
    s_dbc[dl * 48 + jj] = a;
    if (jj >= 16) {
      int q = jj - 16;
      size_t gb = ((size_t)(b * LC) + l0 + dl) * 16;
      if (q < 16) Bm_c[gb + q] = f2b(a);
      else        Cm_c[gb + (q - 16)] = f2b(a);
    }
  }
  __syncthreads();
  for (int i = tid; i < 16 * 512; i += 1024) {
    int l = i >> 9, d = i & 511;
    float a = bdt[d];
#pragma unroll
    for (int r = 0; r < 16; ++r)
      a = fmaf(s_dbc[l * 48 + r], Wdt[r * 512 + d], a);
    dt_c[((size_t)(b * 32 + (d >> 4)) * LC + l0 + l) * 16 + (d & 15)] =
        f2b(softplusf(a));
  }
}

// --- final via MFMA: out = relu(BN([x|yg] @ [WtB|WPB]^T + pb)) ---------------
// M=4608(l), N=64(o), K=768. Grid 288 blocks x 1 wave; M-tile 16.
__global__ __launch_bounds__(64) void k_final_mfma(
    const u16* __restrict__ xTb,   // (4608,256) bf16
    const u16* __restrict__ yg_c,  // (B,32,LC,16) bf16
    const u16* __restrict__ WtB,   // (64,256) bf16
    const u16* __restrict__ WPB,   // (64,512) bf16
    const float* __restrict__ pb, const float* __restrict__ bng,
    const float* __restrict__ bnb, const float* __restrict__ bnm,
    const float* __restrict__ bnv, float* __restrict__ out) {
  int bm = blockIdx.x;             // 288
  int b = bm >= 144;
  int m_base = bm * 16;            // row in 4608 space
  int l_base = m_base - b * 2304;
  int lane = threadIdx.x;
  int mrow = lane & 15;
  int kg = (lane >> 4) * 8;
  f32x4 acc[4];
#pragma unroll
  for (int ni = 0; ni < 4; ++ni) acc[ni] = {0.f, 0.f, 0.f, 0.f};
  // Phase A: K 0..255 from xTb / WtB
#pragma unroll
  for (int kt = 0; kt < 8; ++kt) {
    int k0 = kt * 32;
    bf16x8 af = *(const bf16x8*)&xTb[(size_t)(m_base + mrow) * 256 + k0 + kg];
#pragma unroll
    for (int ni = 0; ni < 4; ++ni) {
      bf16x8 bw = *(const bf16x8*)&WtB[(ni * 16 + mrow) * 256 + k0 + kg];
      acc[ni] = __builtin_amdgcn_mfma_f32_16x16x32_bf16(af, bw, acc[ni], 0, 0, 0);
    }
  }
  // Phase B: K 256..767 from yg_c / WPB
#pragma unroll
  for (int kt = 0; kt < 16; ++kt) {
    int kp = kt * 32 + kg;
    int dt = kp >> 4, j0 = kp & 15;
    bf16x8 af = *(const bf16x8*)
        &yg_c[((size_t)(b * 32 + dt) * LC + l_base + mrow) * 16 + j0];
#pragma unroll
    for (int ni = 0; ni < 4; ++ni) {
      bf16x8 bw = *(const bf16x8*)&WPB[(ni * 16 + mrow) * 512 + kt * 32 + kg];
      acc[ni] = __builtin_amdgcn_mfma_f32_16x16x32_bf16(af, bw, acc[ni], 0, 0, 0);
    }
  }
  int rg = (lane >> 4) * 4;
#pragma unroll
  for (int ni = 0; ni < 4; ++ni) {
    int o = ni * 16 + mrow;
    float bias = pb[o], m = bnm[o], g = bng[o], v = bnv[o], bb2 = bnb[o];
    float scl = g * (1.f / sqrtf(v + 1e-5f));
    float4 r;
    r.x = fmaxf((acc[ni][0] + bias - m) * scl + bb2, 0.f);
    r.y = fmaxf((acc[ni][1] + bias - m) * scl + bb2, 0.f);
    r.z = fmaxf((acc[ni][2] + bias - m) * scl + bb2, 0.f);
    r.w = fmaxf((acc[ni][3] + bias - m) * scl + bb2, 0.f);
    *(float4*)&out[((size_t)(b * 64) + o) * LC + l_base + rg] = r;
  }
}

// -----------------------------------------------------------------------------
extern "C" void kernel_launch(void* const* d_in, const int* in_sizes, int n_in,
                              void* d_out, int out_size, void* d_ws,
                              size_t ws_size, hipStream_t stream) {
  (void)in_sizes; (void)n_in; (void)out_size; (void)ws_size;
  const float* f0 = (const float*)d_in[0];
  const float* f1 = (const float*)d_in[1];
  const float* f2 = (const float*)d_in[2];
  const float* f3 = (const float*)d_in[3];
  const float* lWin   = (const float*)d_in[4];
  const float* lWconv = (const float*)d_in[5];
  const float* lbconv = (const float*)d_in[6];
  const float* lWx    = (const float*)d_in[7];
  const float* lWdt   = (const float*)d_in[8];
  const float* lbdt   = (const float*)d_in[9];
  const float* lAlog  = (const float*)d_in[10];
  const float* lD     = (const float*)d_in[11];
  const float* lWout  = (const float*)d_in[12];
  const float* cWin   = (const float*)d_in[13];
  const float* cWconv = (const float*)d_in[14];
  const float* cbconv = (const float*)d_in[15];
  const float* cWx    = (const float*)d_in[16];
  const float* cWdt   = (const float*)d_in[17];
  const float* cbdt   = (const float*)d_in[18];
  const float* cAlog  = (const float*)d_in[19];
  const float* cD     = (const float*)d_in[20];
  const float* cWout  = (const float*)d_in[21];
  const float* projW  = (const float*)d_in[22];
  const float* projb  = (const float*)d_in[23];
  const float* bng    = (const float*)d_in[24];
  const float* bnb    = (const float*)d_in[25];
  const float* bnm    = (const float*)d_in[26];
  const float* bnv    = (const float*)d_in[27];
  float* out = (float*)d_out;

  float* ws = (float*)d_ws;
  size_t off = 0;
  auto allocf = [&](size_t n) { float* p = ws + off; off += (n + 7) & ~(size_t)7; return p; };
  auto allocb = [&](size_t n) { u16* p = (u16*)(ws + off); off += ((n + 1) / 2 + 7) & ~(size_t)7; return p; };

  float* WxT    = allocf(48 * 512);
  float* fout   = allocf((size_t)B_ * 64 * LTOT);
  float* hloc_l = allocf((size_t)B_ * NCHL * 128 * 16);
  float* S_l    = allocf((size_t)B_ * NCHL * 128);
  float* hin_l  = allocf((size_t)B_ * NCHL * 128 * 16);
  float* hloc_c = allocf((size_t)B_ * NCHC * 512 * 16);
  float* S_c    = allocf((size_t)B_ * NCHC * 512);
  float* hin_c  = allocf((size_t)B_ * NCHC * 512 * 16);

  u16* WPB   = allocb(64 * 512);
  u16* WtB   = allocb(64 * 256);
  u16* WinT  = allocb(1024 * 256);
  u16* xTb   = allocb((size_t)B_ * LC * 256);
  u16* u_l2  = allocb((size_t)B_ * 8 * LTOT * 16);
  u16* dt_l2 = allocb((size_t)B_ * 8 * LTOT * 16);
  u16* z_l2  = allocb((size_t)B_ * 8 * LTOT * 16);
  u16* yg_l2 = allocb((size_t)B_ * 8 * LTOT * 16);
  u16* Bm_l2 = allocb((size_t)B_ * LTOT * 16);
  u16* Cm_l2 = allocb((size_t)B_ * LTOT * 16);
  u16* xs_c2 = allocb((size_t)B_ * LC * 512);
  u16* u_c2  = allocb((size_t)B_ * 32 * LC * 16);
  u16* dt_c2 = allocb((size_t)B_ * 32 * LC * 16);
  u16* z_c2  = allocb((size_t)B_ * 32 * LC * 16);
  u16* yg_c2 = allocb((size_t)B_ * 32 * LC * 16);
  u16* Bm_c2 = allocb((size_t)B_ * LC * 16);
  u16* Cm_c2 = allocb((size_t)B_ * LC * 16);

  k_prep<<<352, 256, 0, stream>>>(projW, cWout, cWin, cWx, WPB, WtB, WinT, WxT);

  k_front_lvl<<<B_ * NTT, 256, 0, stream>>>(f0, f1, f2, f3, lWin, lWconv,
                                            lbconv, lWx, lWdt, lbdt, u_l2,
                                            dt_l2, Bm_l2, Cm_l2, z_l2);

  k_scan<0, 0><<<B_ * NCHL * 2, 256, 0, stream>>>(
      dt_l2, u_l2, Bm_l2, Cm_l2, nullptr, lAlog, lD, hloc_l, S_l, nullptr,
      nullptr);
  k_combine_lvl<<<64, 256, 0, stream>>>(lAlog, hloc_l, S_l, hin_l);
  k_scan<0, 1><<<B_ * NCHL * 2, 256, 0, stream>>>(
      dt_l2, u_l2, Bm_l2, Cm_l2, z_l2, lAlog, lD, nullptr, nullptr, hin_l,
      yg_l2);

  k_out_lvl<<<B_ * NTT, 256, 0, stream>>>(yg_l2, lWout, f0, f1, f2, f3, fout);
  k_resize<<<(B_ * 256 * LC) / 256, 256, 0, stream>>>(fout, xTb);

  k_gemm_mfma<<<72 * 8, 256, 0, stream>>>(xTb, WinT, xs_c2, z_c2);
  k_mid_cr<<<B_ * 144, 1024, 0, stream>>>(xs_c2, cWconv, cbconv, WxT, cWdt,
                                          cbdt, u_c2, dt_c2, Bm_c2, Cm_c2);

  k_scan<1, 0><<<B_ * NCHC * 8, 256, 0, stream>>>(
      dt_c2, u_c2, Bm_c2, Cm_c2, nullptr, cAlog, cD, hloc_c, S_c, nullptr,
      nullptr);
  k_combine_cr<<<64, 256, 0, stream>>>(cAlog, hloc_c, S_c, hin_c);
  k_scan<1, 1><<<B_ * NCHC * 8, 256, 0, stream>>>(
      dt_c2, u_c2, Bm_c2, Cm_c2, z_c2, cAlog, cD, nullptr, nullptr, hin_c,
      yg_c2);

  k_final_mfma<<<288, 64, 0, stream>>>(xTb, yg_c2, WtB, WPB, projb, bng, bnb,
                                       bnm, bnv, out);
}